// Round 1
// baseline (3543.447 us; speedup 1.0000x reference)
//
#include <hip/hip_runtime.h>
#include <math.h>

#define B_ 256
#define T_ 200
#define H_ 256
#define DOF_ 12

typedef __bf16 bf16;
typedef __bf16 bf16x8 __attribute__((ext_vector_type(8)));
typedef float f32x4 __attribute__((ext_vector_type(4)));

#define XK 288      // gate GEMM K: 256 h + 12 prev + 20 zero pad
#define XPAD 296    // xbuf row stride (592B -> stride 20 banks, 2-way max)
#define P1PAD 264

#define PI_D 3.14159265358979323846

// ---- workspace byte offsets (all 16B aligned) ----
#define OFF_TF     0u          // 200*13*4        = 10400
#define OFF_TCON   10400u      // 200*1024*4      = 819200
#define OFF_ZC     829600u     // 256*1024*4      = 1048576
#define OFF_H0     1878176u    // 256*256*4       = 262144
#define OFF_C0     2140320u    // 262144
#define OFF_WCOMB  2402464u    // 1024*288*2      = 589824
#define OFF_WP1    2992288u    // 256*256*2       = 131072
#define OFF_WP2    3123360u    // 16*256*2        = 8192
#define OFF_WO1    3131552u    // 131072
#define OFF_WO2    3262624u    // 8192
#define OFF_WV     3270816u    // 48*256*2        = 24576
#define OFF_HSEQ   3295392u    // 256*200*256*2   = 26214400  (total ~29.5MB)

__device__ __forceinline__ float sigf(float x) { return 1.f / (1.f + __expf(-x)); }
__device__ __forceinline__ float tanh_f(float x) {
  float a = fabsf(x);
  float e = __expf(-2.f * a);
  float t = (1.f - e) / (1.f + e);
  return x < 0.f ? -t : t;
}

// ---------------- time features [T,13] ----------------
__global__ void k_tfeat(float* tf) {
  int i = blockIdx.x * blockDim.x + threadIdx.x;
  if (i >= T_ * 13) return;
  int t = i / 13, j = i % 13;
  float tv = (float)t / 199.f;
  float v;
  if (j == 0) v = tv;
  else {
    int k = (j - 1) >> 1;
    float f = (float)(1 << k);
    double arg = 2.0 * PI_D * (double)f * (double)tv;
    v = (j & 1) ? (float)sin(arg) : (float)cos(arg);
  }
  tf[i] = v;
}

// ------------- precompute tcon, zc, h0, c0 -------------
__global__ void k_prep(const float* __restrict__ tf, const float* __restrict__ Wih,
                       const float* __restrict__ z,
                       const float* __restrict__ bih, const float* __restrict__ bhh,
                       const float* __restrict__ Whz, const float* __restrict__ bhz,
                       const float* __restrict__ Wcz, const float* __restrict__ bcz,
                       float* tcon, float* zc, float* h0, float* c0) {
  int i = blockIdx.x * blockDim.x + threadIdx.x;
  if (i < 204800) {                      // tcon[t][n] = tf . Wih[:,76:89]
    int t = i / 1024, n = i % 1024;
    float s = 0.f;
    #pragma unroll
    for (int j = 0; j < 13; ++j) s += tf[t * 13 + j] * Wih[n * 89 + 76 + j];
    tcon[i] = s;
    return;
  }
  i -= 204800;
  if (i < 262144) {                      // zc[b][n] = bih+bhh + z . Wih[:,12:76]
    int b = i / 1024, n = i % 1024;
    float s = bih[n] + bhh[n];
    for (int k = 0; k < 64; ++k) s += z[b * 64 + k] * Wih[n * 89 + 12 + k];
    zc[i] = s;
    return;
  }
  i -= 262144;
  if (i < 65536) {                       // h0
    int b = i / 256, u = i % 256;
    float s = bhz[u];
    for (int k = 0; k < 64; ++k) s += z[b * 64 + k] * Whz[u * 64 + k];
    h0[i] = s;
    return;
  }
  i -= 65536;
  if (i < 65536) {                       // c0
    int b = i / 256, u = i % 256;
    float s = bcz[u];
    for (int k = 0; k < 64; ++k) s += z[b * 64 + k] * Wcz[u * 64 + k];
    c0[i] = s;
  }
}

// ------------- bf16 weight casts -------------
__global__ void k_cast(const float* __restrict__ Whh, const float* __restrict__ Wih,
                       const float* __restrict__ Wp1, const float* __restrict__ Wp2,
                       const float* __restrict__ Wo1, const float* __restrict__ Wo2,
                       const float* __restrict__ Wv,
                       bf16* Wcomb, bf16* Wp1b, bf16* Wp2b, bf16* Wo1b,
                       bf16* Wo2b, bf16* Wvb) {
  int i = blockIdx.x * blockDim.x + threadIdx.x;
  if (i < 294912) {                      // Wcomb[n][k]: k<256 Whh, 256..267 Wih prev cols
    int n = i / XK, k = i % XK;
    float v = (k < 256) ? Whh[n * 256 + k]
            : ((k < 268) ? Wih[n * 89 + (k - 256)] : 0.f);
    Wcomb[i] = (bf16)v;
    return;
  }
  i -= 294912;
  if (i < 65536) { Wp1b[i] = (bf16)Wp1[i]; return; }
  i -= 65536;
  if (i < 4096) { int r = i / 256; Wp2b[i] = (bf16)((r < 12) ? Wp2[i] : 0.f); return; }
  i -= 4096;
  if (i < 65536) { Wo1b[i] = (bf16)Wo1[i]; return; }
  i -= 65536;
  if (i < 4096) { int r = i / 256; Wo2b[i] = (bf16)((r < 3) ? Wo2[i] : 0.f); return; }
  i -= 4096;
  if (i < 12288) { int r = i / 256; Wvb[i] = (bf16)((r < 42) ? Wv[i] : 0.f); }
}

// ------------- recurrent LSTM: 16 blocks x 16 batch, 8 waves -------------
__global__ __launch_bounds__(512) void k_recur(
    const float* __restrict__ zc, const float* __restrict__ tcon,
    const float* __restrict__ h0, const float* __restrict__ c0,
    const bf16* __restrict__ Wcomb, const bf16* __restrict__ Wp1b,
    const bf16* __restrict__ Wp2b,
    const float* __restrict__ bp1, const float* __restrict__ bp2,
    const float* __restrict__ jlo, const float* __restrict__ jhi,
    const float* __restrict__ ddp,
    bf16* __restrict__ Hseq, float* __restrict__ outJ, float* __restrict__ outA) {
  __shared__ bf16 xbuf[16][XPAD];   // [batch][k]: h(0..255), prev_norm(256..267), 0-pad
  __shared__ bf16 p1buf[16][P1PAD];
  const int tid = threadIdx.x;
  const int wv = tid >> 6;   // 0..7
  const int ln = tid & 63;
  const int lr = ln & 15;    // MFMA "A row / D col" lane field
  const int lq = ln >> 4;    // 0..3
  const int b0 = blockIdx.x * 16;

  // init xbuf: h0 + prev_norm(default_dof_pos) + zero pad
  for (int i = tid; i < 16 * XPAD; i += 512) {
    int r = i / XPAD, c = i % XPAD;
    float v = 0.f;
    if (c < 256) v = h0[(b0 + r) * 256 + c];
    else if (c < 268) {
      int d = c - 256;
      float lo = jlo[d], hi = jhi[d];
      v = (ddp[d] - 0.5f * (hi + lo)) / (0.5f * (hi - lo));
    }
    xbuf[r][c] = (bf16)v;
  }

  // wave wv owns hidden units [32*wv, 32*wv+32): c-state + zc in regs.
  // mapping: ji in {0,1}: unit u = 32*wv + 16*ji + lr ; batch b = lq*4 + r
  float c_reg[2][4];
  float zc_r[2][4][4];  // [ji][gate][r]
  #pragma unroll
  for (int ji = 0; ji < 2; ++ji) {
    int u = 32 * wv + 16 * ji + lr;
    #pragma unroll
    for (int r = 0; r < 4; ++r) {
      int b = lq * 4 + r;
      c_reg[ji][r] = c0[(b0 + b) * 256 + u];
      #pragma unroll
      for (int g = 0; g < 4; ++g)
        zc_r[ji][g][r] = zc[(b0 + b) * 1024 + g * 256 + u];
    }
  }
  __syncthreads();

  for (int t = 0; t < T_; ++t) {
    // A fragments: x = [h, prev_norm, pad], K=288 (9 k-tiles)
    bf16x8 a[9];
    #pragma unroll
    for (int kt = 0; kt < 9; ++kt)
      a[kt] = *reinterpret_cast<const bf16x8*>(&xbuf[lr][kt * 32 + lq * 8]);
    __syncthreads();  // everyone captured x before h gets overwritten

    #pragma unroll
    for (int ji = 0; ji < 2; ++ji) {
      int u = 32 * wv + 16 * ji + lr;
      f32x4 ac[4];
      #pragma unroll
      for (int g = 0; g < 4; ++g) {
        int n0 = g * 256 + 32 * wv + 16 * ji;
        float tc = tcon[t * 1024 + n0 + lr];
        f32x4 acc;
        acc[0] = zc_r[ji][g][0] + tc;
        acc[1] = zc_r[ji][g][1] + tc;
        acc[2] = zc_r[ji][g][2] + tc;
        acc[3] = zc_r[ji][g][3] + tc;
        #pragma unroll
        for (int kt = 0; kt < 9; ++kt) {
          bf16x8 bfr = *reinterpret_cast<const bf16x8*>(
              &Wcomb[(size_t)(n0 + lr) * XK + kt * 32 + lq * 8]);
          acc = __builtin_amdgcn_mfma_f32_16x16x32_bf16(a[kt], bfr, acc, 0, 0, 0);
        }
        ac[g] = acc;
      }
      // LSTM elementwise fully in-register (lane holds all 4 gates of (b,u))
      #pragma unroll
      for (int r = 0; r < 4; ++r) {
        int b = lq * 4 + r;
        float gi = ac[0][r], gf = ac[1][r], gg = ac[2][r], go = ac[3][r];
        float cn = sigf(gf) * c_reg[ji][r] + sigf(gi) * tanh_f(gg);
        float hn = sigf(go) * tanh_f(cn);
        c_reg[ji][r] = cn;
        bf16 hb = (bf16)hn;
        xbuf[b][u] = hb;
        Hseq[((size_t)(b0 + b) * T_ + t) * 256 + u] = hb;
      }
    }
    __syncthreads();  // new h visible

    // p1 = relu(h @ Wp1^T + bp1), wave owns cols [32wv, 32wv+32)
    bf16x8 ah[8];
    #pragma unroll
    for (int kt = 0; kt < 8; ++kt)
      ah[kt] = *reinterpret_cast<const bf16x8*>(&xbuf[lr][kt * 32 + lq * 8]);
    #pragma unroll
    for (int jn = 0; jn < 2; ++jn) {
      int n0 = 32 * wv + 16 * jn;
      float bb = bp1[n0 + lr];
      f32x4 acc = {bb, bb, bb, bb};
      #pragma unroll
      for (int kt = 0; kt < 8; ++kt) {
        bf16x8 bfr = *reinterpret_cast<const bf16x8*>(
            &Wp1b[(size_t)(n0 + lr) * 256 + kt * 32 + lq * 8]);
        acc = __builtin_amdgcn_mfma_f32_16x16x32_bf16(ah[kt], bfr, acc, 0, 0, 0);
      }
      #pragma unroll
      for (int r = 0; r < 4; ++r)
        p1buf[lq * 4 + r][n0 + lr] = (bf16)fmaxf(acc[r], 0.f);
    }
    __syncthreads();

    // action head on wave 0: act = tanh(p1 @ Wp2^T + bp2)
    if (wv == 0) {
      bf16x8 ap[8];
      #pragma unroll
      for (int kt = 0; kt < 8; ++kt)
        ap[kt] = *reinterpret_cast<const bf16x8*>(&p1buf[lr][kt * 32 + lq * 8]);
      f32x4 acc = {0.f, 0.f, 0.f, 0.f};
      #pragma unroll
      for (int kt = 0; kt < 8; ++kt) {
        bf16x8 bfr = *reinterpret_cast<const bf16x8*>(
            &Wp2b[(size_t)lr * 256 + kt * 32 + lq * 8]);
        acc = __builtin_amdgcn_mfma_f32_16x16x32_bf16(ap[kt], bfr, acc, 0, 0, 0);
      }
      if (lr < 12) {
        float bp = bp2[lr], dd = ddp[lr], lo = jlo[lr], hi = jhi[lr];
        float jm = 0.5f * (hi + lo), jr = 0.5f * (hi - lo);
        #pragma unroll
        for (int r = 0; r < 4; ++r) {
          int b = lq * 4 + r;
          float act = tanh_f(acc[r] + bp);
          float cur = act * 0.25f + dd;      // TRACK_ALPHA = 1
          float cl = fminf(fmaxf(cur, lo), hi);
          size_t o = ((size_t)(b0 + b) * T_ + t) * 12 + lr;
          outA[o] = act;
          outJ[o] = cur;                     // joint_traj = pre-clamp cur
          xbuf[b][256 + lr] = (bf16)((cl - jm) / jr);  // next prev_norm
        }
      }
    }
    __syncthreads();
  }
}

// ------------- post pass: obj head, sigma head, FK, normalize -------------
__global__ __launch_bounds__(256) void k_post(
    const bf16* __restrict__ Hseq, const bf16* __restrict__ Wo1b,
    const bf16* __restrict__ Wo2b, const bf16* __restrict__ Wvb,
    const float* __restrict__ bo1, const float* __restrict__ bo2,
    const float* __restrict__ bv,
    const float* __restrict__ Wfk, const float* __restrict__ bfk,
    const float* __restrict__ pm, const float* __restrict__ ps,
    const float* __restrict__ joints, float* __restrict__ out0,
    float* __restrict__ out3) {
  __shared__ bf16 u1buf[16][P1PAD];
  __shared__ float objbuf[16][3];
  __shared__ float jbuf[16][12];
  const int tid = threadIdx.x;
  const int wv = tid >> 6;
  const int ln = tid & 63;
  const int lr = ln & 15;
  const int lq = ln >> 4;

  for (int it = 0; it < 10; ++it) {
    int tt = blockIdx.x * 10 + it;        // 16-row tile of flattened (b,t)
    size_t r0 = (size_t)tt * 16;
    bf16x8 ah[8];
    #pragma unroll
    for (int kt = 0; kt < 8; ++kt)
      ah[kt] = *reinterpret_cast<const bf16x8*>(&Hseq[(r0 + lr) * 256 + kt * 32 + lq * 8]);
    // u1 = relu(h @ Wo1^T + bo1): wave wv cols [64wv, 64wv+64)
    #pragma unroll
    for (int jn = 0; jn < 4; ++jn) {
      int n0 = wv * 64 + jn * 16;
      float bb = bo1[n0 + lr];
      f32x4 acc = {bb, bb, bb, bb};
      #pragma unroll
      for (int kt = 0; kt < 8; ++kt) {
        bf16x8 bfr = *reinterpret_cast<const bf16x8*>(
            &Wo1b[(size_t)(n0 + lr) * 256 + kt * 32 + lq * 8]);
        acc = __builtin_amdgcn_mfma_f32_16x16x32_bf16(ah[kt], bfr, acc, 0, 0, 0);
      }
      #pragma unroll
      for (int r = 0; r < 4; ++r)
        u1buf[lq * 4 + r][n0 + lr] = (bf16)fmaxf(acc[r], 0.f);
    }
    // sigma head on waves 1..3 (48 cols, 42 valid)
    if (wv >= 1) {
      int col = (wv - 1) * 16 + lr;
      float bb = (col < 42) ? bv[col] : 0.f;
      f32x4 acc = {bb, bb, bb, bb};
      #pragma unroll
      for (int kt = 0; kt < 8; ++kt) {
        bf16x8 bfr = *reinterpret_cast<const bf16x8*>(
            &Wvb[(size_t)col * 256 + kt * 32 + lq * 8]);
        acc = __builtin_amdgcn_mfma_f32_16x16x32_bf16(ah[kt], bfr, acc, 0, 0, 0);
      }
      if (col < 42) {
        #pragma unroll
        for (int r = 0; r < 4; ++r) {
          float s = 0.05f + 0.45f * sigf(acc[r]);
          out3[(r0 + lq * 4 + r) * 42 + col] = __logf(s);
        }
      }
    }
    if (tid < 192) {
      int rr = tid / 12, d = tid % 12;
      jbuf[rr][d] = joints[(r0 + rr) * 12 + d];
    }
    __syncthreads();
    // obj = u1 @ Wo2^T + bo2 on wave 0
    if (wv == 0) {
      bf16x8 ap[8];
      #pragma unroll
      for (int kt = 0; kt < 8; ++kt)
        ap[kt] = *reinterpret_cast<const bf16x8*>(&u1buf[lr][kt * 32 + lq * 8]);
      f32x4 acc = {0.f, 0.f, 0.f, 0.f};
      #pragma unroll
      for (int kt = 0; kt < 8; ++kt) {
        bf16x8 bfr = *reinterpret_cast<const bf16x8*>(
            &Wo2b[(size_t)lr * 256 + kt * 32 + lq * 8]);
        acc = __builtin_amdgcn_mfma_f32_16x16x32_bf16(ap[kt], bfr, acc, 0, 0, 0);
      }
      if (lr < 3) {
        #pragma unroll
        for (int r = 0; r < 4; ++r)
          objbuf[lq * 4 + r][lr] = acc[r] + bo2[lr];
      }
    }
    __syncthreads();
    // graph_x_mu: FK(39) + obj(3), normalized
    for (int e = tid; e < 16 * 42; e += 256) {
      int rr = e / 42, pd = e % 42;
      float v;
      if (pd < 39) {
        float s = bfk[pd];
        #pragma unroll
        for (int d = 0; d < 12; ++d) s += jbuf[rr][d] * Wfk[pd * 12 + d];
        v = s;
      } else v = objbuf[rr][pd - 39];
      out0[(r0 + rr) * 42 + pd] = (v - pm[pd]) / ps[pd];
    }
    __syncthreads();
  }
}

extern "C" void kernel_launch(void* const* d_in, const int* in_sizes, int n_in,
                              void* d_out, int out_size, void* d_ws, size_t ws_size,
                              hipStream_t stream) {
  const float* z   = (const float*)d_in[0];
  const float* Whz = (const float*)d_in[1];
  const float* bhz = (const float*)d_in[2];
  const float* Wcz = (const float*)d_in[3];
  const float* bcz = (const float*)d_in[4];
  const float* Wih = (const float*)d_in[5];
  const float* Whh = (const float*)d_in[6];
  const float* bih = (const float*)d_in[7];
  const float* bhh = (const float*)d_in[8];
  const float* Wp1 = (const float*)d_in[9];
  const float* bp1 = (const float*)d_in[10];
  const float* Wp2 = (const float*)d_in[11];
  const float* bp2 = (const float*)d_in[12];
  const float* Wo1 = (const float*)d_in[13];
  const float* bo1 = (const float*)d_in[14];
  const float* Wo2 = (const float*)d_in[15];
  const float* bo2 = (const float*)d_in[16];
  const float* Wv  = (const float*)d_in[17];
  const float* bv  = (const float*)d_in[18];
  const float* Wfk = (const float*)d_in[19];
  const float* bfk = (const float*)d_in[20];
  const float* pm  = (const float*)d_in[21];
  const float* ps  = (const float*)d_in[22];
  const float* jlo = (const float*)d_in[23];
  const float* jhi = (const float*)d_in[24];
  const float* ddp = (const float*)d_in[25];

  char* ws = (char*)d_ws;
  float* tf   = (float*)(ws + OFF_TF);
  float* tcon = (float*)(ws + OFF_TCON);
  float* zc   = (float*)(ws + OFF_ZC);
  float* h0   = (float*)(ws + OFF_H0);
  float* c0   = (float*)(ws + OFF_C0);
  bf16* Wcomb = (bf16*)(ws + OFF_WCOMB);
  bf16* Wp1b  = (bf16*)(ws + OFF_WP1);
  bf16* Wp2b  = (bf16*)(ws + OFF_WP2);
  bf16* Wo1b  = (bf16*)(ws + OFF_WO1);
  bf16* Wo2b  = (bf16*)(ws + OFF_WO2);
  bf16* Wvb   = (bf16*)(ws + OFF_WV);
  bf16* Hseq  = (bf16*)(ws + OFF_HSEQ);

  float* out  = (float*)d_out;
  float* out0 = out;                 // graph_x_mu [B,T,42]
  float* outJ = out + 2150400;       // joint_traj [B,T,12]
  float* outA = out + 2764800;       // actions    [B,T,12]
  float* out3 = out + 3379200;       // log_sigma  [B,T,42]

  k_tfeat<<<11, 256, 0, stream>>>(tf);
  k_prep<<<2336, 256, 0, stream>>>(tf, Wih, z, bih, bhh, Whz, bhz, Wcz, bcz,
                                   tcon, zc, h0, c0);
  k_cast<<<1744, 256, 0, stream>>>(Whh, Wih, Wp1, Wp2, Wo1, Wo2, Wv,
                                   Wcomb, Wp1b, Wp2b, Wo1b, Wo2b, Wvb);
  k_recur<<<16, 512, 0, stream>>>(zc, tcon, h0, c0, Wcomb, Wp1b, Wp2b,
                                  bp1, bp2, jlo, jhi, ddp, Hseq, outJ, outA);
  k_post<<<320, 256, 0, stream>>>(Hseq, Wo1b, Wo2b, Wvb, bo1, bo2, bv,
                                  Wfk, bfk, pm, ps, outJ, out0, out3);
}

// Round 2
// 3405.937 us; speedup vs baseline: 1.0404x; 1.0404x over previous
//
#include <hip/hip_runtime.h>
#include <math.h>

#define B_ 256
#define T_ 200
#define H_ 256
#define DOF_ 12

typedef __bf16 bf16;
typedef __bf16 bf16x8 __attribute__((ext_vector_type(8)));
typedef float f32x4 __attribute__((ext_vector_type(4)));

#define XK 288      // gate GEMM K: 256 h + 12 prev + 20 zero pad
#define XPAD 296    // xbuf row stride: 592B -> 20-bank shift/row -> 2-way max (free)
#define P1PAD 264

#define PI_D 3.14159265358979323846

// ---- workspace byte offsets (all 16B aligned) ----
#define OFF_TF     0u
#define OFF_TCON   10400u
#define OFF_ZC     829600u
#define OFF_H0     1878176u
#define OFF_C0     2140320u
#define OFF_WCOMB  2402464u
#define OFF_WP1    2992288u
#define OFF_WP2    3123360u
#define OFF_WO1    3131552u
#define OFF_WO2    3262624u
#define OFF_WV     3270816u
#define OFF_HSEQ   3295392u    // 256*200*256*2 = 26214400

__device__ __forceinline__ float sigf(float x) { return 1.f / (1.f + __expf(-x)); }
__device__ __forceinline__ float tanh_f(float x) {
  float a = fabsf(x);
  float e = __expf(-2.f * a);
  float t = (1.f - e) / (1.f + e);
  return x < 0.f ? -t : t;
}

// ---------------- time features [T,13] ----------------
__global__ void k_tfeat(float* tf) {
  int i = blockIdx.x * blockDim.x + threadIdx.x;
  if (i >= T_ * 13) return;
  int t = i / 13, j = i % 13;
  float tv = (float)t / 199.f;
  float v;
  if (j == 0) v = tv;
  else {
    int k = (j - 1) >> 1;
    float f = (float)(1 << k);
    double arg = 2.0 * PI_D * (double)f * (double)tv;
    v = (j & 1) ? (float)sin(arg) : (float)cos(arg);
  }
  tf[i] = v;
}

// ------------- precompute tcon, zc, h0, c0 -------------
__global__ void k_prep(const float* __restrict__ tf, const float* __restrict__ Wih,
                       const float* __restrict__ z,
                       const float* __restrict__ bih, const float* __restrict__ bhh,
                       const float* __restrict__ Whz, const float* __restrict__ bhz,
                       const float* __restrict__ Wcz, const float* __restrict__ bcz,
                       float* tcon, float* zc, float* h0, float* c0) {
  int i = blockIdx.x * blockDim.x + threadIdx.x;
  if (i < 204800) {                      // tcon[t][n] = tf . Wih[:,76:89]
    int t = i / 1024, n = i % 1024;
    float s = 0.f;
    #pragma unroll
    for (int j = 0; j < 13; ++j) s += tf[t * 13 + j] * Wih[n * 89 + 76 + j];
    tcon[i] = s;
    return;
  }
  i -= 204800;
  if (i < 262144) {                      // zc[b][n] = bih+bhh + z . Wih[:,12:76]
    int b = i / 1024, n = i % 1024;
    float s = bih[n] + bhh[n];
    for (int k = 0; k < 64; ++k) s += z[b * 64 + k] * Wih[n * 89 + 12 + k];
    zc[i] = s;
    return;
  }
  i -= 262144;
  if (i < 65536) {                       // h0
    int b = i / 256, u = i % 256;
    float s = bhz[u];
    for (int k = 0; k < 64; ++k) s += z[b * 64 + k] * Whz[u * 64 + k];
    h0[i] = s;
    return;
  }
  i -= 65536;
  if (i < 65536) {                       // c0
    int b = i / 256, u = i % 256;
    float s = bcz[u];
    for (int k = 0; k < 64; ++k) s += z[b * 64 + k] * Wcz[u * 64 + k];
    c0[i] = s;
  }
}

// ------------- bf16 weight casts -------------
__global__ void k_cast(const float* __restrict__ Whh, const float* __restrict__ Wih,
                       const float* __restrict__ Wp1, const float* __restrict__ Wp2,
                       const float* __restrict__ Wo1, const float* __restrict__ Wo2,
                       const float* __restrict__ Wv,
                       bf16* Wcomb, bf16* Wp1b, bf16* Wp2b, bf16* Wo1b,
                       bf16* Wo2b, bf16* Wvb) {
  int i = blockIdx.x * blockDim.x + threadIdx.x;
  if (i < 294912) {                      // Wcomb[n][k]: k<256 Whh, 256..267 Wih prev cols
    int n = i / XK, k = i % XK;
    float v = (k < 256) ? Whh[n * 256 + k]
            : ((k < 268) ? Wih[n * 89 + (k - 256)] : 0.f);
    Wcomb[i] = (bf16)v;
    return;
  }
  i -= 294912;
  if (i < 65536) { Wp1b[i] = (bf16)Wp1[i]; return; }
  i -= 65536;
  if (i < 4096) { int r = i / 256; Wp2b[i] = (bf16)((r < 12) ? Wp2[i] : 0.f); return; }
  i -= 4096;
  if (i < 65536) { Wo1b[i] = (bf16)Wo1[i]; return; }
  i -= 65536;
  if (i < 4096) { int r = i / 256; Wo2b[i] = (bf16)((r < 3) ? Wo2[i] : 0.f); return; }
  i -= 4096;
  if (i < 12288) { int r = i / 256; Wvb[i] = (bf16)((r < 42) ? Wv[i] : 0.f); }
}

// ------------- recurrent LSTM: 16 blocks x 16 batch, 16 waves, reg-resident W ---
__global__ __launch_bounds__(1024) void k_recur(
    const float* __restrict__ zc, const float* __restrict__ tcon,
    const float* __restrict__ h0, const float* __restrict__ c0,
    const bf16* __restrict__ Wcomb, const bf16* __restrict__ Wp1b,
    const bf16* __restrict__ Wp2b,
    const float* __restrict__ bp1, const float* __restrict__ bp2,
    const float* __restrict__ jlo, const float* __restrict__ jhi,
    const float* __restrict__ ddp,
    bf16* __restrict__ Hseq, float* __restrict__ outJ, float* __restrict__ outA) {
  __shared__ bf16 xbuf[2][16][XPAD];  // [dbuf][batch][k]: h(0..255) prev_norm(256..267) pad
  __shared__ bf16 p1buf[16][P1PAD];
  const int tid = threadIdx.x;
  const int wv = tid >> 6;   // 0..15
  const int ln = tid & 63;
  const int lr = ln & 15;    // MFMA A-row / D-col lane field
  const int lq = ln >> 4;    // 0..3
  const int b0 = blockIdx.x * 16;
  const int u  = 16 * wv + lr;   // hidden unit owned by this lane

  // init both xbuf buffers: h0 + prev_norm(default_dof_pos) + zero pad
  for (int i = tid; i < 2 * 16 * XPAD; i += 1024) {
    int bufn = i / (16 * XPAD);
    int rem = i % (16 * XPAD);
    int r = rem / XPAD, c = rem % XPAD;
    float v = 0.f;
    if (c < 256) v = h0[(b0 + r) * 256 + c];
    else if (c < 268) {
      int d = c - 256;
      float lo = jlo[d], hi = jhi[d];
      v = (ddp[d] - 0.5f * (hi + lo)) / (0.5f * (hi - lo));
    }
    xbuf[bufn][r][c] = (bf16)v;
  }

  // ---- weights into registers (constant across all 200 steps) ----
  bf16x8 wc[4][9];     // gate g, k-tile : Wcomb rows g*256+u
  #pragma unroll
  for (int g = 0; g < 4; ++g)
    #pragma unroll
    for (int kt = 0; kt < 9; ++kt)
      wc[g][kt] = *reinterpret_cast<const bf16x8*>(
          &Wcomb[(size_t)(g * 256 + u) * XK + kt * 32 + lq * 8]);
  bf16x8 wp1[8];       // Wp1 row u
  #pragma unroll
  for (int kt = 0; kt < 8; ++kt)
    wp1[kt] = *reinterpret_cast<const bf16x8*>(&Wp1b[(size_t)u * 256 + kt * 32 + lq * 8]);
  bf16x8 w2f[8];       // Wp2 row lr (used by wave 0 only)
  #pragma unroll
  for (int kt = 0; kt < 8; ++kt)
    w2f[kt] = *reinterpret_cast<const bf16x8*>(&Wp2b[(size_t)lr * 256 + kt * 32 + lq * 8]);

  // per-lane state: c and zc for (b = lq*4+r, u)
  float c_reg[4], zc_r[4][4];
  #pragma unroll
  for (int r = 0; r < 4; ++r) {
    int b = lq * 4 + r;
    c_reg[r] = c0[(b0 + b) * 256 + u];
    #pragma unroll
    for (int g = 0; g < 4; ++g) zc_r[g][r] = zc[(b0 + b) * 1024 + g * 256 + u];
  }
  float bp1r = bp1[u];
  float bp2r = 0.f, ddr = 0.f, lor = -1.f, hir = 1.f;
  if (lr < 12) { bp2r = bp2[lr]; ddr = ddp[lr]; lor = jlo[lr]; hir = jhi[lr]; }
  const float jmr = 0.5f * (hir + lor), jrr = 0.5f * (hir - lor);

  float tc[4];
  #pragma unroll
  for (int g = 0; g < 4; ++g) tc[g] = tcon[g * 256 + u];

  __syncthreads();
  int cur = 0;
  for (int t = 0; t < T_; ++t) {
    const int nxt = cur ^ 1;
    float tcn[4];
    if (t < T_ - 1) {
      #pragma unroll
      for (int g = 0; g < 4; ++g) tcn[g] = tcon[(t + 1) * 1024 + g * 256 + u];
    }
    // gates: x = [h, prev_norm, pad] from xbuf[cur], W from registers
    bf16x8 a[9];
    #pragma unroll
    for (int kt = 0; kt < 9; ++kt)
      a[kt] = *reinterpret_cast<const bf16x8*>(&xbuf[cur][lr][kt * 32 + lq * 8]);
    f32x4 ac[4];
    #pragma unroll
    for (int g = 0; g < 4; ++g) {
      f32x4 acc;
      acc[0] = zc_r[g][0] + tc[g];
      acc[1] = zc_r[g][1] + tc[g];
      acc[2] = zc_r[g][2] + tc[g];
      acc[3] = zc_r[g][3] + tc[g];
      #pragma unroll
      for (int kt = 0; kt < 9; ++kt)
        acc = __builtin_amdgcn_mfma_f32_16x16x32_bf16(a[kt], wc[g][kt], acc, 0, 0, 0);
      ac[g] = acc;
    }
    // LSTM elementwise in-register; write h_new into the OTHER buffer
    #pragma unroll
    for (int r = 0; r < 4; ++r) {
      int b = lq * 4 + r;
      float cn = sigf(ac[1][r]) * c_reg[r] + sigf(ac[0][r]) * tanh_f(ac[2][r]);
      float hn = sigf(ac[3][r]) * tanh_f(cn);
      c_reg[r] = cn;
      bf16 hb = (bf16)hn;
      xbuf[nxt][b][u] = hb;
      Hseq[((size_t)(b0 + b) * T_ + t) * 256 + u] = hb;
    }
    __syncthreads();   // h_new visible

    // p1 = relu(h_new @ Wp1^T + bp1): wave owns 16 cols
    bf16x8 ah[8];
    #pragma unroll
    for (int kt = 0; kt < 8; ++kt)
      ah[kt] = *reinterpret_cast<const bf16x8*>(&xbuf[nxt][lr][kt * 32 + lq * 8]);
    {
      f32x4 acc = {bp1r, bp1r, bp1r, bp1r};
      #pragma unroll
      for (int kt = 0; kt < 8; ++kt)
        acc = __builtin_amdgcn_mfma_f32_16x16x32_bf16(ah[kt], wp1[kt], acc, 0, 0, 0);
      #pragma unroll
      for (int r = 0; r < 4; ++r)
        p1buf[lq * 4 + r][u] = (bf16)fmaxf(acc[r], 0.f);
    }
    __syncthreads();   // p1 visible

    // action head on wave 0: act = tanh(p1 @ Wp2^T + bp2); writes next prev_norm
    if (wv == 0) {
      bf16x8 ap[8];
      #pragma unroll
      for (int kt = 0; kt < 8; ++kt)
        ap[kt] = *reinterpret_cast<const bf16x8*>(&p1buf[lr][kt * 32 + lq * 8]);
      f32x4 acc = {0.f, 0.f, 0.f, 0.f};
      #pragma unroll
      for (int kt = 0; kt < 8; ++kt)
        acc = __builtin_amdgcn_mfma_f32_16x16x32_bf16(ap[kt], w2f[kt], acc, 0, 0, 0);
      if (lr < 12) {
        #pragma unroll
        for (int r = 0; r < 4; ++r) {
          int b = lq * 4 + r;
          float act = tanh_f(acc[r] + bp2r);
          float curp = act * 0.25f + ddr;          // TRACK_ALPHA = 1
          float cl = fminf(fmaxf(curp, lor), hir);
          size_t o = ((size_t)(b0 + b) * T_ + t) * 12 + lr;
          outA[o] = act;
          outJ[o] = curp;
          xbuf[nxt][b][256 + lr] = (bf16)((cl - jmr) / jrr);
        }
      }
    }
    __syncthreads();   // prev_norm visible for next step
    #pragma unroll
    for (int g = 0; g < 4; ++g) if (t < T_ - 1) tc[g] = tcn[g];
    cur = nxt;
  }
}

// ------------- post pass: obj head, sigma head, FK, normalize -------------
__global__ __launch_bounds__(256) void k_post(
    const bf16* __restrict__ Hseq, const bf16* __restrict__ Wo1b,
    const bf16* __restrict__ Wo2b, const bf16* __restrict__ Wvb,
    const float* __restrict__ bo1, const float* __restrict__ bo2,
    const float* __restrict__ bv,
    const float* __restrict__ Wfk, const float* __restrict__ bfk,
    const float* __restrict__ pm, const float* __restrict__ ps,
    const float* __restrict__ joints, float* __restrict__ out0,
    float* __restrict__ out3) {
  __shared__ bf16 u1buf[16][P1PAD];
  __shared__ float objbuf[16][3];
  __shared__ float jbuf[16][12];
  const int tid = threadIdx.x;
  const int wv = tid >> 6;
  const int ln = tid & 63;
  const int lr = ln & 15;
  const int lq = ln >> 4;

  // ---- hoisted weights (constant across tiles) ----
  bf16x8 wo1f[4][8];
  float bo1r[4];
  #pragma unroll
  for (int jn = 0; jn < 4; ++jn) {
    int n0 = wv * 64 + jn * 16;
    bo1r[jn] = bo1[n0 + lr];
    #pragma unroll
    for (int kt = 0; kt < 8; ++kt)
      wo1f[jn][kt] = *reinterpret_cast<const bf16x8*>(
          &Wo1b[(size_t)(n0 + lr) * 256 + kt * 32 + lq * 8]);
  }
  const int col = (wv - 1) * 16 + lr;   // sigma col for wv>=1
  bf16x8 wvf[8];
  float bvr = 0.f;
  if (wv >= 1) {
    #pragma unroll
    for (int kt = 0; kt < 8; ++kt)
      wvf[kt] = *reinterpret_cast<const bf16x8*>(
          &Wvb[(size_t)col * 256 + kt * 32 + lq * 8]);
    bvr = (col < 42) ? bv[col] : 0.f;
  }
  bf16x8 wo2f[8];
  if (wv == 0) {
    #pragma unroll
    for (int kt = 0; kt < 8; ++kt)
      wo2f[kt] = *reinterpret_cast<const bf16x8*>(
          &Wo2b[(size_t)lr * 256 + kt * 32 + lq * 8]);
  }

  for (int it = 0; it < 10; ++it) {
    int tt = blockIdx.x * 10 + it;        // 16-row tile of flattened (b,t)
    size_t r0 = (size_t)tt * 16;
    bf16x8 ah[8];
    #pragma unroll
    for (int kt = 0; kt < 8; ++kt)
      ah[kt] = *reinterpret_cast<const bf16x8*>(&Hseq[(r0 + lr) * 256 + kt * 32 + lq * 8]);
    // u1 = relu(h @ Wo1^T + bo1): wave wv cols [64wv, 64wv+64)
    #pragma unroll
    for (int jn = 0; jn < 4; ++jn) {
      int n0 = wv * 64 + jn * 16;
      float bb = bo1r[jn];
      f32x4 acc = {bb, bb, bb, bb};
      #pragma unroll
      for (int kt = 0; kt < 8; ++kt)
        acc = __builtin_amdgcn_mfma_f32_16x16x32_bf16(ah[kt], wo1f[jn][kt], acc, 0, 0, 0);
      #pragma unroll
      for (int r = 0; r < 4; ++r)
        u1buf[lq * 4 + r][n0 + lr] = (bf16)fmaxf(acc[r], 0.f);
    }
    // sigma head on waves 1..3 (48 cols, 42 valid)
    if (wv >= 1) {
      f32x4 acc = {bvr, bvr, bvr, bvr};
      #pragma unroll
      for (int kt = 0; kt < 8; ++kt)
        acc = __builtin_amdgcn_mfma_f32_16x16x32_bf16(ah[kt], wvf[kt], acc, 0, 0, 0);
      if (col < 42) {
        #pragma unroll
        for (int r = 0; r < 4; ++r) {
          float s = 0.05f + 0.45f * sigf(acc[r]);
          out3[(r0 + lq * 4 + r) * 42 + col] = __logf(s);
        }
      }
    }
    if (tid < 192) {
      int rr = tid / 12, d = tid % 12;
      jbuf[rr][d] = joints[(r0 + rr) * 12 + d];
    }
    __syncthreads();
    // obj = u1 @ Wo2^T + bo2 on wave 0
    if (wv == 0) {
      bf16x8 ap[8];
      #pragma unroll
      for (int kt = 0; kt < 8; ++kt)
        ap[kt] = *reinterpret_cast<const bf16x8*>(&u1buf[lr][kt * 32 + lq * 8]);
      f32x4 acc = {0.f, 0.f, 0.f, 0.f};
      #pragma unroll
      for (int kt = 0; kt < 8; ++kt)
        acc = __builtin_amdgcn_mfma_f32_16x16x32_bf16(ap[kt], wo2f[kt], acc, 0, 0, 0);
      if (lr < 3) {
        #pragma unroll
        for (int r = 0; r < 4; ++r)
          objbuf[lq * 4 + r][lr] = acc[r] + bo2[lr];
      }
    }
    __syncthreads();
    // graph_x_mu: FK(39) + obj(3), normalized
    for (int e = tid; e < 16 * 42; e += 256) {
      int rr = e / 42, pd = e % 42;
      float v;
      if (pd < 39) {
        float s = bfk[pd];
        #pragma unroll
        for (int d = 0; d < 12; ++d) s += jbuf[rr][d] * Wfk[pd * 12 + d];
        v = s;
      } else v = objbuf[rr][pd - 39];
      out0[(r0 + rr) * 42 + pd] = (v - pm[pd]) / ps[pd];
    }
    __syncthreads();
  }
}

extern "C" void kernel_launch(void* const* d_in, const int* in_sizes, int n_in,
                              void* d_out, int out_size, void* d_ws, size_t ws_size,
                              hipStream_t stream) {
  const float* z   = (const float*)d_in[0];
  const float* Whz = (const float*)d_in[1];
  const float* bhz = (const float*)d_in[2];
  const float* Wcz = (const float*)d_in[3];
  const float* bcz = (const float*)d_in[4];
  const float* Wih = (const float*)d_in[5];
  const float* Whh = (const float*)d_in[6];
  const float* bih = (const float*)d_in[7];
  const float* bhh = (const float*)d_in[8];
  const float* Wp1 = (const float*)d_in[9];
  const float* bp1 = (const float*)d_in[10];
  const float* Wp2 = (const float*)d_in[11];
  const float* bp2 = (const float*)d_in[12];
  const float* Wo1 = (const float*)d_in[13];
  const float* bo1 = (const float*)d_in[14];
  const float* Wo2 = (const float*)d_in[15];
  const float* bo2 = (const float*)d_in[16];
  const float* Wv  = (const float*)d_in[17];
  const float* bv  = (const float*)d_in[18];
  const float* Wfk = (const float*)d_in[19];
  const float* bfk = (const float*)d_in[20];
  const float* pm  = (const float*)d_in[21];
  const float* ps  = (const float*)d_in[22];
  const float* jlo = (const float*)d_in[23];
  const float* jhi = (const float*)d_in[24];
  const float* ddp = (const float*)d_in[25];

  char* ws = (char*)d_ws;
  float* tf   = (float*)(ws + OFF_TF);
  float* tcon = (float*)(ws + OFF_TCON);
  float* zc   = (float*)(ws + OFF_ZC);
  float* h0   = (float*)(ws + OFF_H0);
  float* c0   = (float*)(ws + OFF_C0);
  bf16* Wcomb = (bf16*)(ws + OFF_WCOMB);
  bf16* Wp1b  = (bf16*)(ws + OFF_WP1);
  bf16* Wp2b  = (bf16*)(ws + OFF_WP2);
  bf16* Wo1b  = (bf16*)(ws + OFF_WO1);
  bf16* Wo2b  = (bf16*)(ws + OFF_WO2);
  bf16* Wvb   = (bf16*)(ws + OFF_WV);
  bf16* Hseq  = (bf16*)(ws + OFF_HSEQ);

  float* out  = (float*)d_out;
  float* out0 = out;                 // graph_x_mu [B,T,42]
  float* outJ = out + 2150400;       // joint_traj [B,T,12]
  float* outA = out + 2764800;       // actions    [B,T,12]
  float* out3 = out + 3379200;       // log_sigma  [B,T,42]

  k_tfeat<<<11, 256, 0, stream>>>(tf);
  k_prep<<<2336, 256, 0, stream>>>(tf, Wih, z, bih, bhh, Whz, bhz, Wcz, bcz,
                                   tcon, zc, h0, c0);
  k_cast<<<1744, 256, 0, stream>>>(Whh, Wih, Wp1, Wp2, Wo1, Wo2, Wv,
                                   Wcomb, Wp1b, Wp2b, Wo1b, Wo2b, Wvb);
  k_recur<<<16, 1024, 0, stream>>>(zc, tcon, h0, c0, Wcomb, Wp1b, Wp2b,
                                   bp1, bp2, jlo, jhi, ddp, Hseq, outJ, outA);
  k_post<<<320, 256, 0, stream>>>(Hseq, Wo1b, Wo2b, Wvb, bo1, bo2, bv,
                                  Wfk, bfk, pm, ps, outJ, out0, out3);
}

// Round 3
// 3126.165 us; speedup vs baseline: 1.1335x; 1.0895x over previous
//
#include <hip/hip_runtime.h>
#include <math.h>

#define B_ 256
#define T_ 200
#define H_ 256
#define DOF_ 12

typedef __bf16 bf16;
typedef __bf16 bf16x8 __attribute__((ext_vector_type(8)));
typedef float f32x4 __attribute__((ext_vector_type(4)));

#define XK 288      // gate GEMM K: 256 h + 12 prev + 20 zero pad
#define XPAD 296    // xbuf row stride: 592B -> 20-bank shift/row -> 2-way max (free)
#define P1PAD 264

#define PI_D 3.14159265358979323846

// ---- workspace byte offsets (all 16B aligned) ----
#define OFF_TF     0u
#define OFF_TCON   10400u
#define OFF_ZC     829600u
#define OFF_H0     1878176u
#define OFF_C0     2140320u
#define OFF_WCOMB  2402464u
#define OFF_WP1    2992288u
#define OFF_WP2    3123360u
#define OFF_WO1    3131552u
#define OFF_WO2    3262624u
#define OFF_WV     3270816u
#define OFF_HSEQ   3295392u    // 256*200*256*2 = 26214400

__device__ __forceinline__ float sigf(float x) { return 1.f / (1.f + __expf(-x)); }
__device__ __forceinline__ float tanh_f(float x) {
  float a = fabsf(x);
  float e = __expf(-2.f * a);
  float t = (1.f - e) / (1.f + e);
  return x < 0.f ? -t : t;
}

// light barrier: order LDS, leave global loads/stores in flight
#define LBAR() asm volatile("s_waitcnt lgkmcnt(0)\n\ts_barrier" ::: "memory")

// ---------------- time features [T,13] ----------------
__global__ void k_tfeat(float* tf) {
  int i = blockIdx.x * blockDim.x + threadIdx.x;
  if (i >= T_ * 13) return;
  int t = i / 13, j = i % 13;
  float tv = (float)t / 199.f;
  float v;
  if (j == 0) v = tv;
  else {
    int k = (j - 1) >> 1;
    float f = (float)(1 << k);
    double arg = 2.0 * PI_D * (double)f * (double)tv;
    v = (j & 1) ? (float)sin(arg) : (float)cos(arg);
  }
  tf[i] = v;
}

// ------------- precompute tcon, zc, h0, c0 -------------
__global__ void k_prep(const float* __restrict__ tf, const float* __restrict__ Wih,
                       const float* __restrict__ z,
                       const float* __restrict__ bih, const float* __restrict__ bhh,
                       const float* __restrict__ Whz, const float* __restrict__ bhz,
                       const float* __restrict__ Wcz, const float* __restrict__ bcz,
                       float* tcon, float* zc, float* h0, float* c0) {
  int i = blockIdx.x * blockDim.x + threadIdx.x;
  if (i < 204800) {
    int t = i / 1024, n = i % 1024;
    float s = 0.f;
    #pragma unroll
    for (int j = 0; j < 13; ++j) s += tf[t * 13 + j] * Wih[n * 89 + 76 + j];
    tcon[i] = s;
    return;
  }
  i -= 204800;
  if (i < 262144) {
    int b = i / 1024, n = i % 1024;
    float s = bih[n] + bhh[n];
    for (int k = 0; k < 64; ++k) s += z[b * 64 + k] * Wih[n * 89 + 12 + k];
    zc[i] = s;
    return;
  }
  i -= 262144;
  if (i < 65536) {
    int b = i / 256, u = i % 256;
    float s = bhz[u];
    for (int k = 0; k < 64; ++k) s += z[b * 64 + k] * Whz[u * 64 + k];
    h0[i] = s;
    return;
  }
  i -= 65536;
  if (i < 65536) {
    int b = i / 256, u = i % 256;
    float s = bcz[u];
    for (int k = 0; k < 64; ++k) s += z[b * 64 + k] * Wcz[u * 64 + k];
    c0[i] = s;
  }
}

// ------------- bf16 weight casts -------------
__global__ void k_cast(const float* __restrict__ Whh, const float* __restrict__ Wih,
                       const float* __restrict__ Wp1, const float* __restrict__ Wp2,
                       const float* __restrict__ Wo1, const float* __restrict__ Wo2,
                       const float* __restrict__ Wv,
                       bf16* Wcomb, bf16* Wp1b, bf16* Wp2b, bf16* Wo1b,
                       bf16* Wo2b, bf16* Wvb) {
  int i = blockIdx.x * blockDim.x + threadIdx.x;
  if (i < 294912) {
    int n = i / XK, k = i % XK;
    float v = (k < 256) ? Whh[n * 256 + k]
            : ((k < 268) ? Wih[n * 89 + (k - 256)] : 0.f);
    Wcomb[i] = (bf16)v;
    return;
  }
  i -= 294912;
  if (i < 65536) { Wp1b[i] = (bf16)Wp1[i]; return; }
  i -= 65536;
  if (i < 4096) { int r = i / 256; Wp2b[i] = (bf16)((r < 12) ? Wp2[i] : 0.f); return; }
  i -= 4096;
  if (i < 65536) { Wo1b[i] = (bf16)Wo1[i]; return; }
  i -= 65536;
  if (i < 4096) { int r = i / 256; Wo2b[i] = (bf16)((r < 3) ? Wo2[i] : 0.f); return; }
  i -= 4096;
  if (i < 12288) { int r = i / 256; Wvb[i] = (bf16)((r < 42) ? Wv[i] : 0.f); }
}

// ------- recurrent LSTM: 16 blocks x 16 batch, 8 waves, dbuf-streamed W -------
// wave wv owns units u = 32*wv + 16*ji + lr (ji=0,1); batch b = lq*4 + r.
__global__ __launch_bounds__(512, 2) void k_recur(
    const float* __restrict__ zc, const float* __restrict__ tcon,
    const float* __restrict__ h0, const float* __restrict__ c0,
    const bf16* __restrict__ Wcomb, const bf16* __restrict__ Wp1b,
    const bf16* __restrict__ Wp2b,
    const float* __restrict__ bp1, const float* __restrict__ bp2,
    const float* __restrict__ jlo, const float* __restrict__ jhi,
    const float* __restrict__ ddp,
    bf16* __restrict__ Hseq, float* __restrict__ outJ, float* __restrict__ outA) {
  __shared__ bf16 xbuf[2][16][XPAD];
  __shared__ bf16 p1buf[16][P1PAD];
  __shared__ bf16 w2lds[16][P1PAD];
  const int tid = threadIdx.x;
  const int wv = tid >> 6;   // 0..7
  const int ln = tid & 63;
  const int lr = ln & 15;
  const int lq = ln >> 4;
  const int b0 = blockIdx.x * 16;

  // init xbuf (both buffers) + w2lds
  for (int i = tid; i < 2 * 16 * XPAD; i += 512) {
    int bufn = i / (16 * XPAD);
    int rem = i % (16 * XPAD);
    int r = rem / XPAD, c = rem % XPAD;
    float v = 0.f;
    if (c < 256) v = h0[(b0 + r) * 256 + c];
    else if (c < 268) {
      int d = c - 256;
      float lo = jlo[d], hi = jhi[d];
      v = (ddp[d] - 0.5f * (hi + lo)) / (0.5f * (hi - lo));
    }
    xbuf[bufn][r][c] = (bf16)v;
  }
  for (int i = tid; i < 16 * 256; i += 512) {
    int r = i >> 8, k = i & 255;
    w2lds[r][k] = Wp2b[i];
  }
  __syncthreads();

  // per-lane state
  float c_reg[2][4], zc_r[2][4][4];
  #pragma unroll
  for (int ji = 0; ji < 2; ++ji) {
    int u = 32 * wv + 16 * ji + lr;
    #pragma unroll
    for (int r = 0; r < 4; ++r) {
      int b = lq * 4 + r;
      c_reg[ji][r] = c0[(b0 + b) * 256 + u];
      #pragma unroll
      for (int g = 0; g < 4; ++g) zc_r[ji][g][r] = zc[(b0 + b) * 1024 + g * 256 + u];
    }
  }
  float tc[2][4];
  #pragma unroll
  for (int ji = 0; ji < 2; ++ji)
    #pragma unroll
    for (int g = 0; g < 4; ++g) tc[ji][g] = tcon[g * 256 + 32 * wv + 16 * ji + lr];
  const float bp1r0 = bp1[32 * wv + lr];
  const float bp1r1 = bp1[32 * wv + 16 + lr];
  float bp2r = 0.f, ddr = 0.f, lor = -1.f, hir = 1.f;
  if (lr < 12) { bp2r = bp2[lr]; ddr = ddp[lr]; lor = jlo[lr]; hir = jhi[lr]; }
  const float jmr = 0.5f * (hir + lor), jrr = 0.5f * (hir - lor);

  // weight-row bases
  const int r00 = 32 * wv + lr;        // ji0 unit row within a gate block
  const int r16 = r00 + 16;            // ji1

  bf16x8 bufA[9], bufB[9];
  // prologue: G0 = (ji0, gate0)
  #pragma unroll
  for (int kt = 0; kt < 9; ++kt)
    bufA[kt] = *reinterpret_cast<const bf16x8*>(&Wcomb[(size_t)r00 * XK + kt * 32 + lq * 8]);

#define LDW9(buf, row)                                                         \
  _Pragma("unroll") for (int kt = 0; kt < 9; ++kt)                             \
    buf[kt] = *reinterpret_cast<const bf16x8*>(                                \
        &Wcomb[(size_t)(row) * XK + kt * 32 + lq * 8]);
#define LDP8(buf, row)                                                         \
  _Pragma("unroll") for (int kt = 0; kt < 8; ++kt)                             \
    buf[kt] = *reinterpret_cast<const bf16x8*>(                                \
        &Wp1b[(size_t)(row) * 256 + kt * 32 + lq * 8]);
#define MM9(accv, buf)                                                         \
  _Pragma("unroll") for (int kt = 0; kt < 9; ++kt)                             \
    accv = __builtin_amdgcn_mfma_f32_16x16x32_bf16(a[kt], buf[kt], accv, 0, 0, 0);

  for (int t = 0; t < T_; ++t) {
    const int cur = t & 1, nxt = cur ^ 1;
    // A-fragments for x_t (read once, used by all 8 gate groups)
    bf16x8 a[9];
    #pragma unroll
    for (int kt = 0; kt < 9; ++kt)
      a[kt] = *reinterpret_cast<const bf16x8*>(&xbuf[cur][lr][kt * 32 + lq * 8]);

    f32x4 ac[2][4];
    #pragma unroll
    for (int ji = 0; ji < 2; ++ji)
      #pragma unroll
      for (int g = 0; g < 4; ++g) {
        ac[ji][g][0] = zc_r[ji][g][0] + tc[ji][g];
        ac[ji][g][1] = zc_r[ji][g][1] + tc[ji][g];
        ac[ji][g][2] = zc_r[ji][g][2] + tc[ji][g];
        ac[ji][g][3] = zc_r[ji][g][3] + tc[ji][g];
      }

    // 8 gate groups, one-ahead double-buffered weight stream
    LDW9(bufB, 256 + r00);  MM9(ac[0][0], bufA);   // G1 in, G0 compute
    LDW9(bufA, 512 + r00);  MM9(ac[0][1], bufB);
    LDW9(bufB, 768 + r00);  MM9(ac[0][2], bufA);
    LDW9(bufA, r16);        MM9(ac[0][3], bufB);
    LDW9(bufB, 256 + r16);  MM9(ac[1][0], bufA);
    LDW9(bufA, 512 + r16);  MM9(ac[1][1], bufB);
    LDW9(bufB, 768 + r16);  MM9(ac[1][2], bufA);
    LDP8(bufA, r00);        MM9(ac[1][3], bufB);   // Wp1 jn0 in
    LDP8(bufB, r16);                               // Wp1 jn1 in

    // LSTM elementwise; h_new -> xbuf[nxt] + Hseq
    #pragma unroll
    for (int ji = 0; ji < 2; ++ji) {
      int u = 32 * wv + 16 * ji + lr;
      #pragma unroll
      for (int r = 0; r < 4; ++r) {
        int b = lq * 4 + r;
        float cn = sigf(ac[ji][1][r]) * c_reg[ji][r] + sigf(ac[ji][0][r]) * tanh_f(ac[ji][2][r]);
        float hn = sigf(ac[ji][3][r]) * tanh_f(cn);
        c_reg[ji][r] = cn;
        bf16 hb = (bf16)hn;
        xbuf[nxt][b][u] = hb;
        Hseq[((size_t)(b0 + b) * T_ + t) * 256 + u] = hb;
      }
    }
    LBAR();  // h_new visible; weight loads stay in flight

    bf16x8 ah[8];
    #pragma unroll
    for (int kt = 0; kt < 8; ++kt)
      ah[kt] = *reinterpret_cast<const bf16x8*>(&xbuf[nxt][lr][kt * 32 + lq * 8]);
    // prefetch next step's tcon
    float tcn[2][4];
    {
      int tp = (t < T_ - 1) ? t + 1 : t;
      #pragma unroll
      for (int ji = 0; ji < 2; ++ji)
        #pragma unroll
        for (int g = 0; g < 4; ++g)
          tcn[ji][g] = tcon[tp * 1024 + g * 256 + 32 * wv + 16 * ji + lr];
    }
    // p1 jn0 (weights in bufA)
    {
      f32x4 acc = {bp1r0, bp1r0, bp1r0, bp1r0};
      #pragma unroll
      for (int kt = 0; kt < 8; ++kt)
        acc = __builtin_amdgcn_mfma_f32_16x16x32_bf16(ah[kt], bufA[kt], acc, 0, 0, 0);
      #pragma unroll
      for (int r = 0; r < 4; ++r)
        p1buf[lq * 4 + r][32 * wv + lr] = (bf16)fmaxf(acc[r], 0.f);
    }
    // prefetch next step's G0 into bufA (survives barriers)
    LDW9(bufA, r00);
    // p1 jn1 (weights in bufB)
    {
      f32x4 acc = {bp1r1, bp1r1, bp1r1, bp1r1};
      #pragma unroll
      for (int kt = 0; kt < 8; ++kt)
        acc = __builtin_amdgcn_mfma_f32_16x16x32_bf16(ah[kt], bufB[kt], acc, 0, 0, 0);
      #pragma unroll
      for (int r = 0; r < 4; ++r)
        p1buf[lq * 4 + r][32 * wv + 16 + lr] = (bf16)fmaxf(acc[r], 0.f);
    }
    LBAR();  // p1 visible

    // action head on wave 0
    if (wv == 0) {
      bf16x8 ap[8], w2[8];
      #pragma unroll
      for (int kt = 0; kt < 8; ++kt) {
        ap[kt] = *reinterpret_cast<const bf16x8*>(&p1buf[lr][kt * 32 + lq * 8]);
        w2[kt] = *reinterpret_cast<const bf16x8*>(&w2lds[lr][kt * 32 + lq * 8]);
      }
      f32x4 acc = {0.f, 0.f, 0.f, 0.f};
      #pragma unroll
      for (int kt = 0; kt < 8; ++kt)
        acc = __builtin_amdgcn_mfma_f32_16x16x32_bf16(ap[kt], w2[kt], acc, 0, 0, 0);
      if (lr < 12) {
        #pragma unroll
        for (int r = 0; r < 4; ++r) {
          int b = lq * 4 + r;
          float act = tanh_f(acc[r] + bp2r);
          float curp = act * 0.25f + ddr;
          float cl = fminf(fmaxf(curp, lor), hir);
          size_t o = ((size_t)(b0 + b) * T_ + t) * 12 + lr;
          outA[o] = act;
          outJ[o] = curp;
          xbuf[nxt][b][256 + lr] = (bf16)((cl - jmr) / jrr);
        }
      }
    }
    LBAR();  // prev_norm visible
    #pragma unroll
    for (int ji = 0; ji < 2; ++ji)
      #pragma unroll
      for (int g = 0; g < 4; ++g) tc[ji][g] = tcn[ji][g];
  }
#undef LDW9
#undef LDP8
#undef MM9
}

// ------------- post pass: obj head, sigma head, FK, normalize -------------
__global__ __launch_bounds__(256) void k_post(
    const bf16* __restrict__ Hseq, const bf16* __restrict__ Wo1b,
    const bf16* __restrict__ Wo2b, const bf16* __restrict__ Wvb,
    const float* __restrict__ bo1, const float* __restrict__ bo2,
    const float* __restrict__ bv,
    const float* __restrict__ Wfk, const float* __restrict__ bfk,
    const float* __restrict__ pm, const float* __restrict__ ps,
    const float* __restrict__ joints, float* __restrict__ out0,
    float* __restrict__ out3) {
  __shared__ bf16 u1buf[16][P1PAD];
  __shared__ float objbuf[16][3];
  __shared__ float jbuf[16][12];
  const int tid = threadIdx.x;
  const int wv = tid >> 6;
  const int ln = tid & 63;
  const int lr = ln & 15;
  const int lq = ln >> 4;

  bf16x8 wo1f[4][8];
  float bo1r[4];
  #pragma unroll
  for (int jn = 0; jn < 4; ++jn) {
    int n0 = wv * 64 + jn * 16;
    bo1r[jn] = bo1[n0 + lr];
    #pragma unroll
    for (int kt = 0; kt < 8; ++kt)
      wo1f[jn][kt] = *reinterpret_cast<const bf16x8*>(
          &Wo1b[(size_t)(n0 + lr) * 256 + kt * 32 + lq * 8]);
  }
  const int col = (wv - 1) * 16 + lr;
  bf16x8 wvf[8];
  float bvr = 0.f;
  if (wv >= 1) {
    #pragma unroll
    for (int kt = 0; kt < 8; ++kt)
      wvf[kt] = *reinterpret_cast<const bf16x8*>(
          &Wvb[(size_t)col * 256 + kt * 32 + lq * 8]);
    bvr = (col < 42) ? bv[col] : 0.f;
  }
  bf16x8 wo2f[8];
  if (wv == 0) {
    #pragma unroll
    for (int kt = 0; kt < 8; ++kt)
      wo2f[kt] = *reinterpret_cast<const bf16x8*>(
          &Wo2b[(size_t)lr * 256 + kt * 32 + lq * 8]);
  }

  for (int it = 0; it < 10; ++it) {
    int tt = blockIdx.x * 10 + it;
    size_t r0 = (size_t)tt * 16;
    bf16x8 ah[8];
    #pragma unroll
    for (int kt = 0; kt < 8; ++kt)
      ah[kt] = *reinterpret_cast<const bf16x8*>(&Hseq[(r0 + lr) * 256 + kt * 32 + lq * 8]);
    #pragma unroll
    for (int jn = 0; jn < 4; ++jn) {
      int n0 = wv * 64 + jn * 16;
      float bb = bo1r[jn];
      f32x4 acc = {bb, bb, bb, bb};
      #pragma unroll
      for (int kt = 0; kt < 8; ++kt)
        acc = __builtin_amdgcn_mfma_f32_16x16x32_bf16(ah[kt], wo1f[jn][kt], acc, 0, 0, 0);
      #pragma unroll
      for (int r = 0; r < 4; ++r)
        u1buf[lq * 4 + r][n0 + lr] = (bf16)fmaxf(acc[r], 0.f);
    }
    if (wv >= 1) {
      f32x4 acc = {bvr, bvr, bvr, bvr};
      #pragma unroll
      for (int kt = 0; kt < 8; ++kt)
        acc = __builtin_amdgcn_mfma_f32_16x16x32_bf16(ah[kt], wvf[kt], acc, 0, 0, 0);
      if (col < 42) {
        #pragma unroll
        for (int r = 0; r < 4; ++r) {
          float s = 0.05f + 0.45f * sigf(acc[r]);
          out3[(r0 + lq * 4 + r) * 42 + col] = __logf(s);
        }
      }
    }
    if (tid < 192) {
      int rr = tid / 12, d = tid % 12;
      jbuf[rr][d] = joints[(r0 + rr) * 12 + d];
    }
    __syncthreads();
    if (wv == 0) {
      bf16x8 ap[8];
      #pragma unroll
      for (int kt = 0; kt < 8; ++kt)
        ap[kt] = *reinterpret_cast<const bf16x8*>(&u1buf[lr][kt * 32 + lq * 8]);
      f32x4 acc = {0.f, 0.f, 0.f, 0.f};
      #pragma unroll
      for (int kt = 0; kt < 8; ++kt)
        acc = __builtin_amdgcn_mfma_f32_16x16x32_bf16(ap[kt], wo2f[kt], acc, 0, 0, 0);
      if (lr < 3) {
        #pragma unroll
        for (int r = 0; r < 4; ++r)
          objbuf[lq * 4 + r][lr] = acc[r] + bo2[lr];
      }
    }
    __syncthreads();
    for (int e = tid; e < 16 * 42; e += 256) {
      int rr = e / 42, pd = e % 42;
      float v;
      if (pd < 39) {
        float s = bfk[pd];
        #pragma unroll
        for (int d = 0; d < 12; ++d) s += jbuf[rr][d] * Wfk[pd * 12 + d];
        v = s;
      } else v = objbuf[rr][pd - 39];
      out0[(r0 + rr) * 42 + pd] = (v - pm[pd]) / ps[pd];
    }
    __syncthreads();
  }
}

extern "C" void kernel_launch(void* const* d_in, const int* in_sizes, int n_in,
                              void* d_out, int out_size, void* d_ws, size_t ws_size,
                              hipStream_t stream) {
  const float* z   = (const float*)d_in[0];
  const float* Whz = (const float*)d_in[1];
  const float* bhz = (const float*)d_in[2];
  const float* Wcz = (const float*)d_in[3];
  const float* bcz = (const float*)d_in[4];
  const float* Wih = (const float*)d_in[5];
  const float* Whh = (const float*)d_in[6];
  const float* bih = (const float*)d_in[7];
  const float* bhh = (const float*)d_in[8];
  const float* Wp1 = (const float*)d_in[9];
  const float* bp1 = (const float*)d_in[10];
  const float* Wp2 = (const float*)d_in[11];
  const float* bp2 = (const float*)d_in[12];
  const float* Wo1 = (const float*)d_in[13];
  const float* bo1 = (const float*)d_in[14];
  const float* Wo2 = (const float*)d_in[15];
  const float* bo2 = (const float*)d_in[16];
  const float* Wv  = (const float*)d_in[17];
  const float* bv  = (const float*)d_in[18];
  const float* Wfk = (const float*)d_in[19];
  const float* bfk = (const float*)d_in[20];
  const float* pm  = (const float*)d_in[21];
  const float* ps  = (const float*)d_in[22];
  const float* jlo = (const float*)d_in[23];
  const float* jhi = (const float*)d_in[24];
  const float* ddp = (const float*)d_in[25];

  char* ws = (char*)d_ws;
  float* tf   = (float*)(ws + OFF_TF);
  float* tcon = (float*)(ws + OFF_TCON);
  float* zc   = (float*)(ws + OFF_ZC);
  float* h0   = (float*)(ws + OFF_H0);
  float* c0   = (float*)(ws + OFF_C0);
  bf16* Wcomb = (bf16*)(ws + OFF_WCOMB);
  bf16* Wp1b  = (bf16*)(ws + OFF_WP1);
  bf16* Wp2b  = (bf16*)(ws + OFF_WP2);
  bf16* Wo1b  = (bf16*)(ws + OFF_WO1);
  bf16* Wo2b  = (bf16*)(ws + OFF_WO2);
  bf16* Wvb   = (bf16*)(ws + OFF_WV);
  bf16* Hseq  = (bf16*)(ws + OFF_HSEQ);

  float* out  = (float*)d_out;
  float* out0 = out;                 // graph_x_mu [B,T,42]
  float* outJ = out + 2150400;       // joint_traj [B,T,12]
  float* outA = out + 2764800;       // actions    [B,T,12]
  float* out3 = out + 3379200;       // log_sigma  [B,T,42]

  k_tfeat<<<11, 256, 0, stream>>>(tf);
  k_prep<<<2336, 256, 0, stream>>>(tf, Wih, z, bih, bhh, Whz, bhz, Wcz, bcz,
                                   tcon, zc, h0, c0);
  k_cast<<<1744, 256, 0, stream>>>(Whh, Wih, Wp1, Wp2, Wo1, Wo2, Wv,
                                   Wcomb, Wp1b, Wp2b, Wo1b, Wo2b, Wvb);
  k_recur<<<16, 512, 0, stream>>>(zc, tcon, h0, c0, Wcomb, Wp1b, Wp2b,
                                  bp1, bp2, jlo, jhi, ddp, Hseq, outJ, outA);
  k_post<<<320, 256, 0, stream>>>(Hseq, Wo1b, Wo2b, Wvb, bo1, bo2, bv,
                                  Wfk, bfk, pm, ps, outJ, out0, out3);
}

// Round 5
// 1767.082 us; speedup vs baseline: 2.0053x; 1.7691x over previous
//
#include <hip/hip_runtime.h>
#include <math.h>

#define B_ 256
#define T_ 200
#define H_ 256
#define DOF_ 12

typedef __bf16 bf16;
typedef __bf16 bf16x8 __attribute__((ext_vector_type(8)));
typedef float f32x4 __attribute__((ext_vector_type(4)));

#define XK 288      // gate GEMM K: 256 h + 12 prev + 20 zero pad
#define XPAD 296    // 592B row stride: 16B-aligned, 2-way bank max
#define P1PAD 264   // 528B row stride

#define PI_D 3.14159265358979323846

// ---- workspace byte offsets (all 16B aligned) ----
#define OFF_TF     0u
#define OFF_TCONP  10400u
#define OFF_ZCP    829600u
#define OFF_H0     1878176u
#define OFF_C0     2140320u
#define OFF_WCOMB  2402464u
#define OFF_WP1    2992288u
#define OFF_WP2    3123360u
#define OFF_WO1    3131552u
#define OFF_WO2    3262624u
#define OFF_WV     3270816u
#define OFF_HX     3295392u    // 16 pairs * 2 slots * 2 halves * 4KB
#define OFF_FLAGS  3557536u    // 32 * u32
#define OFF_HSEQ   3558400u    // 256*200*256*2

__device__ __forceinline__ float sigf(float x) { return 1.f / (1.f + __expf(-x)); }
__device__ __forceinline__ float tanh_f(float x) {
  float a = fabsf(x);
  float e = __expf(-2.f * a);
  float t = (1.f - e) / (1.f + e);
  return x < 0.f ? -t : t;
}

// light barrier: order LDS, leave global ops in flight
#define LBAR() asm volatile("s_waitcnt lgkmcnt(0)\n\ts_barrier" ::: "memory")

// ---- zero pair-handshake flags at the COHERENT POINT (agent-scope atomics;
// plain stores can sit in the writer XCD's L2 and be missed by other XCDs'
// agent-scope atomic loads) ----
__global__ void k_zflags(unsigned int* flags) {
  int i = threadIdx.x;
  if (i < 32)
    __hip_atomic_store(&flags[i], 0u, __ATOMIC_RELAXED, __HIP_MEMORY_SCOPE_AGENT);
}

// ---------------- time features [T,13] ----------------
__global__ void k_tfeat(float* tf) {
  int i = blockIdx.x * blockDim.x + threadIdx.x;
  if (i >= T_ * 13) return;
  int t = i / 13, j = i % 13;
  float tv = (float)t / 199.f;
  float v;
  if (j == 0) v = tv;
  else {
    int k = (j - 1) >> 1;
    float f = (float)(1 << k);
    double arg = 2.0 * PI_D * (double)f * (double)tv;
    v = (j & 1) ? (float)sin(arg) : (float)cos(arg);
  }
  tf[i] = v;
}

// ------------- precompute tconp, zcp, h0, c0 (lane-packed layouts) -------------
__global__ void k_prep(const float* __restrict__ tf, const float* __restrict__ Wih,
                       const float* __restrict__ z,
                       const float* __restrict__ bih, const float* __restrict__ bhh,
                       const float* __restrict__ Whz, const float* __restrict__ bhz,
                       const float* __restrict__ Wcz, const float* __restrict__ bcz,
                       float* tconp, float* zcp, float* h0, float* c0) {
  int i = blockIdx.x * blockDim.x + threadIdx.x;
  if (i < 204800) {
    // tconp[t*1024 + half*512 + u_loc*4 + g]
    int g = i & 3, q = i >> 2;
    int m = q & 127, hm = (q >> 7) & 1, t = q >> 8;
    int n = g * 256 + 128 * hm + m;
    float s = 0.f;
    #pragma unroll
    for (int j = 0; j < 13; ++j) s += tf[t * 13 + j] * Wih[n * 89 + 76 + j];
    tconp[i] = s;
    return;
  }
  i -= 204800;
  if (i < 262144) {
    // zcp[((bid*512 + tid)*4 + g)*4 + r]
    int r = i & 3, g = (i >> 2) & 3, tid = (i >> 4) & 511;
    int half = (i >> 13) & 1, pairk = i >> 14;
    int wv = tid >> 6, lr = tid & 15, lq = (tid >> 4) & 3;
    int b = pairk * 16 + lq * 4 + r;
    int n = g * 256 + 128 * half + 16 * wv + lr;
    float s = bih[n] + bhh[n];
    for (int k = 0; k < 64; ++k) s += z[b * 64 + k] * Wih[n * 89 + 12 + k];
    zcp[i] = s;
    return;
  }
  i -= 262144;
  if (i < 65536) {
    int b = i / 256, u = i % 256;
    float s = bhz[u];
    for (int k = 0; k < 64; ++k) s += z[b * 64 + k] * Whz[u * 64 + k];
    h0[i] = s;
    return;
  }
  i -= 65536;
  if (i < 65536) {
    int b = i / 256, u = i % 256;
    float s = bcz[u];
    for (int k = 0; k < 64; ++k) s += z[b * 64 + k] * Wcz[u * 64 + k];
    c0[i] = s;
  }
}

// ------------- bf16 weight casts -------------
__global__ void k_cast(const float* __restrict__ Whh, const float* __restrict__ Wih,
                       const float* __restrict__ Wp1, const float* __restrict__ Wp2,
                       const float* __restrict__ Wo1, const float* __restrict__ Wo2,
                       const float* __restrict__ Wv,
                       bf16* Wcomb, bf16* Wp1b, bf16* Wp2b, bf16* Wo1b,
                       bf16* Wo2b, bf16* Wvb) {
  int i = blockIdx.x * blockDim.x + threadIdx.x;
  if (i < 294912) {
    int n = i / XK, k = i % XK;
    float v = (k < 256) ? Whh[n * 256 + k]
            : ((k < 268) ? Wih[n * 89 + (k - 256)] : 0.f);
    Wcomb[i] = (bf16)v;
    return;
  }
  i -= 294912;
  if (i < 65536) { Wp1b[i] = (bf16)Wp1[i]; return; }
  i -= 65536;
  if (i < 4096) { int r = i / 256; Wp2b[i] = (bf16)((r < 12) ? Wp2[i] : 0.f); return; }
  i -= 4096;
  if (i < 65536) { Wo1b[i] = (bf16)Wo1[i]; return; }
  i -= 65536;
  if (i < 4096) { int r = i / 256; Wo2b[i] = (bf16)((r < 3) ? Wo2[i] : 0.f); return; }
  i -= 4096;
  if (i < 12288) { int r = i / 256; Wvb[i] = (bf16)((r < 42) ? Wv[i] : 0.f); }
}

// ------- recurrent LSTM: 32 blocks = 16 batch-groups x 2 unit-halves -------
__global__ __launch_bounds__(512, 2) void k_recur(
    const float* __restrict__ zcp, const float* __restrict__ tconp,
    const float* __restrict__ h0, const float* __restrict__ c0,
    const bf16* __restrict__ Wcomb, const bf16* __restrict__ Wp1b,
    const bf16* __restrict__ Wp2b,
    const float* __restrict__ bp1, const float* __restrict__ bp2,
    const float* __restrict__ jlo, const float* __restrict__ jhi,
    const float* __restrict__ ddp,
    unsigned long long* hx, unsigned int* flags,
    bf16* __restrict__ Hseq, float* __restrict__ outJ, float* __restrict__ outA) {
  __shared__ bf16 xbuf[16][XPAD];
  __shared__ bf16 w1[272][P1PAD];      // 0..255 Wp1, 256..271 Wp2
  __shared__ bf16 p1buf[16][P1PAD];
  const int tid = threadIdx.x;
  const int wv = tid >> 6, ln = tid & 63, lr = ln & 15, lq = ln >> 4;
  const int bid = blockIdx.x, pairk = bid >> 1, half = bid & 1;
  const int b0 = pairk * 16;
  const int u_loc = 16 * wv + lr;
  const int u_gl = 128 * half + u_loc;

  // ---- one-time LDS fills ----
  for (int i = tid; i < 272 * 32; i += 512) {
    int r = i >> 5, c8 = (i & 31) * 8;
    bf16x8 v = (r < 256)
      ? *reinterpret_cast<const bf16x8*>(&Wp1b[r * 256 + c8])
      : *reinterpret_cast<const bf16x8*>(&Wp2b[(r - 256) * 256 + c8]);
    *reinterpret_cast<bf16x8*>(&w1[r][c8]) = v;
  }
  for (int i = tid; i < 16 * XPAD; i += 512) {
    int r = i / XPAD, c = i % XPAD;
    float v = 0.f;
    if (c < 256) v = h0[(b0 + r) * 256 + c];
    else if (c < 268) {
      int d = c - 256;
      float lo = jlo[d], hi = jhi[d];
      v = (ddp[d] - 0.5f * (hi + lo)) / (0.5f * (hi - lo));
    }
    xbuf[r][c] = (bf16)v;
  }

  // ---- VGPR-resident gate weights (144 regs/lane) ----
  bf16x8 wc[4][9];
  #pragma unroll
  for (int g = 0; g < 4; ++g)
    #pragma unroll
    for (int kt = 0; kt < 9; ++kt)
      wc[g][kt] = *reinterpret_cast<const bf16x8*>(
          &Wcomb[(size_t)(g * 256 + u_gl) * XK + kt * 32 + lq * 8]);

  // ---- per-lane state: c, zc (in regs, constant over t) ----
  float c_reg[4];
  #pragma unroll
  for (int r = 0; r < 4; ++r) c_reg[r] = c0[(b0 + lq * 4 + r) * 256 + u_gl];
  f32x4 zcreg[4];
  #pragma unroll
  for (int g = 0; g < 4; ++g)
    zcreg[g] = *reinterpret_cast<const f32x4*>(
        zcp + ((size_t)bid * 512 + tid) * 16 + g * 4);
  const float* tcb = tconp + (size_t)(half * 512 + u_loc * 4);
  const float bp1r0 = bp1[32 * wv + lr];
  const float bp1r1 = bp1[32 * wv + 16 + lr];
  float bp2r = 0.f, ddr = 0.f, lor = -1.f, hir = 1.f;
  if (lr < 12) { bp2r = bp2[lr]; ddr = ddp[lr]; lor = jlo[lr]; hir = jhi[lr]; }
  const float jmr = 0.5f * (hir + lor), jrr = 0.5f * (hir - lor);
  bf16* hs = Hseq + ((size_t)(b0 + lq * 4) * T_) * 256 + u_gl;

  unsigned int* myf = &flags[bid];
  unsigned int* pf = &flags[bid ^ 1];
  const int ru = tid >> 2, rc = tid & 3;
  const int rcol = 128 * (half ^ 1) + ru;

  f32x4 tcv = *reinterpret_cast<const f32x4*>(tcb);  // t=0
  __syncthreads();
  bool dead = false;

  for (int t = 0; t < T_; ++t) {
    // A-fragments of x_t (capture before h overwrite)
    bf16x8 a[9];
    #pragma unroll
    for (int kt = 0; kt < 9; ++kt)
      a[kt] = *reinterpret_cast<const bf16x8*>(&xbuf[lr][kt * 32 + lq * 8]);
    LBAR();

    f32x4 ac[4];
    #pragma unroll
    for (int g = 0; g < 4; ++g) {
      ac[g] = zcreg[g] + tcv[g];
      #pragma unroll
      for (int kt = 0; kt < 9; ++kt)
        ac[g] = __builtin_amdgcn_mfma_f32_16x16x32_bf16(a[kt], wc[g][kt], ac[g], 0, 0, 0);
    }

    // LSTM elementwise; own h -> xbuf + pack for exchange
    union { unsigned long long v; unsigned short s[4]; } pk;
    bf16 hb4[4];
    #pragma unroll
    for (int r = 0; r < 4; ++r) {
      float cn = sigf(ac[1][r]) * c_reg[r] + sigf(ac[0][r]) * tanh_f(ac[2][r]);
      float hn = sigf(ac[3][r]) * tanh_f(cn);
      c_reg[r] = cn;
      bf16 hb = (bf16)hn;
      hb4[r] = hb;
      xbuf[lq * 4 + r][u_gl] = hb;
      pk.s[r] = __builtin_bit_cast(unsigned short, hb);
    }
    // publish own half at coherent point
    __hip_atomic_store(
        &hx[(((size_t)(pairk * 2 + (t & 1)) * 2 + half) * 128 + u_loc) * 4 + lq],
        pk.v, __ATOMIC_RELAXED, __HIP_MEMORY_SCOPE_AGENT);
    asm volatile("s_waitcnt vmcnt(0)" ::: "memory");  // hx stores acked
    __builtin_amdgcn_s_barrier();                     // all lanes published
    const unsigned int want = t + 1;
    if (tid == 0)
      __hip_atomic_store(myf, want, __ATOMIC_RELEASE, __HIP_MEMORY_SCOPE_AGENT);
    // Hseq stores overlap the partner spin
    #pragma unroll
    for (int r = 0; r < 4; ++r)
      hs[(size_t)r * (T_ * 256) + (size_t)t * 256] = hb4[r];

    if (!dead) {
      int guard = 1 << 24;
      for (;;) {
        unsigned int fv =
            __hip_atomic_load(pf, __ATOMIC_ACQUIRE, __HIP_MEMORY_SCOPE_AGENT);
        if ((int)(fv - want) >= 0) break;
        if (--guard == 0) { dead = true; break; }
      }
    }
    unsigned long long pv = __hip_atomic_load(
        &hx[(((size_t)(pairk * 2 + (t & 1)) * 2 + (half ^ 1)) * 128 + ru) * 4 + rc],
        __ATOMIC_RELAXED, __HIP_MEMORY_SCOPE_AGENT);
    {
      unsigned short* ph = (unsigned short*)&pv;
      #pragma unroll
      for (int j = 0; j < 4; ++j)
        xbuf[rc * 4 + j][rcol] = __builtin_bit_cast(bf16, ph[j]);
    }
    // prefetch next-step tcon (global load stays in flight through LBAR)
    f32x4 tcn = *reinterpret_cast<const f32x4*>(
        tcb + (size_t)((t + 1 < T_) ? t + 1 : t) * 1024);
    LBAR();  // full h_new visible

    // p1 = relu(h_new @ Wp1^T + bp1): fragments streamed from LDS
    #pragma unroll
    for (int jn = 0; jn < 2; ++jn) {
      int n0 = 32 * wv + 16 * jn;
      float bb = (jn == 0) ? bp1r0 : bp1r1;
      f32x4 acc = {bb, bb, bb, bb};
      #pragma unroll
      for (int kt = 0; kt < 8; ++kt) {
        bf16x8 av = *reinterpret_cast<const bf16x8*>(&xbuf[lr][kt * 32 + lq * 8]);
        bf16x8 bv = *reinterpret_cast<const bf16x8*>(&w1[n0 + lr][kt * 32 + lq * 8]);
        acc = __builtin_amdgcn_mfma_f32_16x16x32_bf16(av, bv, acc, 0, 0, 0);
      }
      #pragma unroll
      for (int r = 0; r < 4; ++r)
        p1buf[lq * 4 + r][n0 + lr] = (bf16)fmaxf(acc[r], 0.f);
    }
    LBAR();  // p1 visible

    // action head on wave 0 (both halves redundantly; global writes gated)
    if (wv == 0) {
      f32x4 acc = {0.f, 0.f, 0.f, 0.f};
      #pragma unroll
      for (int kt = 0; kt < 8; ++kt) {
        bf16x8 ap = *reinterpret_cast<const bf16x8*>(&p1buf[lr][kt * 32 + lq * 8]);
        bf16x8 w2 = *reinterpret_cast<const bf16x8*>(&w1[256 + lr][kt * 32 + lq * 8]);
        acc = __builtin_amdgcn_mfma_f32_16x16x32_bf16(ap, w2, acc, 0, 0, 0);
      }
      if (lr < 12) {
        #pragma unroll
        for (int r = 0; r < 4; ++r) {
          int b = lq * 4 + r;
          float act = tanh_f(acc[r] + bp2r);
          float curp = act * 0.25f + ddr;   // TRACK_ALPHA = 1
          float cl = fminf(fmaxf(curp, lor), hir);
          if (half == 0) {
            size_t o = ((size_t)(b0 + b) * T_ + t) * 12 + lr;
            outA[o] = act;
            outJ[o] = curp;
          }
          xbuf[b][256 + lr] = (bf16)((cl - jmr) / jrr);
        }
      }
    }
    LBAR();  // prev_norm visible for next step
    tcv = tcn;
  }
}

// ------------- post pass: obj head, sigma head, FK, normalize -------------
__global__ __launch_bounds__(256) void k_post(
    const bf16* __restrict__ Hseq, const bf16* __restrict__ Wo1b,
    const bf16* __restrict__ Wo2b, const bf16* __restrict__ Wvb,
    const float* __restrict__ bo1, const float* __restrict__ bo2,
    const float* __restrict__ bv,
    const float* __restrict__ Wfk, const float* __restrict__ bfk,
    const float* __restrict__ pm, const float* __restrict__ ps,
    const float* __restrict__ joints, float* __restrict__ out0,
    float* __restrict__ out3) {
  __shared__ bf16 u1buf[16][P1PAD];
  __shared__ float objbuf[16][3];
  __shared__ float jbuf[16][12];
  const int tid = threadIdx.x;
  const int wv = tid >> 6;
  const int ln = tid & 63;
  const int lr = ln & 15;
  const int lq = ln >> 4;

  bf16x8 wo1f[4][8];
  float bo1r[4];
  #pragma unroll
  for (int jn = 0; jn < 4; ++jn) {
    int n0 = wv * 64 + jn * 16;
    bo1r[jn] = bo1[n0 + lr];
    #pragma unroll
    for (int kt = 0; kt < 8; ++kt)
      wo1f[jn][kt] = *reinterpret_cast<const bf16x8*>(
          &Wo1b[(size_t)(n0 + lr) * 256 + kt * 32 + lq * 8]);
  }
  const int col = (wv - 1) * 16 + lr;
  bf16x8 wvf[8];
  float bvr = 0.f;
  if (wv >= 1) {
    #pragma unroll
    for (int kt = 0; kt < 8; ++kt)
      wvf[kt] = *reinterpret_cast<const bf16x8*>(
          &Wvb[(size_t)col * 256 + kt * 32 + lq * 8]);
    bvr = (col < 42) ? bv[col] : 0.f;
  }
  bf16x8 wo2f[8];
  if (wv == 0) {
    #pragma unroll
    for (int kt = 0; kt < 8; ++kt)
      wo2f[kt] = *reinterpret_cast<const bf16x8*>(
          &Wo2b[(size_t)lr * 256 + kt * 32 + lq * 8]);
  }

  for (int it = 0; it < 10; ++it) {
    int tt = blockIdx.x * 10 + it;
    size_t r0 = (size_t)tt * 16;
    bf16x8 ah[8];
    #pragma unroll
    for (int kt = 0; kt < 8; ++kt)
      ah[kt] = *reinterpret_cast<const bf16x8*>(&Hseq[(r0 + lr) * 256 + kt * 32 + lq * 8]);
    #pragma unroll
    for (int jn = 0; jn < 4; ++jn) {
      int n0 = wv * 64 + jn * 16;
      float bb = bo1r[jn];
      f32x4 acc = {bb, bb, bb, bb};
      #pragma unroll
      for (int kt = 0; kt < 8; ++kt)
        acc = __builtin_amdgcn_mfma_f32_16x16x32_bf16(ah[kt], wo1f[jn][kt], acc, 0, 0, 0);
      #pragma unroll
      for (int r = 0; r < 4; ++r)
        u1buf[lq * 4 + r][n0 + lr] = (bf16)fmaxf(acc[r], 0.f);
    }
    if (wv >= 1) {
      f32x4 acc = {bvr, bvr, bvr, bvr};
      #pragma unroll
      for (int kt = 0; kt < 8; ++kt)
        acc = __builtin_amdgcn_mfma_f32_16x16x32_bf16(ah[kt], wvf[kt], acc, 0, 0, 0);
      if (col < 42) {
        #pragma unroll
        for (int r = 0; r < 4; ++r) {
          float s = 0.05f + 0.45f * sigf(acc[r]);
          out3[(r0 + lq * 4 + r) * 42 + col] = __logf(s);
        }
      }
    }
    if (tid < 192) {
      int rr = tid / 12, d = tid % 12;
      jbuf[rr][d] = joints[(r0 + rr) * 12 + d];
    }
    __syncthreads();
    if (wv == 0) {
      bf16x8 ap[8];
      #pragma unroll
      for (int kt = 0; kt < 8; ++kt)
        ap[kt] = *reinterpret_cast<const bf16x8*>(&u1buf[lr][kt * 32 + lq * 8]);
      f32x4 acc = {0.f, 0.f, 0.f, 0.f};
      #pragma unroll
      for (int kt = 0; kt < 8; ++kt)
        acc = __builtin_amdgcn_mfma_f32_16x16x32_bf16(ap[kt], wo2f[kt], acc, 0, 0, 0);
      if (lr < 3) {
        #pragma unroll
        for (int r = 0; r < 4; ++r)
          objbuf[lq * 4 + r][lr] = acc[r] + bo2[lr];
      }
    }
    __syncthreads();
    for (int e = tid; e < 16 * 42; e += 256) {
      int rr = e / 42, pd = e % 42;
      float v;
      if (pd < 39) {
        float s = bfk[pd];
        #pragma unroll
        for (int d = 0; d < 12; ++d) s += jbuf[rr][d] * Wfk[pd * 12 + d];
        v = s;
      } else v = objbuf[rr][pd - 39];
      out0[(r0 + rr) * 42 + pd] = (v - pm[pd]) / ps[pd];
    }
    __syncthreads();
  }
}

extern "C" void kernel_launch(void* const* d_in, const int* in_sizes, int n_in,
                              void* d_out, int out_size, void* d_ws, size_t ws_size,
                              hipStream_t stream) {
  const float* z   = (const float*)d_in[0];
  const float* Whz = (const float*)d_in[1];
  const float* bhz = (const float*)d_in[2];
  const float* Wcz = (const float*)d_in[3];
  const float* bcz = (const float*)d_in[4];
  const float* Wih = (const float*)d_in[5];
  const float* Whh = (const float*)d_in[6];
  const float* bih = (const float*)d_in[7];
  const float* bhh = (const float*)d_in[8];
  const float* Wp1 = (const float*)d_in[9];
  const float* bp1 = (const float*)d_in[10];
  const float* Wp2 = (const float*)d_in[11];
  const float* bp2 = (const float*)d_in[12];
  const float* Wo1 = (const float*)d_in[13];
  const float* bo1 = (const float*)d_in[14];
  const float* Wo2 = (const float*)d_in[15];
  const float* bo2 = (const float*)d_in[16];
  const float* Wv  = (const float*)d_in[17];
  const float* bv  = (const float*)d_in[18];
  const float* Wfk = (const float*)d_in[19];
  const float* bfk = (const float*)d_in[20];
  const float* pm  = (const float*)d_in[21];
  const float* ps  = (const float*)d_in[22];
  const float* jlo = (const float*)d_in[23];
  const float* jhi = (const float*)d_in[24];
  const float* ddp = (const float*)d_in[25];

  char* ws = (char*)d_ws;
  float* tf    = (float*)(ws + OFF_TF);
  float* tconp = (float*)(ws + OFF_TCONP);
  float* zcp   = (float*)(ws + OFF_ZCP);
  float* h0    = (float*)(ws + OFF_H0);
  float* c0    = (float*)(ws + OFF_C0);
  bf16* Wcomb  = (bf16*)(ws + OFF_WCOMB);
  bf16* Wp1b   = (bf16*)(ws + OFF_WP1);
  bf16* Wp2b   = (bf16*)(ws + OFF_WP2);
  bf16* Wo1b   = (bf16*)(ws + OFF_WO1);
  bf16* Wo2b   = (bf16*)(ws + OFF_WO2);
  bf16* Wvb    = (bf16*)(ws + OFF_WV);
  unsigned long long* hx = (unsigned long long*)(ws + OFF_HX);
  unsigned int* flags    = (unsigned int*)(ws + OFF_FLAGS);
  bf16* Hseq   = (bf16*)(ws + OFF_HSEQ);

  float* out  = (float*)d_out;
  float* out0 = out;                 // graph_x_mu [B,T,42]
  float* outJ = out + 2150400;       // joint_traj [B,T,12]
  float* outA = out + 2764800;       // actions    [B,T,12]
  float* out3 = out + 3379200;       // log_sigma  [B,T,42]

  k_zflags<<<1, 64, 0, stream>>>(flags);
  k_tfeat<<<11, 256, 0, stream>>>(tf);
  k_prep<<<2336, 256, 0, stream>>>(tf, Wih, z, bih, bhh, Whz, bhz, Wcz, bcz,
                                   tconp, zcp, h0, c0);
  k_cast<<<1744, 256, 0, stream>>>(Whh, Wih, Wp1, Wp2, Wo1, Wo2, Wv,
                                   Wcomb, Wp1b, Wp2b, Wo1b, Wo2b, Wvb);
  k_recur<<<32, 512, 0, stream>>>(zcp, tconp, h0, c0, Wcomb, Wp1b, Wp2b,
                                  bp1, bp2, jlo, jhi, ddp, hx, flags,
                                  Hseq, outJ, outA);
  k_post<<<320, 256, 0, stream>>>(Hseq, Wo1b, Wo2b, Wvb, bo1, bo2, bv,
                                  Wfk, bfk, pm, ps, outJ, out0, out3);
}

// Round 6
// 1205.057 us; speedup vs baseline: 2.9405x; 1.4664x over previous
//
#include <hip/hip_runtime.h>
#include <math.h>

#define B_ 256
#define T_ 200
#define H_ 256
#define DOF_ 12

typedef __bf16 bf16;
typedef __bf16 bf16x8 __attribute__((ext_vector_type(8)));
typedef float f32x4 __attribute__((ext_vector_type(4)));

#define XK 288      // gate GEMM K: 256 h + 12 prev + 20 zero pad
#define XPAD 296
#define P1PAD 264

#define PI_D 3.14159265358979323846

// ---- workspace byte offsets (all 16B aligned) ----
#define OFF_TF     0u
#define OFF_TCONP  10400u
#define OFF_ZCP    829600u
#define OFF_H0     1878176u
#define OFF_C0     2140320u
#define OFF_WCOMB  2402464u
#define OFF_WP1    2992288u
#define OFF_WP2    3123360u
#define OFF_WO1    3131552u
#define OFF_WO2    3262624u
#define OFF_WV     3270816u
#define OFF_HX     3295392u    // 16 pairs * 2 slots * 2 halves * 4KB
#define OFF_FLAGS  3557536u    // 32 * u32
#define OFF_HSEQ   3558400u    // 256*200*256*2

__device__ __forceinline__ float sigf(float x) { return 1.f / (1.f + __expf(-x)); }
__device__ __forceinline__ float tanh_f(float x) {
  float a = fabsf(x);
  float e = __expf(-2.f * a);
  float t = (1.f - e) / (1.f + e);
  return x < 0.f ? -t : t;
}

// light barrier: order LDS, leave global ops in flight
#define LBAR() asm volatile("s_waitcnt lgkmcnt(0)\n\ts_barrier" ::: "memory")

// zero pair-handshake flags at the coherent point
__global__ void k_zflags(unsigned int* flags) {
  int i = threadIdx.x;
  if (i < 32)
    __hip_atomic_store(&flags[i], 0u, __ATOMIC_RELAXED, __HIP_MEMORY_SCOPE_AGENT);
}

// ---------------- time features [T,13] ----------------
__global__ void k_tfeat(float* tf) {
  int i = blockIdx.x * blockDim.x + threadIdx.x;
  if (i >= T_ * 13) return;
  int t = i / 13, j = i % 13;
  float tv = (float)t / 199.f;
  float v;
  if (j == 0) v = tv;
  else {
    int k = (j - 1) >> 1;
    float f = (float)(1 << k);
    double arg = 2.0 * PI_D * (double)f * (double)tv;
    v = (j & 1) ? (float)sin(arg) : (float)cos(arg);
  }
  tf[i] = v;
}

// ------------- precompute tconp, zcp, h0, c0 (lane-packed layouts) -------------
__global__ void k_prep(const float* __restrict__ tf, const float* __restrict__ Wih,
                       const float* __restrict__ z,
                       const float* __restrict__ bih, const float* __restrict__ bhh,
                       const float* __restrict__ Whz, const float* __restrict__ bhz,
                       const float* __restrict__ Wcz, const float* __restrict__ bcz,
                       float* tconp, float* zcp, float* h0, float* c0) {
  int i = blockIdx.x * blockDim.x + threadIdx.x;
  if (i < 204800) {
    // tconp[t*1024 + half*512 + u_loc*4 + g]
    int g = i & 3, q = i >> 2;
    int m = q & 127, hm = (q >> 7) & 1, t = q >> 8;
    int n = g * 256 + 128 * hm + m;
    float s = 0.f;
    #pragma unroll
    for (int j = 0; j < 13; ++j) s += tf[t * 13 + j] * Wih[n * 89 + 76 + j];
    tconp[i] = s;
    return;
  }
  i -= 204800;
  if (i < 262144) {
    // zcp[((bid*512 + tid)*4 + g)*4 + r]
    int r = i & 3, g = (i >> 2) & 3, tid = (i >> 4) & 511;
    int half = (i >> 13) & 1, pairk = i >> 14;
    int wv = tid >> 6, lr = tid & 15, lq = (tid >> 4) & 3;
    int b = pairk * 16 + lq * 4 + r;
    int n = g * 256 + 128 * half + 16 * wv + lr;
    float s = bih[n] + bhh[n];
    for (int k = 0; k < 64; ++k) s += z[b * 64 + k] * Wih[n * 89 + 12 + k];
    zcp[i] = s;
    return;
  }
  i -= 262144;
  if (i < 65536) {
    int b = i / 256, u = i % 256;
    float s = bhz[u];
    for (int k = 0; k < 64; ++k) s += z[b * 64 + k] * Whz[u * 64 + k];
    h0[i] = s;
    return;
  }
  i -= 65536;
  if (i < 65536) {
    int b = i / 256, u = i % 256;
    float s = bcz[u];
    for (int k = 0; k < 64; ++k) s += z[b * 64 + k] * Wcz[u * 64 + k];
    c0[i] = s;
  }
}

// ------------- bf16 weight casts -------------
__global__ void k_cast(const float* __restrict__ Whh, const float* __restrict__ Wih,
                       const float* __restrict__ Wp1, const float* __restrict__ Wp2,
                       const float* __restrict__ Wo1, const float* __restrict__ Wo2,
                       const float* __restrict__ Wv,
                       bf16* Wcomb, bf16* Wp1b, bf16* Wp2b, bf16* Wo1b,
                       bf16* Wo2b, bf16* Wvb) {
  int i = blockIdx.x * blockDim.x + threadIdx.x;
  if (i < 294912) {
    int n = i / XK, k = i % XK;
    float v = (k < 256) ? Whh[n * 256 + k]
            : ((k < 268) ? Wih[n * 89 + (k - 256)] : 0.f);
    Wcomb[i] = (bf16)v;
    return;
  }
  i -= 294912;
  if (i < 65536) { Wp1b[i] = (bf16)Wp1[i]; return; }
  i -= 65536;
  if (i < 4096) { int r = i / 256; Wp2b[i] = (bf16)((r < 12) ? Wp2[i] : 0.f); return; }
  i -= 4096;
  if (i < 65536) { Wo1b[i] = (bf16)Wo1[i]; return; }
  i -= 65536;
  if (i < 4096) { int r = i / 256; Wo2b[i] = (bf16)((r < 3) ? Wo2[i] : 0.f); return; }
  i -= 4096;
  if (i < 12288) { int r = i / 256; Wvb[i] = (bf16)((r < 42) ? Wv[i] : 0.f); }
}

// ------- recurrent LSTM: 32 blocks = 16 batch-groups x 2 unit-halves -------
__global__ __launch_bounds__(512, 2) void k_recur(
    const float* __restrict__ zcp, const float* __restrict__ tconp,
    const float* __restrict__ h0, const float* __restrict__ c0,
    const bf16* __restrict__ Wcomb, const bf16* __restrict__ Wp1b,
    const bf16* __restrict__ Wp2b,
    const float* __restrict__ bp1, const float* __restrict__ bp2,
    const float* __restrict__ jlo, const float* __restrict__ jhi,
    const float* __restrict__ ddp,
    unsigned long long* hx, unsigned int* flags,
    bf16* __restrict__ Hseq, float* __restrict__ outJ, float* __restrict__ outA) {
  __shared__ bf16 xbuf[16][XPAD];
  __shared__ bf16 w1[272][P1PAD];      // 0..255 Wp1, 256..271 Wp2
  __shared__ bf16 p1buf[16][P1PAD];
  const int tid = threadIdx.x;
  const int wv = tid >> 6, ln = tid & 63, lr = ln & 15, lq = ln >> 4;
  const int bid = blockIdx.x, pairk = bid >> 1, half = bid & 1;
  const int b0 = pairk * 16;
  const int u_loc = 16 * wv + lr;
  const int u_gl = 128 * half + u_loc;

  // ---- one-time LDS fills ----
  for (int i = tid; i < 272 * 32; i += 512) {
    int r = i >> 5, c8 = (i & 31) * 8;
    bf16x8 v = (r < 256)
      ? *reinterpret_cast<const bf16x8*>(&Wp1b[r * 256 + c8])
      : *reinterpret_cast<const bf16x8*>(&Wp2b[(r - 256) * 256 + c8]);
    *reinterpret_cast<bf16x8*>(&w1[r][c8]) = v;
  }
  for (int i = tid; i < 16 * XPAD; i += 512) {
    int r = i / XPAD, c = i % XPAD;
    float v = 0.f;
    if (c < 256) v = h0[(b0 + r) * 256 + c];
    else if (c < 268) {
      int d = c - 256;
      float lo = jlo[d], hi = jhi[d];
      v = (ddp[d] - 0.5f * (hi + lo)) / (0.5f * (hi - lo));
    }
    xbuf[r][c] = (bf16)v;
  }

  // ---- gate weights -> registers, laundered through opaque asm so the
  // allocator can neither rematerialize nor sink the loads into the loop ----
  bf16x8 wc[4][9];
  #pragma unroll
  for (int g = 0; g < 4; ++g)
    #pragma unroll
    for (int kt = 0; kt < 9; ++kt) {
      wc[g][kt] = *reinterpret_cast<const bf16x8*>(
          &Wcomb[(size_t)(g * 256 + u_gl) * XK + kt * 32 + lq * 8]);
      f32x4 tmp = __builtin_bit_cast(f32x4, wc[g][kt]);
      asm volatile("" : "+v"(tmp));
      wc[g][kt] = __builtin_bit_cast(bf16x8, tmp);
    }

  // ---- per-lane state ----
  float c_reg[4];
  #pragma unroll
  for (int r = 0; r < 4; ++r) c_reg[r] = c0[(b0 + lq * 4 + r) * 256 + u_gl];
  f32x4 zcreg[4];
  #pragma unroll
  for (int g = 0; g < 4; ++g)
    zcreg[g] = *reinterpret_cast<const f32x4*>(
        zcp + ((size_t)bid * 512 + tid) * 16 + g * 4);
  const float* tcb = tconp + (size_t)(half * 512 + u_loc * 4);
  const float bp1r0 = bp1[32 * wv + lr];
  const float bp1r1 = bp1[32 * wv + 16 + lr];
  float bp2r = 0.f, ddr = 0.f, lor = -1.f, hir = 1.f;
  if (lr < 12) { bp2r = bp2[lr]; ddr = ddp[lr]; lor = jlo[lr]; hir = jhi[lr]; }
  const float jmr = 0.5f * (hir + lor), jrr = 0.5f * (hir - lor);
  bf16* hs = Hseq + ((size_t)(b0 + lq * 4) * T_) * 256 + u_gl;

  unsigned int* pf = &flags[bid ^ 1];
  unsigned int* myf = &flags[bid];
  const int ru = tid >> 2, rc = tid & 3;
  const int rcol = 128 * (half ^ 1) + ru;

  f32x4 tcv = *reinterpret_cast<const f32x4*>(tcb);  // t=0
  __syncthreads();
  bool dead = false;

  for (int t = 0; t < T_; ++t) {
    // A-fragments of x_t (capture before h overwrite)
    bf16x8 a[9];
    #pragma unroll
    for (int kt = 0; kt < 9; ++kt)
      a[kt] = *reinterpret_cast<const bf16x8*>(&xbuf[lr][kt * 32 + lq * 8]);
    LBAR();

    f32x4 ac[4];
    #pragma unroll
    for (int g = 0; g < 4; ++g) {
      ac[g] = zcreg[g] + tcv[g];
      #pragma unroll
      for (int kt = 0; kt < 9; ++kt)
        ac[g] = __builtin_amdgcn_mfma_f32_16x16x32_bf16(a[kt], wc[g][kt], ac[g], 0, 0, 0);
    }

    // LSTM elementwise; own h -> xbuf + pack for exchange
    union { unsigned long long v; unsigned short s[4]; } pk;
    bf16 hb4[4];
    #pragma unroll
    for (int r = 0; r < 4; ++r) {
      float cn = sigf(ac[1][r]) * c_reg[r] + sigf(ac[0][r]) * tanh_f(ac[2][r]);
      float hn = sigf(ac[3][r]) * tanh_f(cn);
      c_reg[r] = cn;
      bf16 hb = (bf16)hn;
      hb4[r] = hb;
      xbuf[lq * 4 + r][u_gl] = hb;
      pk.s[r] = __builtin_bit_cast(unsigned short, hb);
    }
    // publish own half at coherent point (RELAXED everywhere; ordering is
    // vmcnt(0)+barrier before the flag store, program order on the reader)
    __hip_atomic_store(
        &hx[(((size_t)(pairk * 2 + (t & 1)) * 2 + half) * 128 + u_loc) * 4 + lq],
        pk.v, __ATOMIC_RELAXED, __HIP_MEMORY_SCOPE_AGENT);
    asm volatile("s_waitcnt vmcnt(0)" ::: "memory");
    __builtin_amdgcn_s_barrier();
    const unsigned int want = t + 1;
    if (tid == 0)
      __hip_atomic_store(myf, want, __ATOMIC_RELAXED, __HIP_MEMORY_SCOPE_AGENT);
    // overlap the spin: Hseq stores + next-step tcon prefetch
    #pragma unroll
    for (int r = 0; r < 4; ++r)
      hs[(size_t)r * (T_ * 256) + (size_t)t * 256] = hb4[r];
    f32x4 tcn = *reinterpret_cast<const f32x4*>(
        tcb + (size_t)((t + 1 < T_) ? t + 1 : t) * 1024);

    if (!dead) {
      int guard = 1 << 20;
      for (;;) {
        unsigned int fv =
            __hip_atomic_load(pf, __ATOMIC_RELAXED, __HIP_MEMORY_SCOPE_AGENT);
        if ((int)(fv - want) >= 0) break;
        if (--guard == 0) { dead = true; break; }
      }
    }
    unsigned long long pv = __hip_atomic_load(
        &hx[(((size_t)(pairk * 2 + (t & 1)) * 2 + (half ^ 1)) * 128 + ru) * 4 + rc],
        __ATOMIC_RELAXED, __HIP_MEMORY_SCOPE_AGENT);
    {
      unsigned short* ph = (unsigned short*)&pv;
      #pragma unroll
      for (int j = 0; j < 4; ++j)
        xbuf[rc * 4 + j][rcol] = __builtin_bit_cast(bf16, ph[j]);
    }
    LBAR();  // full h_new visible

    // p1 = relu(h_new @ Wp1^T + bp1): fragments streamed from LDS
    #pragma unroll
    for (int jn = 0; jn < 2; ++jn) {
      int n0 = 32 * wv + 16 * jn;
      float bb = (jn == 0) ? bp1r0 : bp1r1;
      f32x4 acc = {bb, bb, bb, bb};
      #pragma unroll
      for (int kt = 0; kt < 8; ++kt) {
        bf16x8 av = *reinterpret_cast<const bf16x8*>(&xbuf[lr][kt * 32 + lq * 8]);
        bf16x8 bv = *reinterpret_cast<const bf16x8*>(&w1[n0 + lr][kt * 32 + lq * 8]);
        acc = __builtin_amdgcn_mfma_f32_16x16x32_bf16(av, bv, acc, 0, 0, 0);
      }
      #pragma unroll
      for (int r = 0; r < 4; ++r)
        p1buf[lq * 4 + r][n0 + lr] = (bf16)fmaxf(acc[r], 0.f);
    }
    LBAR();  // p1 visible

    // action head on wave 0 (redundant across halves; global writes gated)
    if (wv == 0) {
      f32x4 acc = {0.f, 0.f, 0.f, 0.f};
      #pragma unroll
      for (int kt = 0; kt < 8; ++kt) {
        bf16x8 ap = *reinterpret_cast<const bf16x8*>(&p1buf[lr][kt * 32 + lq * 8]);
        bf16x8 w2 = *reinterpret_cast<const bf16x8*>(&w1[256 + lr][kt * 32 + lq * 8]);
        acc = __builtin_amdgcn_mfma_f32_16x16x32_bf16(ap, w2, acc, 0, 0, 0);
      }
      if (lr < 12) {
        #pragma unroll
        for (int r = 0; r < 4; ++r) {
          int b = lq * 4 + r;
          float act = tanh_f(acc[r] + bp2r);
          float curp = act * 0.25f + ddr;   // TRACK_ALPHA = 1
          float cl = fminf(fmaxf(curp, lor), hir);
          if (half == 0) {
            size_t o = ((size_t)(b0 + b) * T_ + t) * 12 + lr;
            outA[o] = act;
            outJ[o] = curp;
          }
          xbuf[b][256 + lr] = (bf16)((cl - jmr) / jrr);
        }
      }
    }
    LBAR();  // prev_norm visible for next step
    tcv = tcn;
  }
}

// ------------- post pass: obj head, sigma head, FK, normalize -------------
__global__ __launch_bounds__(256) void k_post(
    const bf16* __restrict__ Hseq, const bf16* __restrict__ Wo1b,
    const bf16* __restrict__ Wo2b, const bf16* __restrict__ Wvb,
    const float* __restrict__ bo1, const float* __restrict__ bo2,
    const float* __restrict__ bv,
    const float* __restrict__ Wfk, const float* __restrict__ bfk,
    const float* __restrict__ pm, const float* __restrict__ ps,
    const float* __restrict__ joints, float* __restrict__ out0,
    float* __restrict__ out3) {
  __shared__ bf16 u1buf[16][P1PAD];
  __shared__ float objbuf[16][3];
  __shared__ float jbuf[16][12];
  const int tid = threadIdx.x;
  const int wv = tid >> 6;
  const int ln = tid & 63;
  const int lr = ln & 15;
  const int lq = ln >> 4;

  bf16x8 wo1f[4][8];
  float bo1r[4];
  #pragma unroll
  for (int jn = 0; jn < 4; ++jn) {
    int n0 = wv * 64 + jn * 16;
    bo1r[jn] = bo1[n0 + lr];
    #pragma unroll
    for (int kt = 0; kt < 8; ++kt)
      wo1f[jn][kt] = *reinterpret_cast<const bf16x8*>(
          &Wo1b[(size_t)(n0 + lr) * 256 + kt * 32 + lq * 8]);
  }
  const int col = (wv - 1) * 16 + lr;
  bf16x8 wvf[8];
  float bvr = 0.f;
  if (wv >= 1) {
    #pragma unroll
    for (int kt = 0; kt < 8; ++kt)
      wvf[kt] = *reinterpret_cast<const bf16x8*>(
          &Wvb[(size_t)col * 256 + kt * 32 + lq * 8]);
    bvr = (col < 42) ? bv[col] : 0.f;
  }
  bf16x8 wo2f[8];
  if (wv == 0) {
    #pragma unroll
    for (int kt = 0; kt < 8; ++kt)
      wo2f[kt] = *reinterpret_cast<const bf16x8*>(
          &Wo2b[(size_t)lr * 256 + kt * 32 + lq * 8]);
  }

  for (int it = 0; it < 10; ++it) {
    int tt = blockIdx.x * 10 + it;
    size_t r0 = (size_t)tt * 16;
    bf16x8 ah[8];
    #pragma unroll
    for (int kt = 0; kt < 8; ++kt)
      ah[kt] = *reinterpret_cast<const bf16x8*>(&Hseq[(r0 + lr) * 256 + kt * 32 + lq * 8]);
    #pragma unroll
    for (int jn = 0; jn < 4; ++jn) {
      int n0 = wv * 64 + jn * 16;
      float bb = bo1r[jn];
      f32x4 acc = {bb, bb, bb, bb};
      #pragma unroll
      for (int kt = 0; kt < 8; ++kt)
        acc = __builtin_amdgcn_mfma_f32_16x16x32_bf16(ah[kt], wo1f[jn][kt], acc, 0, 0, 0);
      #pragma unroll
      for (int r = 0; r < 4; ++r)
        u1buf[lq * 4 + r][n0 + lr] = (bf16)fmaxf(acc[r], 0.f);
    }
    if (wv >= 1) {
      f32x4 acc = {bvr, bvr, bvr, bvr};
      #pragma unroll
      for (int kt = 0; kt < 8; ++kt)
        acc = __builtin_amdgcn_mfma_f32_16x16x32_bf16(ah[kt], wvf[kt], acc, 0, 0, 0);
      if (col < 42) {
        #pragma unroll
        for (int r = 0; r < 4; ++r) {
          float s = 0.05f + 0.45f * sigf(acc[r]);
          out3[(r0 + lq * 4 + r) * 42 + col] = __logf(s);
        }
      }
    }
    if (tid < 192) {
      int rr = tid / 12, d = tid % 12;
      jbuf[rr][d] = joints[(r0 + rr) * 12 + d];
    }
    __syncthreads();
    if (wv == 0) {
      bf16x8 ap[8];
      #pragma unroll
      for (int kt = 0; kt < 8; ++kt)
        ap[kt] = *reinterpret_cast<const bf16x8*>(&u1buf[lr][kt * 32 + lq * 8]);
      f32x4 acc = {0.f, 0.f, 0.f, 0.f};
      #pragma unroll
      for (int kt = 0; kt < 8; ++kt)
        acc = __builtin_amdgcn_mfma_f32_16x16x32_bf16(ap[kt], wo2f[kt], acc, 0, 0, 0);
      if (lr < 3) {
        #pragma unroll
        for (int r = 0; r < 4; ++r)
          objbuf[lq * 4 + r][lr] = acc[r] + bo2[lr];
      }
    }
    __syncthreads();
    for (int e = tid; e < 16 * 42; e += 256) {
      int rr = e / 42, pd = e % 42;
      float v;
      if (pd < 39) {
        float s = bfk[pd];
        #pragma unroll
        for (int d = 0; d < 12; ++d) s += jbuf[rr][d] * Wfk[pd * 12 + d];
        v = s;
      } else v = objbuf[rr][pd - 39];
      out0[(r0 + rr) * 42 + pd] = (v - pm[pd]) / ps[pd];
    }
    __syncthreads();
  }
}

extern "C" void kernel_launch(void* const* d_in, const int* in_sizes, int n_in,
                              void* d_out, int out_size, void* d_ws, size_t ws_size,
                              hipStream_t stream) {
  const float* z   = (const float*)d_in[0];
  const float* Whz = (const float*)d_in[1];
  const float* bhz = (const float*)d_in[2];
  const float* Wcz = (const float*)d_in[3];
  const float* bcz = (const float*)d_in[4];
  const float* Wih = (const float*)d_in[5];
  const float* Whh = (const float*)d_in[6];
  const float* bih = (const float*)d_in[7];
  const float* bhh = (const float*)d_in[8];
  const float* Wp1 = (const float*)d_in[9];
  const float* bp1 = (const float*)d_in[10];
  const float* Wp2 = (const float*)d_in[11];
  const float* bp2 = (const float*)d_in[12];
  const float* Wo1 = (const float*)d_in[13];
  const float* bo1 = (const float*)d_in[14];
  const float* Wo2 = (const float*)d_in[15];
  const float* bo2 = (const float*)d_in[16];
  const float* Wv  = (const float*)d_in[17];
  const float* bv  = (const float*)d_in[18];
  const float* Wfk = (const float*)d_in[19];
  const float* bfk = (const float*)d_in[20];
  const float* pm  = (const float*)d_in[21];
  const float* ps  = (const float*)d_in[22];
  const float* jlo = (const float*)d_in[23];
  const float* jhi = (const float*)d_in[24];
  const float* ddp = (const float*)d_in[25];

  char* ws = (char*)d_ws;
  float* tf    = (float*)(ws + OFF_TF);
  float* tconp = (float*)(ws + OFF_TCONP);
  float* zcp   = (float*)(ws + OFF_ZCP);
  float* h0    = (float*)(ws + OFF_H0);
  float* c0    = (float*)(ws + OFF_C0);
  bf16* Wcomb  = (bf16*)(ws + OFF_WCOMB);
  bf16* Wp1b   = (bf16*)(ws + OFF_WP1);
  bf16* Wp2b   = (bf16*)(ws + OFF_WP2);
  bf16* Wo1b   = (bf16*)(ws + OFF_WO1);
  bf16* Wo2b   = (bf16*)(ws + OFF_WO2);
  bf16* Wvb    = (bf16*)(ws + OFF_WV);
  unsigned long long* hx = (unsigned long long*)(ws + OFF_HX);
  unsigned int* flags    = (unsigned int*)(ws + OFF_FLAGS);
  bf16* Hseq   = (bf16*)(ws + OFF_HSEQ);

  float* out  = (float*)d_out;
  float* out0 = out;                 // graph_x_mu [B,T,42]
  float* outJ = out + 2150400;       // joint_traj [B,T,12]
  float* outA = out + 2764800;       // actions    [B,T,12]
  float* out3 = out + 3379200;       // log_sigma  [B,T,42]

  k_zflags<<<1, 64, 0, stream>>>(flags);
  k_tfeat<<<11, 256, 0, stream>>>(tf);
  k_prep<<<2336, 256, 0, stream>>>(tf, Wih, z, bih, bhh, Whz, bhz, Wcz, bcz,
                                   tconp, zcp, h0, c0);
  k_cast<<<1744, 256, 0, stream>>>(Whh, Wih, Wp1, Wp2, Wo1, Wo2, Wv,
                                   Wcomb, Wp1b, Wp2b, Wo1b, Wo2b, Wvb);
  k_recur<<<32, 512, 0, stream>>>(zcp, tconp, h0, c0, Wcomb, Wp1b, Wp2b,
                                  bp1, bp2, jlo, jhi, ddp, hx, flags,
                                  Hseq, outJ, outA);
  k_post<<<320, 256, 0, stream>>>(Hseq, Wo1b, Wo2b, Wvb, bo1, bo2, bv,
                                  Wfk, bfk, pm, ps, outJ, out0, out3);
}

// Round 7
// 1122.013 us; speedup vs baseline: 3.1581x; 1.0740x over previous
//
#include <hip/hip_runtime.h>
#include <math.h>

#define B_ 256
#define T_ 200
#define H_ 256
#define DOF_ 12

typedef __bf16 bf16;
typedef __bf16 bf16x8 __attribute__((ext_vector_type(8)));
typedef float f32x4 __attribute__((ext_vector_type(4)));

#define XK 288      // gate GEMM K: 256 h + 12 prev + 20 zero pad
#define XPAD 296
#define P1PAD 264

#define PI_D 3.14159265358979323846

// ---- workspace byte offsets (all 16B aligned) ----
#define OFF_TF     0u
#define OFF_TCONP  10400u
#define OFF_ZCP    829600u
#define OFF_H0     1878176u
#define OFF_C0     2140320u
#define OFF_WCOMB  2402464u
#define OFF_WP1    2992288u
#define OFF_WP2    3123360u
#define OFF_WO1    3131552u
#define OFF_WO2    3262624u
#define OFF_WV     3270816u
// flags live inside Wvb's zero-pad rows 42..47 (3 KiB of dead space that k_cast
// zeroes every launch; k_post loads but discards those rows). 256 u32 = 1 KiB.
#define OFF_FLAGS  (OFF_WV + 21504u)
#define OFF_HX     3295392u    // 16 pairs * 2 slots * 2 halves * 4KB = 262144
#define OFF_HSEQ   3558400u    // 256*200*256*2

__device__ __forceinline__ float sigf(float x) { return 1.f / (1.f + __expf(-x)); }
__device__ __forceinline__ float tanh_f(float x) {
  float a = fabsf(x);
  float e = __expf(-2.f * a);
  float t = (1.f - e) / (1.f + e);
  return x < 0.f ? -t : t;
}

// light barrier: order LDS, leave global ops in flight
#define LBAR() asm volatile("s_waitcnt lgkmcnt(0)\n\ts_barrier" ::: "memory")

// zero the per-wave handshake flags (k_cast re-zeroes the same bytes too)
__global__ void k_zflags(unsigned int* flags) {
  int i = threadIdx.x;
  if (i < 256)
    __hip_atomic_store(&flags[i], 0u, __ATOMIC_RELAXED, __HIP_MEMORY_SCOPE_AGENT);
}

// ---------------- time features [T,13] ----------------
__global__ void k_tfeat(float* tf) {
  int i = blockIdx.x * blockDim.x + threadIdx.x;
  if (i >= T_ * 13) return;
  int t = i / 13, j = i % 13;
  float tv = (float)t / 199.f;
  float v;
  if (j == 0) v = tv;
  else {
    int k = (j - 1) >> 1;
    float f = (float)(1 << k);
    double arg = 2.0 * PI_D * (double)f * (double)tv;
    v = (j & 1) ? (float)sin(arg) : (float)cos(arg);
  }
  tf[i] = v;
}

// ------------- precompute tconp, zcp, h0, c0 (lane-packed layouts) -------------
__global__ void k_prep(const float* __restrict__ tf, const float* __restrict__ Wih,
                       const float* __restrict__ z,
                       const float* __restrict__ bih, const float* __restrict__ bhh,
                       const float* __restrict__ Whz, const float* __restrict__ bhz,
                       const float* __restrict__ Wcz, const float* __restrict__ bcz,
                       float* tconp, float* zcp, float* h0, float* c0) {
  int i = blockIdx.x * blockDim.x + threadIdx.x;
  if (i < 204800) {
    // tconp[t*1024 + half*512 + u_loc*4 + g]
    int g = i & 3, q = i >> 2;
    int m = q & 127, hm = (q >> 7) & 1, t = q >> 8;
    int n = g * 256 + 128 * hm + m;
    float s = 0.f;
    #pragma unroll
    for (int j = 0; j < 13; ++j) s += tf[t * 13 + j] * Wih[n * 89 + 76 + j];
    tconp[i] = s;
    return;
  }
  i -= 204800;
  if (i < 262144) {
    // zcp[((lbid*512 + tid)*4 + g)*4 + r] : lbid = pairk*2+half
    int r = i & 3, g = (i >> 2) & 3, tid = (i >> 4) & 511;
    int half = (i >> 13) & 1, pairk = i >> 14;
    int wv = tid >> 6, lr = tid & 15, lq = (tid >> 4) & 3;
    int b = pairk * 16 + lq * 4 + r;
    int n = g * 256 + 128 * half + 16 * wv + lr;
    float s = bih[n] + bhh[n];
    for (int k = 0; k < 64; ++k) s += z[b * 64 + k] * Wih[n * 89 + 12 + k];
    zcp[i] = s;
    return;
  }
  i -= 262144;
  if (i < 65536) {
    int b = i / 256, u = i % 256;
    float s = bhz[u];
    for (int k = 0; k < 64; ++k) s += z[b * 64 + k] * Whz[u * 64 + k];
    h0[i] = s;
    return;
  }
  i -= 65536;
  if (i < 65536) {
    int b = i / 256, u = i % 256;
    float s = bcz[u];
    for (int k = 0; k < 64; ++k) s += z[b * 64 + k] * Wcz[u * 64 + k];
    c0[i] = s;
  }
}

// ------------- bf16 weight casts -------------
__global__ void k_cast(const float* __restrict__ Whh, const float* __restrict__ Wih,
                       const float* __restrict__ Wp1, const float* __restrict__ Wp2,
                       const float* __restrict__ Wo1, const float* __restrict__ Wo2,
                       const float* __restrict__ Wv,
                       bf16* Wcomb, bf16* Wp1b, bf16* Wp2b, bf16* Wo1b,
                       bf16* Wo2b, bf16* Wvb) {
  int i = blockIdx.x * blockDim.x + threadIdx.x;
  if (i < 294912) {
    int n = i / XK, k = i % XK;
    float v = (k < 256) ? Whh[n * 256 + k]
            : ((k < 268) ? Wih[n * 89 + (k - 256)] : 0.f);
    Wcomb[i] = (bf16)v;
    return;
  }
  i -= 294912;
  if (i < 65536) { Wp1b[i] = (bf16)Wp1[i]; return; }
  i -= 65536;
  if (i < 4096) { int r = i / 256; Wp2b[i] = (bf16)((r < 12) ? Wp2[i] : 0.f); return; }
  i -= 4096;
  if (i < 65536) { Wo1b[i] = (bf16)Wo1[i]; return; }
  i -= 65536;
  if (i < 4096) { int r = i / 256; Wo2b[i] = (bf16)((r < 3) ? Wo2[i] : 0.f); return; }
  i -= 4096;
  if (i < 12288) { int r = i / 256; Wvb[i] = (bf16)((r < 42) ? Wv[i] : 0.f); }
}

// ------- recurrent LSTM: 32 blocks = 16 batch-groups x 2 unit-halves -------
// Partner = bid^8 (same bid%8 -> same XCD). Per-WAVE handshake: wave wv only
// needs partner wave wv's units, so each wave publishes {hx, vmcnt(0), flag}
// and spins independently -- no block barrier in the exchange path.
__global__ __launch_bounds__(512)
__attribute__((amdgpu_waves_per_eu(2, 2))) void k_recur(
    const float* __restrict__ zcp, const float* __restrict__ tconp,
    const float* __restrict__ h0, const float* __restrict__ c0,
    const bf16* __restrict__ Wcomb, const bf16* __restrict__ Wp1b,
    const bf16* __restrict__ Wp2b,
    const float* __restrict__ bp1, const float* __restrict__ bp2,
    const float* __restrict__ jlo, const float* __restrict__ jhi,
    const float* __restrict__ ddp,
    unsigned long long* hx, unsigned int* flags,
    bf16* __restrict__ Hseq, float* __restrict__ outJ, float* __restrict__ outA) {
  __shared__ bf16 xbuf[16][XPAD];
  __shared__ bf16 w1[272][P1PAD];      // 0..255 Wp1, 256..271 Wp2
  __shared__ bf16 p1buf[16][P1PAD];
  const int tid = threadIdx.x;
  const int wv = tid >> 6, ln = tid & 63, lr = ln & 15, lq = ln >> 4;
  const int bid = blockIdx.x;
  const int pairk = ((bid >> 4) << 3) | (bid & 7);   // bid^8 shares this
  const int half = (bid >> 3) & 1;
  const int lbid = pairk * 2 + half;
  const int pbid = bid ^ 8;
  const int b0 = pairk * 16;
  const int u_loc = 16 * wv + lr;
  const int u_gl = 128 * half + u_loc;

  // ---- one-time LDS fills ----
  for (int i = tid; i < 272 * 32; i += 512) {
    int r = i >> 5, c8 = (i & 31) * 8;
    bf16x8 v = (r < 256)
      ? *reinterpret_cast<const bf16x8*>(&Wp1b[r * 256 + c8])
      : *reinterpret_cast<const bf16x8*>(&Wp2b[(r - 256) * 256 + c8]);
    *reinterpret_cast<bf16x8*>(&w1[r][c8]) = v;
  }
  for (int i = tid; i < 16 * XPAD; i += 512) {
    int r = i / XPAD, c = i % XPAD;
    float v = 0.f;
    if (c < 256) v = h0[(b0 + r) * 256 + c];
    else if (c < 268) {
      int d = c - 256;
      float lo = jlo[d], hi = jhi[d];
      v = (ddp[d] - 0.5f * (hi + lo)) / (0.5f * (hi - lo));
    }
    xbuf[r][c] = (bf16)v;
  }

  // ---- gate weights -> registers, laundered so the loads can't be
  // rematerialized or sunk into the loop ----
  bf16x8 wc[4][9];
  #pragma unroll
  for (int g = 0; g < 4; ++g)
    #pragma unroll
    for (int kt = 0; kt < 9; ++kt) {
      wc[g][kt] = *reinterpret_cast<const bf16x8*>(
          &Wcomb[(size_t)(g * 256 + u_gl) * XK + kt * 32 + lq * 8]);
      f32x4 tmp = __builtin_bit_cast(f32x4, wc[g][kt]);
      asm volatile("" : "+v"(tmp));
      wc[g][kt] = __builtin_bit_cast(bf16x8, tmp);
    }

  // ---- per-lane state ----
  float c_reg[4];
  #pragma unroll
  for (int r = 0; r < 4; ++r) c_reg[r] = c0[(b0 + lq * 4 + r) * 256 + u_gl];
  f32x4 zcreg[4];
  #pragma unroll
  for (int g = 0; g < 4; ++g)
    zcreg[g] = *reinterpret_cast<const f32x4*>(
        zcp + ((size_t)lbid * 512 + tid) * 16 + g * 4);
  const float* tcb = tconp + (size_t)(half * 512 + u_loc * 4);
  const float bp1r0 = bp1[32 * wv + lr];
  const float bp1r1 = bp1[32 * wv + 16 + lr];
  float bp2r = 0.f, ddr = 0.f, lor = -1.f, hir = 1.f;
  if (lr < 12) { bp2r = bp2[lr]; ddr = ddp[lr]; lor = jlo[lr]; hir = jhi[lr]; }
  const float jmr = 0.5f * (hir + lor), jrr = 0.5f * (hir - lor);
  bf16* hs = Hseq + ((size_t)(b0 + lq * 4) * T_) * 256 + u_gl;

  // handshake addresses (hoisted)
  unsigned int* myf = &flags[bid * 8 + wv];
  unsigned int* pf  = &flags[pbid * 8 + wv];
  const int wru = 16 * wv + (ln >> 2), wrc = ln & 3;   // partner read mapping
  const int rcol = 128 * (half ^ 1) + wru;
  unsigned long long* hxw0 = &hx[(((size_t)(pairk * 2 + 0) * 2 + half) * 128 + u_loc) * 4 + lq];
  unsigned long long* hxw1 = &hx[(((size_t)(pairk * 2 + 1) * 2 + half) * 128 + u_loc) * 4 + lq];
  unsigned long long* hxr0 = &hx[(((size_t)(pairk * 2 + 0) * 2 + (half ^ 1)) * 128 + wru) * 4 + wrc];
  unsigned long long* hxr1 = &hx[(((size_t)(pairk * 2 + 1) * 2 + (half ^ 1)) * 128 + wru) * 4 + wrc];

  f32x4 tcv = *reinterpret_cast<const f32x4*>(tcb);  // t=0
  __syncthreads();
  bool dead = false;

  for (int t = 0; t < T_; ++t) {
    // ---- gates: kt-outer (one A fragment live at a time) ----
    f32x4 ac[4];
    #pragma unroll
    for (int g = 0; g < 4; ++g) ac[g] = zcreg[g] + tcv[g];
    #pragma unroll
    for (int kt = 0; kt < 9; ++kt) {
      bf16x8 a = *reinterpret_cast<const bf16x8*>(&xbuf[lr][kt * 32 + lq * 8]);
      #pragma unroll
      for (int g = 0; g < 4; ++g)
        ac[g] = __builtin_amdgcn_mfma_f32_16x16x32_bf16(a, wc[g][kt], ac[g], 0, 0, 0);
    }
    LBAR();  // all xbuf reads done before h overwrite

    // ---- LSTM elementwise; own h -> xbuf + pack ----
    union { unsigned long long v; unsigned short s[4]; } pk;
    bf16 hb4[4];
    #pragma unroll
    for (int r = 0; r < 4; ++r) {
      float cn = sigf(ac[1][r]) * c_reg[r] + sigf(ac[0][r]) * tanh_f(ac[2][r]);
      float hn = sigf(ac[3][r]) * tanh_f(cn);
      c_reg[r] = cn;
      bf16 hb = (bf16)hn;
      hb4[r] = hb;
      xbuf[lq * 4 + r][u_gl] = hb;
      pk.s[r] = __builtin_bit_cast(unsigned short, hb);
    }
    // ---- per-wave publish: hx store -> wave-local vmcnt(0) -> flag ----
    __hip_atomic_store((t & 1) ? hxw1 : hxw0, pk.v,
                       __ATOMIC_RELAXED, __HIP_MEMORY_SCOPE_AGENT);
    asm volatile("s_waitcnt vmcnt(0)" ::: "memory");
    const unsigned int want = t + 1;
    if (ln == 0)
      __hip_atomic_store(myf, want, __ATOMIC_RELAXED, __HIP_MEMORY_SCOPE_AGENT);
    // overlap the spin: Hseq stores + next-step tcon prefetch
    #pragma unroll
    for (int r = 0; r < 4; ++r)
      hs[(size_t)r * (T_ * 256) + (size_t)t * 256] = hb4[r];
    f32x4 tcn = *reinterpret_cast<const f32x4*>(
        tcb + (size_t)((t + 1 < T_) ? t + 1 : t) * 1024);

    if (!dead) {
      int guard = 1 << 18;
      for (;;) {
        unsigned int fv =
            __hip_atomic_load(pf, __ATOMIC_RELAXED, __HIP_MEMORY_SCOPE_AGENT);
        if ((int)(fv - want) >= 0) break;
        if (--guard == 0) { dead = true; break; }
      }
    }
    unsigned long long pv = __hip_atomic_load((t & 1) ? hxr1 : hxr0,
                                              __ATOMIC_RELAXED,
                                              __HIP_MEMORY_SCOPE_AGENT);
    {
      unsigned short* ph = (unsigned short*)&pv;
      #pragma unroll
      for (int j = 0; j < 4; ++j)
        xbuf[wrc * 4 + j][rcol] = __builtin_bit_cast(bf16, ph[j]);
    }
    LBAR();  // full h_new visible

    // ---- p1 = relu(h_new @ Wp1^T + bp1), kt-outer ----
    {
      f32x4 acc0 = {bp1r0, bp1r0, bp1r0, bp1r0};
      f32x4 acc1 = {bp1r1, bp1r1, bp1r1, bp1r1};
      #pragma unroll
      for (int kt = 0; kt < 8; ++kt) {
        bf16x8 av = *reinterpret_cast<const bf16x8*>(&xbuf[lr][kt * 32 + lq * 8]);
        bf16x8 b0v = *reinterpret_cast<const bf16x8*>(&w1[32 * wv + lr][kt * 32 + lq * 8]);
        bf16x8 b1v = *reinterpret_cast<const bf16x8*>(&w1[32 * wv + 16 + lr][kt * 32 + lq * 8]);
        acc0 = __builtin_amdgcn_mfma_f32_16x16x32_bf16(av, b0v, acc0, 0, 0, 0);
        acc1 = __builtin_amdgcn_mfma_f32_16x16x32_bf16(av, b1v, acc1, 0, 0, 0);
      }
      #pragma unroll
      for (int r = 0; r < 4; ++r) {
        p1buf[lq * 4 + r][32 * wv + lr] = (bf16)fmaxf(acc0[r], 0.f);
        p1buf[lq * 4 + r][32 * wv + 16 + lr] = (bf16)fmaxf(acc1[r], 0.f);
      }
    }
    LBAR();  // p1 visible

    // ---- action head on wave 0 (redundant across halves; writes gated) ----
    if (wv == 0) {
      f32x4 acc = {0.f, 0.f, 0.f, 0.f};
      #pragma unroll
      for (int kt = 0; kt < 8; ++kt) {
        bf16x8 ap = *reinterpret_cast<const bf16x8*>(&p1buf[lr][kt * 32 + lq * 8]);
        bf16x8 w2 = *reinterpret_cast<const bf16x8*>(&w1[256 + lr][kt * 32 + lq * 8]);
        acc = __builtin_amdgcn_mfma_f32_16x16x32_bf16(ap, w2, acc, 0, 0, 0);
      }
      if (lr < 12) {
        #pragma unroll
        for (int r = 0; r < 4; ++r) {
          int b = lq * 4 + r;
          float act = tanh_f(acc[r] + bp2r);
          float curp = act * 0.25f + ddr;   // TRACK_ALPHA = 1
          float cl = fminf(fmaxf(curp, lor), hir);
          if (half == 0) {
            size_t o = ((size_t)(b0 + b) * T_ + t) * 12 + lr;
            outA[o] = act;
            outJ[o] = curp;
          }
          xbuf[b][256 + lr] = (bf16)((cl - jmr) / jrr);
        }
      }
    }
    LBAR();  // prev_norm visible for next step
    tcv = tcn;
  }
}

// ------------- post pass: obj head, sigma head, FK, normalize -------------
__global__ __launch_bounds__(256) void k_post(
    const bf16* __restrict__ Hseq, const bf16* __restrict__ Wo1b,
    const bf16* __restrict__ Wo2b, const bf16* __restrict__ Wvb,
    const float* __restrict__ bo1, const float* __restrict__ bo2,
    const float* __restrict__ bv,
    const float* __restrict__ Wfk, const float* __restrict__ bfk,
    const float* __restrict__ pm, const float* __restrict__ ps,
    const float* __restrict__ joints, float* __restrict__ out0,
    float* __restrict__ out3) {
  __shared__ bf16 u1buf[16][P1PAD];
  __shared__ float objbuf[16][3];
  __shared__ float jbuf[16][12];
  const int tid = threadIdx.x;
  const int wv = tid >> 6;
  const int ln = tid & 63;
  const int lr = ln & 15;
  const int lq = ln >> 4;

  bf16x8 wo1f[4][8];
  float bo1r[4];
  #pragma unroll
  for (int jn = 0; jn < 4; ++jn) {
    int n0 = wv * 64 + jn * 16;
    bo1r[jn] = bo1[n0 + lr];
    #pragma unroll
    for (int kt = 0; kt < 8; ++kt)
      wo1f[jn][kt] = *reinterpret_cast<const bf16x8*>(
          &Wo1b[(size_t)(n0 + lr) * 256 + kt * 32 + lq * 8]);
  }
  const int col = (wv - 1) * 16 + lr;
  bf16x8 wvf[8];
  float bvr = 0.f;
  if (wv >= 1) {
    #pragma unroll
    for (int kt = 0; kt < 8; ++kt)
      wvf[kt] = *reinterpret_cast<const bf16x8*>(
          &Wvb[(size_t)col * 256 + kt * 32 + lq * 8]);
    bvr = (col < 42) ? bv[col] : 0.f;
  }
  bf16x8 wo2f[8];
  if (wv == 0) {
    #pragma unroll
    for (int kt = 0; kt < 8; ++kt)
      wo2f[kt] = *reinterpret_cast<const bf16x8*>(
          &Wo2b[(size_t)lr * 256 + kt * 32 + lq * 8]);
  }

  for (int it = 0; it < 10; ++it) {
    int tt = blockIdx.x * 10 + it;
    size_t r0 = (size_t)tt * 16;
    bf16x8 ah[8];
    #pragma unroll
    for (int kt = 0; kt < 8; ++kt)
      ah[kt] = *reinterpret_cast<const bf16x8*>(&Hseq[(r0 + lr) * 256 + kt * 32 + lq * 8]);
    #pragma unroll
    for (int jn = 0; jn < 4; ++jn) {
      int n0 = wv * 64 + jn * 16;
      float bb = bo1r[jn];
      f32x4 acc = {bb, bb, bb, bb};
      #pragma unroll
      for (int kt = 0; kt < 8; ++kt)
        acc = __builtin_amdgcn_mfma_f32_16x16x32_bf16(ah[kt], wo1f[jn][kt], acc, 0, 0, 0);
      #pragma unroll
      for (int r = 0; r < 4; ++r)
        u1buf[lq * 4 + r][n0 + lr] = (bf16)fmaxf(acc[r], 0.f);
    }
    if (wv >= 1) {
      f32x4 acc = {bvr, bvr, bvr, bvr};
      #pragma unroll
      for (int kt = 0; kt < 8; ++kt)
        acc = __builtin_amdgcn_mfma_f32_16x16x32_bf16(ah[kt], wvf[kt], acc, 0, 0, 0);
      if (col < 42) {
        #pragma unroll
        for (int r = 0; r < 4; ++r) {
          float s = 0.05f + 0.45f * sigf(acc[r]);
          out3[(r0 + lq * 4 + r) * 42 + col] = __logf(s);
        }
      }
    }
    if (tid < 192) {
      int rr = tid / 12, d = tid % 12;
      jbuf[rr][d] = joints[(r0 + rr) * 12 + d];
    }
    __syncthreads();
    if (wv == 0) {
      bf16x8 ap[8];
      #pragma unroll
      for (int kt = 0; kt < 8; ++kt)
        ap[kt] = *reinterpret_cast<const bf16x8*>(&u1buf[lr][kt * 32 + lq * 8]);
      f32x4 acc = {0.f, 0.f, 0.f, 0.f};
      #pragma unroll
      for (int kt = 0; kt < 8; ++kt)
        acc = __builtin_amdgcn_mfma_f32_16x16x32_bf16(ap[kt], wo2f[kt], acc, 0, 0, 0);
      if (lr < 3) {
        #pragma unroll
        for (int r = 0; r < 4; ++r)
          objbuf[lq * 4 + r][lr] = acc[r] + bo2[lr];
      }
    }
    __syncthreads();
    for (int e = tid; e < 16 * 42; e += 256) {
      int rr = e / 42, pd = e % 42;
      float v;
      if (pd < 39) {
        float s = bfk[pd];
        #pragma unroll
        for (int d = 0; d < 12; ++d) s += jbuf[rr][d] * Wfk[pd * 12 + d];
        v = s;
      } else v = objbuf[rr][pd - 39];
      out0[(r0 + rr) * 42 + pd] = (v - pm[pd]) / ps[pd];
    }
    __syncthreads();
  }
}

extern "C" void kernel_launch(void* const* d_in, const int* in_sizes, int n_in,
                              void* d_out, int out_size, void* d_ws, size_t ws_size,
                              hipStream_t stream) {
  const float* z   = (const float*)d_in[0];
  const float* Whz = (const float*)d_in[1];
  const float* bhz = (const float*)d_in[2];
  const float* Wcz = (const float*)d_in[3];
  const float* bcz = (const float*)d_in[4];
  const float* Wih = (const float*)d_in[5];
  const float* Whh = (const float*)d_in[6];
  const float* bih = (const float*)d_in[7];
  const float* bhh = (const float*)d_in[8];
  const float* Wp1 = (const float*)d_in[9];
  const float* bp1 = (const float*)d_in[10];
  const float* Wp2 = (const float*)d_in[11];
  const float* bp2 = (const float*)d_in[12];
  const float* Wo1 = (const float*)d_in[13];
  const float* bo1 = (const float*)d_in[14];
  const float* Wo2 = (const float*)d_in[15];
  const float* bo2 = (const float*)d_in[16];
  const float* Wv  = (const float*)d_in[17];
  const float* bv  = (const float*)d_in[18];
  const float* Wfk = (const float*)d_in[19];
  const float* bfk = (const float*)d_in[20];
  const float* pm  = (const float*)d_in[21];
  const float* ps  = (const float*)d_in[22];
  const float* jlo = (const float*)d_in[23];
  const float* jhi = (const float*)d_in[24];
  const float* ddp = (const float*)d_in[25];

  char* ws = (char*)d_ws;
  float* tf    = (float*)(ws + OFF_TF);
  float* tconp = (float*)(ws + OFF_TCONP);
  float* zcp   = (float*)(ws + OFF_ZCP);
  float* h0    = (float*)(ws + OFF_H0);
  float* c0    = (float*)(ws + OFF_C0);
  bf16* Wcomb  = (bf16*)(ws + OFF_WCOMB);
  bf16* Wp1b   = (bf16*)(ws + OFF_WP1);
  bf16* Wp2b   = (bf16*)(ws + OFF_WP2);
  bf16* Wo1b   = (bf16*)(ws + OFF_WO1);
  bf16* Wo2b   = (bf16*)(ws + OFF_WO2);
  bf16* Wvb    = (bf16*)(ws + OFF_WV);
  unsigned long long* hx = (unsigned long long*)(ws + OFF_HX);
  unsigned int* flags    = (unsigned int*)(ws + OFF_FLAGS);
  bf16* Hseq   = (bf16*)(ws + OFF_HSEQ);

  float* out  = (float*)d_out;
  float* out0 = out;                 // graph_x_mu [B,T,42]
  float* outJ = out + 2150400;       // joint_traj [B,T,12]
  float* outA = out + 2764800;       // actions    [B,T,12]
  float* out3 = out + 3379200;       // log_sigma  [B,T,42]

  k_zflags<<<1, 256, 0, stream>>>(flags);
  k_tfeat<<<11, 256, 0, stream>>>(tf);
  k_prep<<<2336, 256, 0, stream>>>(tf, Wih, z, bih, bhh, Whz, bhz, Wcz, bcz,
                                   tconp, zcp, h0, c0);
  k_cast<<<1744, 256, 0, stream>>>(Whh, Wih, Wp1, Wp2, Wo1, Wo2, Wv,
                                   Wcomb, Wp1b, Wp2b, Wo1b, Wo2b, Wvb);
  k_recur<<<32, 512, 0, stream>>>(zcp, tconp, h0, c0, Wcomb, Wp1b, Wp2b,
                                  bp1, bp2, jlo, jhi, ddp, hx, flags,
                                  Hseq, outJ, outA);
  k_post<<<320, 256, 0, stream>>>(Hseq, Wo1b, Wo2b, Wvb, bo1, bo2, bv,
                                  Wfk, bfk, pm, ps, outJ, out0, out3);
}

// Round 9
// 1118.513 us; speedup vs baseline: 3.1680x; 1.0031x over previous
//
#include <hip/hip_runtime.h>
#include <math.h>

#define B_ 256
#define T_ 200
#define H_ 256
#define DOF_ 12

typedef __bf16 bf16;
typedef __bf16 bf16x8 __attribute__((ext_vector_type(8)));
typedef float f32x4 __attribute__((ext_vector_type(4)));
typedef unsigned long long u64;

#define XK 288      // gate GEMM K: 256 h + 12 prev + 20 zero pad
#define XPAD 296
#define P1PAD 264

#define PI_D 3.14159265358979323846

// ---- workspace byte offsets (all 16B aligned) ----
#define OFF_TF     0u
#define OFF_TCONP  10400u
#define OFF_ZCP    829600u
#define OFF_H0     1878176u
#define OFF_C0     2140320u
#define OFF_WCOMB  2402464u
#define OFF_WP1    2992288u
#define OFF_WP2    3123360u
#define OFF_WO1    3131552u
#define OFF_WO2    3262624u
#define OFF_WV     3270816u
#define OFF_HX     3295392u    // 16 pairs * 2 slots * 2 halves * 128 * 4 * 16B = 512KB
#define OFF_HSEQ   3819680u    // 256*200*256*2 = 26214400 (end ~30.0MB)

__device__ __forceinline__ float sigf(float x) { return 1.f / (1.f + __expf(-x)); }
__device__ __forceinline__ float tanh_f(float x) {
  float a = fabsf(x);
  float e = __expf(-2.f * a);
  float t = (1.f - e) / (1.f + e);
  return x < 0.f ? -t : t;
}

// light barrier: order LDS, leave global ops in flight
#define LBAR() asm volatile("s_waitcnt lgkmcnt(0)\n\ts_barrier" ::: "memory")

// ---------------- time features [T,13] ----------------
__global__ void k_tfeat(float* tf) {
  int i = blockIdx.x * blockDim.x + threadIdx.x;
  if (i >= T_ * 13) return;
  int t = i / 13, j = i % 13;
  float tv = (float)t / 199.f;
  float v;
  if (j == 0) v = tv;
  else {
    int k = (j - 1) >> 1;
    float f = (float)(1 << k);
    double arg = 2.0 * PI_D * (double)f * (double)tv;
    v = (j & 1) ? (float)sin(arg) : (float)cos(arg);
  }
  tf[i] = v;
}

// ------------- precompute tconp, zcp, h0, c0 (lane-packed layouts) -------------
__global__ void k_prep(const float* __restrict__ tf, const float* __restrict__ Wih,
                       const float* __restrict__ z,
                       const float* __restrict__ bih, const float* __restrict__ bhh,
                       const float* __restrict__ Whz, const float* __restrict__ bhz,
                       const float* __restrict__ Wcz, const float* __restrict__ bcz,
                       float* tconp, float* zcp, float* h0, float* c0) {
  int i = blockIdx.x * blockDim.x + threadIdx.x;
  if (i < 204800) {
    // tconp[t*1024 + half*512 + u_loc*4 + g]
    int g = i & 3, q = i >> 2;
    int m = q & 127, hm = (q >> 7) & 1, t = q >> 8;
    int n = g * 256 + 128 * hm + m;
    float s = 0.f;
    #pragma unroll
    for (int j = 0; j < 13; ++j) s += tf[t * 13 + j] * Wih[n * 89 + 76 + j];
    tconp[i] = s;
    return;
  }
  i -= 204800;
  if (i < 262144) {
    // zcp[((lbid*512 + tid)*4 + g)*4 + r] : lbid = pairk*2+half
    int r = i & 3, g = (i >> 2) & 3, tid = (i >> 4) & 511;
    int half = (i >> 13) & 1, pairk = i >> 14;
    int wv = tid >> 6, lr = tid & 15, lq = (tid >> 4) & 3;
    int b = pairk * 16 + lq * 4 + r;
    int n = g * 256 + 128 * half + 16 * wv + lr;
    float s = bih[n] + bhh[n];
    for (int k = 0; k < 64; ++k) s += z[b * 64 + k] * Wih[n * 89 + 12 + k];
    zcp[i] = s;
    return;
  }
  i -= 262144;
  if (i < 65536) {
    int b = i / 256, u = i % 256;
    float s = bhz[u];
    for (int k = 0; k < 64; ++k) s += z[b * 64 + k] * Whz[u * 64 + k];
    h0[i] = s;
    return;
  }
  i -= 65536;
  if (i < 65536) {
    int b = i / 256, u = i % 256;
    float s = bcz[u];
    for (int k = 0; k < 64; ++k) s += z[b * 64 + k] * Wcz[u * 64 + k];
    c0[i] = s;
  }
}

// ------------- bf16 weight casts -------------
__global__ void k_cast(const float* __restrict__ Whh, const float* __restrict__ Wih,
                       const float* __restrict__ Wp1, const float* __restrict__ Wp2,
                       const float* __restrict__ Wo1, const float* __restrict__ Wo2,
                       const float* __restrict__ Wv,
                       bf16* Wcomb, bf16* Wp1b, bf16* Wp2b, bf16* Wo1b,
                       bf16* Wo2b, bf16* Wvb) {
  int i = blockIdx.x * blockDim.x + threadIdx.x;
  if (i < 294912) {
    int n = i / XK, k = i % XK;
    float v = (k < 256) ? Whh[n * 256 + k]
            : ((k < 268) ? Wih[n * 89 + (k - 256)] : 0.f);
    Wcomb[i] = (bf16)v;
    return;
  }
  i -= 294912;
  if (i < 65536) { Wp1b[i] = (bf16)Wp1[i]; return; }
  i -= 65536;
  if (i < 4096) { int r = i / 256; Wp2b[i] = (bf16)((r < 12) ? Wp2[i] : 0.f); return; }
  i -= 4096;
  if (i < 65536) { Wo1b[i] = (bf16)Wo1[i]; return; }
  i -= 65536;
  if (i < 4096) { int r = i / 256; Wo2b[i] = (bf16)((r < 3) ? Wo2[i] : 0.f); return; }
  i -= 4096;
  if (i < 12288) { int r = i / 256; Wvb[i] = (bf16)((r < 42) ? Wv[i] : 0.f); }
}

// ------- recurrent LSTM: 32 blocks = 16 batch-groups x 2 unit-halves -------
// Gate weights pinned in AGPRs (144/lane); Wp1+Wp2 in LDS. Per-wave h exchange
// via tag-embedded u64 relaxed agent atomics (no flag, no vmcnt drain).
__global__ __launch_bounds__(512, 2) void k_recur(
    const float* __restrict__ zcp, const float* __restrict__ tconp,
    const float* __restrict__ h0, const float* __restrict__ c0,
    const bf16* __restrict__ Wcomb, const bf16* __restrict__ Wp1b,
    const bf16* __restrict__ Wp2b,
    const float* __restrict__ bp1, const float* __restrict__ bp2,
    const float* __restrict__ jlo, const float* __restrict__ jhi,
    const float* __restrict__ ddp,
    u64* hxt,
    bf16* __restrict__ Hseq, float* __restrict__ outJ, float* __restrict__ outA) {
  __shared__ bf16 xbuf[16][XPAD];
  __shared__ bf16 w1[272][P1PAD];      // 0..255 Wp1, 256..271 Wp2
  __shared__ bf16 p1buf[16][P1PAD];
  const int tid = threadIdx.x;
  const int wv = tid >> 6, ln = tid & 63, lr = ln & 15, lq = ln >> 4;
  const int bid = blockIdx.x;
  const int pairk = ((bid >> 4) << 3) | (bid & 7);   // bid^8 shares this
  const int half = (bid >> 3) & 1;
  const int lbid = pairk * 2 + half;
  const int b0 = pairk * 16;
  const int u_loc = 16 * wv + lr;
  const int u_gl = 128 * half + u_loc;

  // ---- one-time LDS fills ----
  for (int i = tid; i < 272 * 32; i += 512) {
    int r = i >> 5, c8 = (i & 31) * 8;
    bf16x8 v = (r < 256)
      ? *reinterpret_cast<const bf16x8*>(&Wp1b[r * 256 + c8])
      : *reinterpret_cast<const bf16x8*>(&Wp2b[(r - 256) * 256 + c8]);
    *reinterpret_cast<bf16x8*>(&w1[r][c8]) = v;
  }
  for (int i = tid; i < 16 * XPAD; i += 512) {
    int r = i / XPAD, c = i % XPAD;
    float v = 0.f;
    if (c < 256) v = h0[(b0 + r) * 256 + c];
    else if (c < 268) {
      int d = c - 256;
      float lo = jlo[d], hi = jhi[d];
      v = (ddp[d] - 0.5f * (hi + lo)) / (0.5f * (hi - lo));
    }
    xbuf[r][c] = (bf16)v;
  }

  // ---- gate weights -> AGPRs (144 regs/lane, pinned by "a"-class asm) ----
  f32x4 wc0[9], wc1[9], wc2[9], wc3[9];
  #pragma unroll
  for (int kt = 0; kt < 9; ++kt) {
    wc0[kt] = *reinterpret_cast<const f32x4*>(&Wcomb[(size_t)(0 * 256 + u_gl) * XK + kt * 32 + lq * 8]);
    wc1[kt] = *reinterpret_cast<const f32x4*>(&Wcomb[(size_t)(1 * 256 + u_gl) * XK + kt * 32 + lq * 8]);
    wc2[kt] = *reinterpret_cast<const f32x4*>(&Wcomb[(size_t)(2 * 256 + u_gl) * XK + kt * 32 + lq * 8]);
    wc3[kt] = *reinterpret_cast<const f32x4*>(&Wcomb[(size_t)(3 * 256 + u_gl) * XK + kt * 32 + lq * 8]);
    asm volatile("" : "+a"(wc0[kt]), "+a"(wc1[kt]), "+a"(wc2[kt]), "+a"(wc3[kt]));
  }

  // ---- per-lane state ----
  float c_reg[4];
  #pragma unroll
  for (int r = 0; r < 4; ++r) c_reg[r] = c0[(b0 + lq * 4 + r) * 256 + u_gl];
  f32x4 zcreg[4];
  #pragma unroll
  for (int g = 0; g < 4; ++g)
    zcreg[g] = *reinterpret_cast<const f32x4*>(
        zcp + ((size_t)lbid * 512 + tid) * 16 + g * 4);
  const float* tcb = tconp + (size_t)(half * 512 + u_loc * 4);
  const float bp1r0 = bp1[32 * wv + lr];
  const float bp1r1 = bp1[32 * wv + 16 + lr];
  float bp2r = 0.f, ddr = 0.f, lor = -1.f, hir = 1.f;
  if (lr < 12) { bp2r = bp2[lr]; ddr = ddp[lr]; lor = jlo[lr]; hir = jhi[lr]; }
  const float jmr = 0.5f * (hir + lor), jrr = 0.5f * (hir - lor);
  bf16* hs = Hseq + ((size_t)(b0 + lq * 4) * T_) * 256 + u_gl;

  // tag-exchange addresses: entry [pairk][slot][half][u_loc][lq] = 2 u64
  const int wru = 16 * wv + (ln >> 2), wrc = ln & 3;
  const int rcol = 128 * (half ^ 1) + wru;
  u64* pws0 = hxt + ((((size_t)(pairk * 2 + 0) * 2 + half) * 128 + u_loc) * 4 + lq) * 2;
  u64* pws1 = hxt + ((((size_t)(pairk * 2 + 1) * 2 + half) * 128 + u_loc) * 4 + lq) * 2;
  u64* prs0 = hxt + ((((size_t)(pairk * 2 + 0) * 2 + (half ^ 1)) * 128 + wru) * 4 + wrc) * 2;
  u64* prs1 = hxt + ((((size_t)(pairk * 2 + 1) * 2 + (half ^ 1)) * 128 + wru) * 4 + wrc) * 2;

  f32x4 tcv = *reinterpret_cast<const f32x4*>(tcb);  // t=0
  __syncthreads();
  bool dead = false;

  for (int t = 0; t < T_; ++t) {
    // ---- gates: kt-outer; weights consumed straight from AGPRs ----
    f32x4 ac[4];
    #pragma unroll
    for (int g = 0; g < 4; ++g) ac[g] = zcreg[g] + tcv[g];
    #pragma unroll
    for (int kt = 0; kt < 9; ++kt) {
      bf16x8 a = *reinterpret_cast<const bf16x8*>(&xbuf[lr][kt * 32 + lq * 8]);
      // re-pin each iteration: loop-carried a-class, cannot be spilled/remat'd
      asm volatile("" : "+a"(wc0[kt]), "+a"(wc1[kt]), "+a"(wc2[kt]), "+a"(wc3[kt]));
      ac[0] = __builtin_amdgcn_mfma_f32_16x16x32_bf16(a, __builtin_bit_cast(bf16x8, wc0[kt]), ac[0], 0, 0, 0);
      ac[1] = __builtin_amdgcn_mfma_f32_16x16x32_bf16(a, __builtin_bit_cast(bf16x8, wc1[kt]), ac[1], 0, 0, 0);
      ac[2] = __builtin_amdgcn_mfma_f32_16x16x32_bf16(a, __builtin_bit_cast(bf16x8, wc2[kt]), ac[2], 0, 0, 0);
      ac[3] = __builtin_amdgcn_mfma_f32_16x16x32_bf16(a, __builtin_bit_cast(bf16x8, wc3[kt]), ac[3], 0, 0, 0);
    }
    LBAR();  // all xbuf reads done before h overwrite

    // ---- LSTM elementwise ----
    union { u64 v[1]; unsigned short s[4]; } pk;
    bf16 hb4[4];
    #pragma unroll
    for (int r = 0; r < 4; ++r) {
      float cn = sigf(ac[1][r]) * c_reg[r] + sigf(ac[0][r]) * tanh_f(ac[2][r]);
      float hn = sigf(ac[3][r]) * tanh_f(cn);
      c_reg[r] = cn;
      bf16 hb = (bf16)hn;
      hb4[r] = hb;
      pk.s[r] = __builtin_bit_cast(unsigned short, hb);
    }
    // ---- publish FIRST (tag-embedded, no fence/flag) ----
    const unsigned int want = t + 1;
    {
      u64 q0 = ((u64)want << 32) | (u64)pk.s[0] | ((u64)pk.s[1] << 16);
      u64 q1 = ((u64)want << 32) | (u64)pk.s[2] | ((u64)pk.s[3] << 16);
      u64* pw = (t & 1) ? pws1 : pws0;
      __hip_atomic_store(pw, q0, __ATOMIC_RELAXED, __HIP_MEMORY_SCOPE_AGENT);
      __hip_atomic_store(pw + 1, q1, __ATOMIC_RELAXED, __HIP_MEMORY_SCOPE_AGENT);
    }
    // own h -> xbuf + Hseq; next tcon prefetch (overlap partner latency)
    #pragma unroll
    for (int r = 0; r < 4; ++r) {
      xbuf[lq * 4 + r][u_gl] = hb4[r];
      hs[(size_t)r * (T_ * 256) + (size_t)t * 256] = hb4[r];
    }
    f32x4 tcn = *reinterpret_cast<const f32x4*>(
        tcb + (size_t)((t + 1 < T_) ? t + 1 : t) * 1024);

    // ---- poll partner payload (self-validating tags) ----
    u64 pq0, pq1;
    {
      u64* pr = (t & 1) ? prs1 : prs0;
      int guard = 1 << 16;
      for (;;) {
        pq0 = __hip_atomic_load(pr, __ATOMIC_RELAXED, __HIP_MEMORY_SCOPE_AGENT);
        pq1 = __hip_atomic_load(pr + 1, __ATOMIC_RELAXED, __HIP_MEMORY_SCOPE_AGENT);
        int ok = ((unsigned)(pq0 >> 32) == want) & ((unsigned)(pq1 >> 32) == want);
        if (__all(ok)) break;
        if (dead || --guard == 0) { dead = true; break; }
      }
    }
    xbuf[wrc * 4 + 0][rcol] = __builtin_bit_cast(bf16, (unsigned short)(pq0));
    xbuf[wrc * 4 + 1][rcol] = __builtin_bit_cast(bf16, (unsigned short)(pq0 >> 16));
    xbuf[wrc * 4 + 2][rcol] = __builtin_bit_cast(bf16, (unsigned short)(pq1));
    xbuf[wrc * 4 + 3][rcol] = __builtin_bit_cast(bf16, (unsigned short)(pq1 >> 16));
    LBAR();  // full h_new visible

    // ---- p1 = relu(h_new @ Wp1^T + bp1), LDS weights ----
    {
      f32x4 acc0 = {bp1r0, bp1r0, bp1r0, bp1r0};
      f32x4 acc1 = {bp1r1, bp1r1, bp1r1, bp1r1};
      #pragma unroll
      for (int kt = 0; kt < 8; ++kt) {
        bf16x8 av = *reinterpret_cast<const bf16x8*>(&xbuf[lr][kt * 32 + lq * 8]);
        bf16x8 b0v = *reinterpret_cast<const bf16x8*>(&w1[32 * wv + lr][kt * 32 + lq * 8]);
        bf16x8 b1v = *reinterpret_cast<const bf16x8*>(&w1[32 * wv + 16 + lr][kt * 32 + lq * 8]);
        acc0 = __builtin_amdgcn_mfma_f32_16x16x32_bf16(av, b0v, acc0, 0, 0, 0);
        acc1 = __builtin_amdgcn_mfma_f32_16x16x32_bf16(av, b1v, acc1, 0, 0, 0);
      }
      #pragma unroll
      for (int r = 0; r < 4; ++r) {
        p1buf[lq * 4 + r][32 * wv + lr] = (bf16)fmaxf(acc0[r], 0.f);
        p1buf[lq * 4 + r][32 * wv + 16 + lr] = (bf16)fmaxf(acc1[r], 0.f);
      }
    }
    LBAR();  // p1 visible

    // ---- action head on wave 0 (redundant across halves; writes gated) ----
    if (wv == 0) {
      f32x4 acc = {0.f, 0.f, 0.f, 0.f};
      #pragma unroll
      for (int kt = 0; kt < 8; ++kt) {
        bf16x8 ap = *reinterpret_cast<const bf16x8*>(&p1buf[lr][kt * 32 + lq * 8]);
        bf16x8 w2 = *reinterpret_cast<const bf16x8*>(&w1[256 + lr][kt * 32 + lq * 8]);
        acc = __builtin_amdgcn_mfma_f32_16x16x32_bf16(ap, w2, acc, 0, 0, 0);
      }
      if (lr < 12) {
        #pragma unroll
        for (int r = 0; r < 4; ++r) {
          int b = lq * 4 + r;
          float act = tanh_f(acc[r] + bp2r);
          float curp = act * 0.25f + ddr;   // TRACK_ALPHA = 1
          float cl = fminf(fmaxf(curp, lor), hir);
          if (half == 0) {
            size_t o = ((size_t)(b0 + b) * T_ + t) * 12 + lr;
            outA[o] = act;
            outJ[o] = curp;
          }
          xbuf[b][256 + lr] = (bf16)((cl - jmr) / jrr);
        }
      }
    }
    LBAR();  // prev_norm visible for next step
    tcv = tcn;
  }
}

// ------------- post pass: obj head, sigma head, FK, normalize -------------
__global__ __launch_bounds__(256) void k_post(
    const bf16* __restrict__ Hseq, const bf16* __restrict__ Wo1b,
    const bf16* __restrict__ Wo2b, const bf16* __restrict__ Wvb,
    const float* __restrict__ bo1, const float* __restrict__ bo2,
    const float* __restrict__ bv,
    const float* __restrict__ Wfk, const float* __restrict__ bfk,
    const float* __restrict__ pm, const float* __restrict__ ps,
    const float* __restrict__ joints, float* __restrict__ out0,
    float* __restrict__ out3) {
  __shared__ bf16 u1buf[16][P1PAD];
  __shared__ float objbuf[16][3];
  __shared__ float jbuf[16][12];
  const int tid = threadIdx.x;
  const int wv = tid >> 6;
  const int ln = tid & 63;
  const int lr = ln & 15;
  const int lq = ln >> 4;

  bf16x8 wo1f[4][8];
  float bo1r[4];
  #pragma unroll
  for (int jn = 0; jn < 4; ++jn) {
    int n0 = wv * 64 + jn * 16;
    bo1r[jn] = bo1[n0 + lr];
    #pragma unroll
    for (int kt = 0; kt < 8; ++kt)
      wo1f[jn][kt] = *reinterpret_cast<const bf16x8*>(
          &Wo1b[(size_t)(n0 + lr) * 256 + kt * 32 + lq * 8]);
  }
  const int col = (wv - 1) * 16 + lr;
  bf16x8 wvf[8];
  float bvr = 0.f;
  if (wv >= 1) {
    #pragma unroll
    for (int kt = 0; kt < 8; ++kt)
      wvf[kt] = *reinterpret_cast<const bf16x8*>(
          &Wvb[(size_t)col * 256 + kt * 32 + lq * 8]);
    bvr = (col < 42) ? bv[col] : 0.f;
  }
  bf16x8 wo2f[8];
  if (wv == 0) {
    #pragma unroll
    for (int kt = 0; kt < 8; ++kt)
      wo2f[kt] = *reinterpret_cast<const bf16x8*>(
          &Wo2b[(size_t)lr * 256 + kt * 32 + lq * 8]);
  }

  for (int it = 0; it < 10; ++it) {
    int tt = blockIdx.x * 10 + it;
    size_t r0 = (size_t)tt * 16;
    bf16x8 ah[8];
    #pragma unroll
    for (int kt = 0; kt < 8; ++kt)
      ah[kt] = *reinterpret_cast<const bf16x8*>(&Hseq[(r0 + lr) * 256 + kt * 32 + lq * 8]);
    #pragma unroll
    for (int jn = 0; jn < 4; ++jn) {
      int n0 = wv * 64 + jn * 16;
      float bb = bo1r[jn];
      f32x4 acc = {bb, bb, bb, bb};
      #pragma unroll
      for (int kt = 0; kt < 8; ++kt)
        acc = __builtin_amdgcn_mfma_f32_16x16x32_bf16(ah[kt], wo1f[jn][kt], acc, 0, 0, 0);
      #pragma unroll
      for (int r = 0; r < 4; ++r)
        u1buf[lq * 4 + r][n0 + lr] = (bf16)fmaxf(acc[r], 0.f);
    }
    if (wv >= 1) {
      f32x4 acc = {bvr, bvr, bvr, bvr};
      #pragma unroll
      for (int kt = 0; kt < 8; ++kt)
        acc = __builtin_amdgcn_mfma_f32_16x16x32_bf16(ah[kt], wvf[kt], acc, 0, 0, 0);
      if (col < 42) {
        #pragma unroll
        for (int r = 0; r < 4; ++r) {
          float s = 0.05f + 0.45f * sigf(acc[r]);
          out3[(r0 + lq * 4 + r) * 42 + col] = __logf(s);
        }
      }
    }
    if (tid < 192) {
      int rr = tid / 12, d = tid % 12;
      jbuf[rr][d] = joints[(r0 + rr) * 12 + d];
    }
    __syncthreads();
    if (wv == 0) {
      bf16x8 ap[8];
      #pragma unroll
      for (int kt = 0; kt < 8; ++kt)
        ap[kt] = *reinterpret_cast<const bf16x8*>(&u1buf[lr][kt * 32 + lq * 8]);
      f32x4 acc = {0.f, 0.f, 0.f, 0.f};
      #pragma unroll
      for (int kt = 0; kt < 8; ++kt)
        acc = __builtin_amdgcn_mfma_f32_16x16x32_bf16(ap[kt], wo2f[kt], acc, 0, 0, 0);
      if (lr < 3) {
        #pragma unroll
        for (int r = 0; r < 4; ++r)
          objbuf[lq * 4 + r][lr] = acc[r] + bo2[lr];
      }
    }
    __syncthreads();
    for (int e = tid; e < 16 * 42; e += 256) {
      int rr = e / 42, pd = e % 42;
      float v;
      if (pd < 39) {
        float s = bfk[pd];
        #pragma unroll
        for (int d = 0; d < 12; ++d) s += jbuf[rr][d] * Wfk[pd * 12 + d];
        v = s;
      } else v = objbuf[rr][pd - 39];
      out0[(r0 + rr) * 42 + pd] = (v - pm[pd]) / ps[pd];
    }
    __syncthreads();
  }
}

extern "C" void kernel_launch(void* const* d_in, const int* in_sizes, int n_in,
                              void* d_out, int out_size, void* d_ws, size_t ws_size,
                              hipStream_t stream) {
  const float* z   = (const float*)d_in[0];
  const float* Whz = (const float*)d_in[1];
  const float* bhz = (const float*)d_in[2];
  const float* Wcz = (const float*)d_in[3];
  const float* bcz = (const float*)d_in[4];
  const float* Wih = (const float*)d_in[5];
  const float* Whh = (const float*)d_in[6];
  const float* bih = (const float*)d_in[7];
  const float* bhh = (const float*)d_in[8];
  const float* Wp1 = (const float*)d_in[9];
  const float* bp1 = (const float*)d_in[10];
  const float* Wp2 = (const float*)d_in[11];
  const float* bp2 = (const float*)d_in[12];
  const float* Wo1 = (const float*)d_in[13];
  const float* bo1 = (const float*)d_in[14];
  const float* Wo2 = (const float*)d_in[15];
  const float* bo2 = (const float*)d_in[16];
  const float* Wv  = (const float*)d_in[17];
  const float* bv  = (const float*)d_in[18];
  const float* Wfk = (const float*)d_in[19];
  const float* bfk = (const float*)d_in[20];
  const float* pm  = (const float*)d_in[21];
  const float* ps  = (const float*)d_in[22];
  const float* jlo = (const float*)d_in[23];
  const float* jhi = (const float*)d_in[24];
  const float* ddp = (const float*)d_in[25];

  char* ws = (char*)d_ws;
  float* tf    = (float*)(ws + OFF_TF);
  float* tconp = (float*)(ws + OFF_TCONP);
  float* zcp   = (float*)(ws + OFF_ZCP);
  float* h0    = (float*)(ws + OFF_H0);
  float* c0    = (float*)(ws + OFF_C0);
  bf16* Wcomb  = (bf16*)(ws + OFF_WCOMB);
  bf16* Wp1b   = (bf16*)(ws + OFF_WP1);
  bf16* Wp2b   = (bf16*)(ws + OFF_WP2);
  bf16* Wo1b   = (bf16*)(ws + OFF_WO1);
  bf16* Wo2b   = (bf16*)(ws + OFF_WO2);
  bf16* Wvb    = (bf16*)(ws + OFF_WV);
  u64* hxt     = (u64*)(ws + OFF_HX);
  bf16* Hseq   = (bf16*)(ws + OFF_HSEQ);

  float* out  = (float*)d_out;
  float* out0 = out;                 // graph_x_mu [B,T,42]
  float* outJ = out + 2150400;       // joint_traj [B,T,12]
  float* outA = out + 2764800;       // actions    [B,T,12]
  float* out3 = out + 3379200;       // log_sigma  [B,T,42]

  k_tfeat<<<11, 256, 0, stream>>>(tf);
  k_prep<<<2336, 256, 0, stream>>>(tf, Wih, z, bih, bhh, Whz, bhz, Wcz, bcz,
                                   tconp, zcp, h0, c0);
  k_cast<<<1744, 256, 0, stream>>>(Whh, Wih, Wp1, Wp2, Wo1, Wo2, Wv,
                                   Wcomb, Wp1b, Wp2b, Wo1b, Wo2b, Wvb);
  k_recur<<<32, 512, 0, stream>>>(zcp, tconp, h0, c0, Wcomb, Wp1b, Wp2b,
                                  bp1, bp2, jlo, jhi, ddp, hxt,
                                  Hseq, outJ, outA);
  k_post<<<320, 256, 0, stream>>>(Hseq, Wo1b, Wo2b, Wvb, bo1, bo2, bv,
                                  Wfk, bfk, pm, ps, outJ, out0, out3);
}

// Round 10
// 1102.051 us; speedup vs baseline: 3.2153x; 1.0149x over previous
//
#include <hip/hip_runtime.h>
#include <math.h>

#define B_ 256
#define T_ 200
#define H_ 256
#define DOF_ 12

typedef __bf16 bf16;
typedef __bf16 bf16x8 __attribute__((ext_vector_type(8)));
typedef float f32x4 __attribute__((ext_vector_type(4)));
typedef unsigned long long u64;

#define XK 288      // gate GEMM K: 256 h + 12 prev + 20 zero pad
#define XPAD 296
#define P1PAD 264

#define PI_D 3.14159265358979323846

// ---- workspace byte offsets (all 16B aligned) ----
#define OFF_TF     0u
#define OFF_TCONP  10400u
#define OFF_ZCP    829600u
#define OFF_H0     1878176u
#define OFF_C0     2140320u
#define OFF_WCOMB  2402464u
#define OFF_WP1    2992288u
#define OFF_WP2    3123360u
#define OFF_WO1    3131552u
#define OFF_WO2    3262624u
#define OFF_WV     3270816u
#define OFF_HX     3295392u    // 16 pairs * 2 slots * 2 halves * 128 * 4 * 16B = 512KB
#define OFF_HSEQ   3819680u    // 256*200*256*2 = 26214400 (end ~30.0MB)

__device__ __forceinline__ float sigf(float x) { return 1.f / (1.f + __expf(-x)); }
__device__ __forceinline__ float tanh_f(float x) {
  float a = fabsf(x);
  float e = __expf(-2.f * a);
  float t = (1.f - e) * __builtin_amdgcn_rcpf(1.f + e);
  return x < 0.f ? -t : t;
}

// light barrier: order LDS, leave global ops in flight
#define LBAR() asm volatile("s_waitcnt lgkmcnt(0)\n\ts_barrier" ::: "memory")

// ---------------- time features [T,13] ----------------
__global__ void k_tfeat(float* tf) {
  int i = blockIdx.x * blockDim.x + threadIdx.x;
  if (i >= T_ * 13) return;
  int t = i / 13, j = i % 13;
  float tv = (float)t / 199.f;
  float v;
  if (j == 0) v = tv;
  else {
    int k = (j - 1) >> 1;
    float f = (float)(1 << k);
    double arg = 2.0 * PI_D * (double)f * (double)tv;
    v = (j & 1) ? (float)sin(arg) : (float)cos(arg);
  }
  tf[i] = v;
}

// ------------- precompute tconp, zcp, h0, c0 (lane-packed layouts) -------------
__global__ void k_prep(const float* __restrict__ tf, const float* __restrict__ Wih,
                       const float* __restrict__ z,
                       const float* __restrict__ bih, const float* __restrict__ bhh,
                       const float* __restrict__ Whz, const float* __restrict__ bhz,
                       const float* __restrict__ Wcz, const float* __restrict__ bcz,
                       float* tconp, float* zcp, float* h0, float* c0) {
  int i = blockIdx.x * blockDim.x + threadIdx.x;
  if (i < 204800) {
    // tconp[t*1024 + half*512 + u_loc*4 + g]
    int g = i & 3, q = i >> 2;
    int m = q & 127, hm = (q >> 7) & 1, t = q >> 8;
    int n = g * 256 + 128 * hm + m;
    float s = 0.f;
    #pragma unroll
    for (int j = 0; j < 13; ++j) s += tf[t * 13 + j] * Wih[n * 89 + 76 + j];
    tconp[i] = s;
    return;
  }
  i -= 204800;
  if (i < 262144) {
    // zcp[((lbid*512 + tid512)*4 + g)*4 + r] ; tid512 = wv8*64 + ln, unit = 16*wv8 + lr
    int r = i & 3, g = (i >> 2) & 3, tid = (i >> 4) & 511;
    int half = (i >> 13) & 1, pairk = i >> 14;
    int wv = tid >> 6, lr = tid & 15, lq = (tid >> 4) & 3;
    int b = pairk * 16 + lq * 4 + r;
    int n = g * 256 + 128 * half + 16 * wv + lr;
    float s = bih[n] + bhh[n];
    for (int k = 0; k < 64; ++k) s += z[b * 64 + k] * Wih[n * 89 + 12 + k];
    zcp[i] = s;
    return;
  }
  i -= 262144;
  if (i < 65536) {
    int b = i / 256, u = i % 256;
    float s = bhz[u];
    for (int k = 0; k < 64; ++k) s += z[b * 64 + k] * Whz[u * 64 + k];
    h0[i] = s;
    return;
  }
  i -= 65536;
  if (i < 65536) {
    int b = i / 256, u = i % 256;
    float s = bcz[u];
    for (int k = 0; k < 64; ++k) s += z[b * 64 + k] * Wcz[u * 64 + k];
    c0[i] = s;
  }
}

// ------------- bf16 weight casts -------------
__global__ void k_cast(const float* __restrict__ Whh, const float* __restrict__ Wih,
                       const float* __restrict__ Wp1, const float* __restrict__ Wp2,
                       const float* __restrict__ Wo1, const float* __restrict__ Wo2,
                       const float* __restrict__ Wv,
                       bf16* Wcomb, bf16* Wp1b, bf16* Wp2b, bf16* Wo1b,
                       bf16* Wo2b, bf16* Wvb) {
  int i = blockIdx.x * blockDim.x + threadIdx.x;
  if (i < 294912) {
    int n = i / XK, k = i % XK;
    float v = (k < 256) ? Whh[n * 256 + k]
            : ((k < 268) ? Wih[n * 89 + (k - 256)] : 0.f);
    Wcomb[i] = (bf16)v;
    return;
  }
  i -= 294912;
  if (i < 65536) { Wp1b[i] = (bf16)Wp1[i]; return; }
  i -= 65536;
  if (i < 4096) { int r = i / 256; Wp2b[i] = (bf16)((r < 12) ? Wp2[i] : 0.f); return; }
  i -= 4096;
  if (i < 65536) { Wo1b[i] = (bf16)Wo1[i]; return; }
  i -= 65536;
  if (i < 4096) { int r = i / 256; Wo2b[i] = (bf16)((r < 3) ? Wo2[i] : 0.f); return; }
  i -= 4096;
  if (i < 12288) { int r = i / 256; Wvb[i] = (bf16)((r < 42) ? Wv[i] : 0.f); }
}

// ------- recurrent LSTM: 32 blocks (16 pairs x 2 halves), 256 thr, 4 waves -------
// 1 wave/SIMD -> 512-reg budget/wave: ALL 4 gates' weights (2 ji x 4 g x 9 kt =
// 72 frags = 288 regs) pinned in AGPRs. Wp1+Wp2 in LDS. Tag-embedded u64
// relaxed agent-atomic exchange of h halves, batched 4-load poll.
__global__ __launch_bounds__(256, 1) void k_recur(
    const float* __restrict__ zcp, const float* __restrict__ tconp,
    const float* __restrict__ h0, const float* __restrict__ c0,
    const bf16* __restrict__ Wcomb, const bf16* __restrict__ Wp1b,
    const bf16* __restrict__ Wp2b,
    const float* __restrict__ bp1, const float* __restrict__ bp2,
    const float* __restrict__ jlo, const float* __restrict__ jhi,
    const float* __restrict__ ddp,
    u64* hxt,
    bf16* __restrict__ Hseq, float* __restrict__ outJ, float* __restrict__ outA) {
  __shared__ bf16 xbuf[16][XPAD];
  __shared__ bf16 w1[272][P1PAD];      // 0..255 Wp1, 256..271 Wp2
  __shared__ bf16 p1buf[16][P1PAD];
  const int tid = threadIdx.x;
  const int wv = tid >> 6, ln = tid & 63, lr = ln & 15, lq = ln >> 4;
  const int bid = blockIdx.x;
  const int pairk = ((bid >> 4) << 3) | (bid & 7);   // bid^8 shares this (same XCD)
  const int half = (bid >> 3) & 1;
  const int lbid = pairk * 2 + half;
  const int b0 = pairk * 16;

  // ---- one-time LDS fills (stride 256) ----
  for (int i = tid; i < 272 * 32; i += 256) {
    int r = i >> 5, c8 = (i & 31) * 8;
    bf16x8 v = (r < 256)
      ? *reinterpret_cast<const bf16x8*>(&Wp1b[r * 256 + c8])
      : *reinterpret_cast<const bf16x8*>(&Wp2b[(r - 256) * 256 + c8]);
    *reinterpret_cast<bf16x8*>(&w1[r][c8]) = v;
  }
  for (int i = tid; i < 16 * XPAD; i += 256) {
    int r = i / XPAD, c = i % XPAD;
    float v = 0.f;
    if (c < 256) v = h0[(b0 + r) * 256 + c];
    else if (c < 268) {
      int d = c - 256;
      float lo = jlo[d], hi = jhi[d];
      v = (ddp[d] - 0.5f * (hi + lo)) / (0.5f * (hi - lo));
    }
    xbuf[r][c] = (bf16)v;
  }

  // ---- ALL gate weights -> AGPRs (288 regs/lane) ----
  // wave owns units u_loc = 32*wv + 16*ji + lr, ji in {0,1}
  f32x4 wc[2][4][9];
  #pragma unroll
  for (int ji = 0; ji < 2; ++ji) {
    const int ug = 128 * half + 32 * wv + 16 * ji + lr;
    #pragma unroll
    for (int g = 0; g < 4; ++g)
      #pragma unroll
      for (int kt = 0; kt < 9; ++kt)
        wc[ji][g][kt] = *reinterpret_cast<const f32x4*>(
            &Wcomb[(size_t)(g * 256 + ug) * XK + kt * 32 + lq * 8]);
  }
  #pragma unroll
  for (int kt = 0; kt < 9; ++kt)
    asm volatile("" : "+a"(wc[0][0][kt]), "+a"(wc[0][1][kt]),
                      "+a"(wc[0][2][kt]), "+a"(wc[0][3][kt]),
                      "+a"(wc[1][0][kt]), "+a"(wc[1][1][kt]),
                      "+a"(wc[1][2][kt]), "+a"(wc[1][3][kt]));

  // ---- per-lane state (per ji) ----
  float c_reg[2][4];
  f32x4 zcreg[2][4];
  bf16* hs[2];
  #pragma unroll
  for (int ji = 0; ji < 2; ++ji) {
    const int ug = 128 * half + 32 * wv + 16 * ji + lr;
    #pragma unroll
    for (int r = 0; r < 4; ++r) c_reg[ji][r] = c0[(b0 + lq * 4 + r) * 256 + ug];
    const int tid512 = (2 * wv + ji) * 64 + ln;   // matches zcp's 8-wave layout
    #pragma unroll
    for (int g = 0; g < 4; ++g)
      zcreg[ji][g] = *reinterpret_cast<const f32x4*>(
          zcp + ((size_t)lbid * 512 + tid512) * 16 + g * 4);
    hs[ji] = Hseq + ((size_t)(b0 + lq * 4) * T_) * 256 + ug;
  }
  const float* tcb0 = tconp + (size_t)(half * 512 + (32 * wv + lr) * 4);
  const float* tcb1 = tcb0 + 64;   // +16 units * 4
  // p1: wave owns 64 cols [64wv, 64wv+64)
  float bp1r[4];
  #pragma unroll
  for (int jn = 0; jn < 4; ++jn) bp1r[jn] = bp1[64 * wv + 16 * jn + lr];
  float bp2r = 0.f, ddr = 0.f, lor = -1.f, hir = 1.f;
  if (lr < 12) { bp2r = bp2[lr]; ddr = ddp[lr]; lor = jlo[lr]; hir = jhi[lr]; }
  const float jmr = 0.5f * (hir + lor), jrr = 0.5f * (hir - lor);

  // ---- exchange addresses ----
  // writer: entry [(pairk*2+slot)*2+half][u_loc][lq], 2 u64 each; per ji.
  u64* pws[2][2];
  #pragma unroll
  for (int ji = 0; ji < 2; ++ji) {
    const int ul = 32 * wv + 16 * ji + lr;
    #pragma unroll
    for (int s = 0; s < 2; ++s)
      pws[ji][s] = hxt + ((((size_t)(pairk * 2 + s) * 2 + half) * 128 + ul) * 4 + lq) * 2;
  }
  // reader: partner col ru = 32wv + (ln>>1); this lane covers 8 rows (ln&1)*8..+8
  const int ru = 32 * wv + (ln >> 1);
  const int rcol = 128 * (half ^ 1) + ru;
  const int row0 = (ln & 1) * 8;
  u64* prs[2];
  #pragma unroll
  for (int s = 0; s < 2; ++s)
    prs[s] = hxt + ((((size_t)(pairk * 2 + s) * 2 + (half ^ 1)) * 128 + ru) * 4 + 2 * (ln & 1)) * 2;

  f32x4 tcv0 = *reinterpret_cast<const f32x4*>(tcb0);
  f32x4 tcv1 = *reinterpret_cast<const f32x4*>(tcb1);
  __syncthreads();
  bool dead = false;

  for (int t = 0; t < T_; ++t) {
    // ---- gates: kt-outer, shared A fragment, AGPR weights ----
    f32x4 ac[2][4];
    #pragma unroll
    for (int g = 0; g < 4; ++g) { ac[0][g] = zcreg[0][g] + tcv0[g]; ac[1][g] = zcreg[1][g] + tcv1[g]; }
    #pragma unroll
    for (int kt = 0; kt < 9; ++kt) {
      bf16x8 a = *reinterpret_cast<const bf16x8*>(&xbuf[lr][kt * 32 + lq * 8]);
      asm volatile("" : "+a"(wc[0][0][kt]), "+a"(wc[0][1][kt]),
                        "+a"(wc[0][2][kt]), "+a"(wc[0][3][kt]),
                        "+a"(wc[1][0][kt]), "+a"(wc[1][1][kt]),
                        "+a"(wc[1][2][kt]), "+a"(wc[1][3][kt]));
      #pragma unroll
      for (int ji = 0; ji < 2; ++ji)
        #pragma unroll
        for (int g = 0; g < 4; ++g)
          ac[ji][g] = __builtin_amdgcn_mfma_f32_16x16x32_bf16(
              a, __builtin_bit_cast(bf16x8, wc[ji][g][kt]), ac[ji][g], 0, 0, 0);
    }
    LBAR();  // all xbuf reads done before h overwrite

    // ---- LSTM elementwise + publish (tag-embedded) ----
    const unsigned int want = t + 1;
    bf16 hb[2][4];
    #pragma unroll
    for (int ji = 0; ji < 2; ++ji) {
      unsigned short s4[4];
      #pragma unroll
      for (int r = 0; r < 4; ++r) {
        float cn = sigf(ac[ji][1][r]) * c_reg[ji][r] + sigf(ac[ji][0][r]) * tanh_f(ac[ji][2][r]);
        float hn = sigf(ac[ji][3][r]) * tanh_f(cn);
        c_reg[ji][r] = cn;
        bf16 h = (bf16)hn;
        hb[ji][r] = h;
        s4[r] = __builtin_bit_cast(unsigned short, h);
      }
      u64 q0 = ((u64)want << 32) | (u64)s4[0] | ((u64)s4[1] << 16);
      u64 q1 = ((u64)want << 32) | (u64)s4[2] | ((u64)s4[3] << 16);
      u64* pw = pws[ji][t & 1];
      __hip_atomic_store(pw, q0, __ATOMIC_RELAXED, __HIP_MEMORY_SCOPE_AGENT);
      __hip_atomic_store(pw + 1, q1, __ATOMIC_RELAXED, __HIP_MEMORY_SCOPE_AGENT);
    }
    // own h -> xbuf + Hseq; next-step tcon prefetch (all in the poll shadow)
    #pragma unroll
    for (int ji = 0; ji < 2; ++ji) {
      const int ug = 128 * half + 32 * wv + 16 * ji + lr;
      #pragma unroll
      for (int r = 0; r < 4; ++r) {
        xbuf[lq * 4 + r][ug] = hb[ji][r];
        hs[ji][(size_t)r * (T_ * 256) + (size_t)t * 256] = hb[ji][r];
      }
    }
    {
      size_t tp = (size_t)((t + 1 < T_) ? t + 1 : t) * 1024;
      f32x4 tn0 = *reinterpret_cast<const f32x4*>(tcb0 + tp);
      f32x4 tn1 = *reinterpret_cast<const f32x4*>(tcb1 + tp);
      tcv0 = tn0; tcv1 = tn1;
    }

    // ---- batched poll: 4 u64 per lane, one waitcnt per attempt ----
    u64 pq0, pq1, pq2, pq3;
    {
      u64* pr = prs[t & 1];
      int guard = 1 << 16;
      for (;;) {
        pq0 = __hip_atomic_load(pr + 0, __ATOMIC_RELAXED, __HIP_MEMORY_SCOPE_AGENT);
        pq1 = __hip_atomic_load(pr + 1, __ATOMIC_RELAXED, __HIP_MEMORY_SCOPE_AGENT);
        pq2 = __hip_atomic_load(pr + 2, __ATOMIC_RELAXED, __HIP_MEMORY_SCOPE_AGENT);
        pq3 = __hip_atomic_load(pr + 3, __ATOMIC_RELAXED, __HIP_MEMORY_SCOPE_AGENT);
        int ok = ((unsigned)(pq0 >> 32) == want) & ((unsigned)(pq1 >> 32) == want) &
                 ((unsigned)(pq2 >> 32) == want) & ((unsigned)(pq3 >> 32) == want);
        if (__all(ok)) break;
        if (dead || --guard == 0) { dead = true; break; }
      }
    }
    xbuf[row0 + 0][rcol] = __builtin_bit_cast(bf16, (unsigned short)(pq0));
    xbuf[row0 + 1][rcol] = __builtin_bit_cast(bf16, (unsigned short)(pq0 >> 16));
    xbuf[row0 + 2][rcol] = __builtin_bit_cast(bf16, (unsigned short)(pq1));
    xbuf[row0 + 3][rcol] = __builtin_bit_cast(bf16, (unsigned short)(pq1 >> 16));
    xbuf[row0 + 4][rcol] = __builtin_bit_cast(bf16, (unsigned short)(pq2));
    xbuf[row0 + 5][rcol] = __builtin_bit_cast(bf16, (unsigned short)(pq2 >> 16));
    xbuf[row0 + 6][rcol] = __builtin_bit_cast(bf16, (unsigned short)(pq3));
    xbuf[row0 + 7][rcol] = __builtin_bit_cast(bf16, (unsigned short)(pq3 >> 16));
    LBAR();  // full h_new visible

    // ---- p1 = relu(h_new @ Wp1^T + bp1): wave owns 64 cols, kt-outer ----
    {
      f32x4 pa0 = {bp1r[0], bp1r[0], bp1r[0], bp1r[0]};
      f32x4 pa1 = {bp1r[1], bp1r[1], bp1r[1], bp1r[1]};
      f32x4 pa2 = {bp1r[2], bp1r[2], bp1r[2], bp1r[2]};
      f32x4 pa3 = {bp1r[3], bp1r[3], bp1r[3], bp1r[3]};
      #pragma unroll
      for (int kt = 0; kt < 8; ++kt) {
        bf16x8 av = *reinterpret_cast<const bf16x8*>(&xbuf[lr][kt * 32 + lq * 8]);
        bf16x8 b0v = *reinterpret_cast<const bf16x8*>(&w1[64 * wv + lr][kt * 32 + lq * 8]);
        bf16x8 b1v = *reinterpret_cast<const bf16x8*>(&w1[64 * wv + 16 + lr][kt * 32 + lq * 8]);
        bf16x8 b2v = *reinterpret_cast<const bf16x8*>(&w1[64 * wv + 32 + lr][kt * 32 + lq * 8]);
        bf16x8 b3v = *reinterpret_cast<const bf16x8*>(&w1[64 * wv + 48 + lr][kt * 32 + lq * 8]);
        pa0 = __builtin_amdgcn_mfma_f32_16x16x32_bf16(av, b0v, pa0, 0, 0, 0);
        pa1 = __builtin_amdgcn_mfma_f32_16x16x32_bf16(av, b1v, pa1, 0, 0, 0);
        pa2 = __builtin_amdgcn_mfma_f32_16x16x32_bf16(av, b2v, pa2, 0, 0, 0);
        pa3 = __builtin_amdgcn_mfma_f32_16x16x32_bf16(av, b3v, pa3, 0, 0, 0);
      }
      #pragma unroll
      for (int r = 0; r < 4; ++r) {
        p1buf[lq * 4 + r][64 * wv + lr]      = (bf16)fmaxf(pa0[r], 0.f);
        p1buf[lq * 4 + r][64 * wv + 16 + lr] = (bf16)fmaxf(pa1[r], 0.f);
        p1buf[lq * 4 + r][64 * wv + 32 + lr] = (bf16)fmaxf(pa2[r], 0.f);
        p1buf[lq * 4 + r][64 * wv + 48 + lr] = (bf16)fmaxf(pa3[r], 0.f);
      }
    }
    LBAR();  // p1 visible

    // ---- action head on wave 0 (redundant across halves; writes gated) ----
    if (wv == 0) {
      f32x4 acc = {0.f, 0.f, 0.f, 0.f};
      #pragma unroll
      for (int kt = 0; kt < 8; ++kt) {
        bf16x8 ap = *reinterpret_cast<const bf16x8*>(&p1buf[lr][kt * 32 + lq * 8]);
        bf16x8 w2 = *reinterpret_cast<const bf16x8*>(&w1[256 + lr][kt * 32 + lq * 8]);
        acc = __builtin_amdgcn_mfma_f32_16x16x32_bf16(ap, w2, acc, 0, 0, 0);
      }
      if (lr < 12) {
        #pragma unroll
        for (int r = 0; r < 4; ++r) {
          int b = lq * 4 + r;
          float act = tanh_f(acc[r] + bp2r);
          float curp = act * 0.25f + ddr;   // TRACK_ALPHA = 1
          float cl = fminf(fmaxf(curp, lor), hir);
          if (half == 0) {
            size_t o = ((size_t)(b0 + b) * T_ + t) * 12 + lr;
            outA[o] = act;
            outJ[o] = curp;
          }
          xbuf[b][256 + lr] = (bf16)((cl - jmr) / jrr);
        }
      }
    }
    LBAR();  // prev_norm visible for next step
  }
}

// ------------- post pass: obj head, sigma head, FK, normalize -------------
__global__ __launch_bounds__(256) void k_post(
    const bf16* __restrict__ Hseq, const bf16* __restrict__ Wo1b,
    const bf16* __restrict__ Wo2b, const bf16* __restrict__ Wvb,
    const float* __restrict__ bo1, const float* __restrict__ bo2,
    const float* __restrict__ bv,
    const float* __restrict__ Wfk, const float* __restrict__ bfk,
    const float* __restrict__ pm, const float* __restrict__ ps,
    const float* __restrict__ joints, float* __restrict__ out0,
    float* __restrict__ out3) {
  __shared__ bf16 u1buf[16][P1PAD];
  __shared__ float objbuf[16][3];
  __shared__ float jbuf[16][12];
  const int tid = threadIdx.x;
  const int wv = tid >> 6;
  const int ln = tid & 63;
  const int lr = ln & 15;
  const int lq = ln >> 4;

  bf16x8 wo1f[4][8];
  float bo1r[4];
  #pragma unroll
  for (int jn = 0; jn < 4; ++jn) {
    int n0 = wv * 64 + jn * 16;
    bo1r[jn] = bo1[n0 + lr];
    #pragma unroll
    for (int kt = 0; kt < 8; ++kt)
      wo1f[jn][kt] = *reinterpret_cast<const bf16x8*>(
          &Wo1b[(size_t)(n0 + lr) * 256 + kt * 32 + lq * 8]);
  }
  const int col = (wv - 1) * 16 + lr;
  bf16x8 wvf[8];
  float bvr = 0.f;
  if (wv >= 1) {
    #pragma unroll
    for (int kt = 0; kt < 8; ++kt)
      wvf[kt] = *reinterpret_cast<const bf16x8*>(
          &Wvb[(size_t)col * 256 + kt * 32 + lq * 8]);
    bvr = (col < 42) ? bv[col] : 0.f;
  }
  bf16x8 wo2f[8];
  if (wv == 0) {
    #pragma unroll
    for (int kt = 0; kt < 8; ++kt)
      wo2f[kt] = *reinterpret_cast<const bf16x8*>(
          &Wo2b[(size_t)lr * 256 + kt * 32 + lq * 8]);
  }

  for (int it = 0; it < 10; ++it) {
    int tt = blockIdx.x * 10 + it;
    size_t r0 = (size_t)tt * 16;
    bf16x8 ah[8];
    #pragma unroll
    for (int kt = 0; kt < 8; ++kt)
      ah[kt] = *reinterpret_cast<const bf16x8*>(&Hseq[(r0 + lr) * 256 + kt * 32 + lq * 8]);
    #pragma unroll
    for (int jn = 0; jn < 4; ++jn) {
      int n0 = wv * 64 + jn * 16;
      float bb = bo1r[jn];
      f32x4 acc = {bb, bb, bb, bb};
      #pragma unroll
      for (int kt = 0; kt < 8; ++kt)
        acc = __builtin_amdgcn_mfma_f32_16x16x32_bf16(ah[kt], wo1f[jn][kt], acc, 0, 0, 0);
      #pragma unroll
      for (int r = 0; r < 4; ++r)
        u1buf[lq * 4 + r][n0 + lr] = (bf16)fmaxf(acc[r], 0.f);
    }
    if (wv >= 1) {
      f32x4 acc = {bvr, bvr, bvr, bvr};
      #pragma unroll
      for (int kt = 0; kt < 8; ++kt)
        acc = __builtin_amdgcn_mfma_f32_16x16x32_bf16(ah[kt], wvf[kt], acc, 0, 0, 0);
      if (col < 42) {
        #pragma unroll
        for (int r = 0; r < 4; ++r) {
          float s = 0.05f + 0.45f * sigf(acc[r]);
          out3[(r0 + lq * 4 + r) * 42 + col] = __logf(s);
        }
      }
    }
    if (tid < 192) {
      int rr = tid / 12, d = tid % 12;
      jbuf[rr][d] = joints[(r0 + rr) * 12 + d];
    }
    __syncthreads();
    if (wv == 0) {
      bf16x8 ap[8];
      #pragma unroll
      for (int kt = 0; kt < 8; ++kt)
        ap[kt] = *reinterpret_cast<const bf16x8*>(&u1buf[lr][kt * 32 + lq * 8]);
      f32x4 acc = {0.f, 0.f, 0.f, 0.f};
      #pragma unroll
      for (int kt = 0; kt < 8; ++kt)
        acc = __builtin_amdgcn_mfma_f32_16x16x32_bf16(ap[kt], wo2f[kt], acc, 0, 0, 0);
      if (lr < 3) {
        #pragma unroll
        for (int r = 0; r < 4; ++r)
          objbuf[lq * 4 + r][lr] = acc[r] + bo2[lr];
      }
    }
    __syncthreads();
    for (int e = tid; e < 16 * 42; e += 256) {
      int rr = e / 42, pd = e % 42;
      float v;
      if (pd < 39) {
        float s = bfk[pd];
        #pragma unroll
        for (int d = 0; d < 12; ++d) s += jbuf[rr][d] * Wfk[pd * 12 + d];
        v = s;
      } else v = objbuf[rr][pd - 39];
      out0[(r0 + rr) * 42 + pd] = (v - pm[pd]) / ps[pd];
    }
    __syncthreads();
  }
}

extern "C" void kernel_launch(void* const* d_in, const int* in_sizes, int n_in,
                              void* d_out, int out_size, void* d_ws, size_t ws_size,
                              hipStream_t stream) {
  const float* z   = (const float*)d_in[0];
  const float* Whz = (const float*)d_in[1];
  const float* bhz = (const float*)d_in[2];
  const float* Wcz = (const float*)d_in[3];
  const float* bcz = (const float*)d_in[4];
  const float* Wih = (const float*)d_in[5];
  const float* Whh = (const float*)d_in[6];
  const float* bih = (const float*)d_in[7];
  const float* bhh = (const float*)d_in[8];
  const float* Wp1 = (const float*)d_in[9];
  const float* bp1 = (const float*)d_in[10];
  const float* Wp2 = (const float*)d_in[11];
  const float* bp2 = (const float*)d_in[12];
  const float* Wo1 = (const float*)d_in[13];
  const float* bo1 = (const float*)d_in[14];
  const float* Wo2 = (const float*)d_in[15];
  const float* bo2 = (const float*)d_in[16];
  const float* Wv  = (const float*)d_in[17];
  const float* bv  = (const float*)d_in[18];
  const float* Wfk = (const float*)d_in[19];
  const float* bfk = (const float*)d_in[20];
  const float* pm  = (const float*)d_in[21];
  const float* ps  = (const float*)d_in[22];
  const float* jlo = (const float*)d_in[23];
  const float* jhi = (const float*)d_in[24];
  const float* ddp = (const float*)d_in[25];

  char* ws = (char*)d_ws;
  float* tf    = (float*)(ws + OFF_TF);
  float* tconp = (float*)(ws + OFF_TCONP);
  float* zcp   = (float*)(ws + OFF_ZCP);
  float* h0    = (float*)(ws + OFF_H0);
  float* c0    = (float*)(ws + OFF_C0);
  bf16* Wcomb  = (bf16*)(ws + OFF_WCOMB);
  bf16* Wp1b   = (bf16*)(ws + OFF_WP1);
  bf16* Wp2b   = (bf16*)(ws + OFF_WP2);
  bf16* Wo1b   = (bf16*)(ws + OFF_WO1);
  bf16* Wo2b   = (bf16*)(ws + OFF_WO2);
  bf16* Wvb    = (bf16*)(ws + OFF_WV);
  u64* hxt     = (u64*)(ws + OFF_HX);
  bf16* Hseq   = (bf16*)(ws + OFF_HSEQ);

  float* out  = (float*)d_out;
  float* out0 = out;                 // graph_x_mu [B,T,42]
  float* outJ = out + 2150400;       // joint_traj [B,T,12]
  float* outA = out + 2764800;       // actions    [B,T,12]
  float* out3 = out + 3379200;       // log_sigma  [B,T,42]

  k_tfeat<<<11, 256, 0, stream>>>(tf);
  k_prep<<<2336, 256, 0, stream>>>(tf, Wih, z, bih, bhh, Whz, bhz, Wcz, bcz,
                                   tconp, zcp, h0, c0);
  k_cast<<<1744, 256, 0, stream>>>(Whh, Wih, Wp1, Wp2, Wo1, Wo2, Wv,
                                   Wcomb, Wp1b, Wp2b, Wo1b, Wo2b, Wvb);
  k_recur<<<32, 256, 0, stream>>>(zcp, tconp, h0, c0, Wcomb, Wp1b, Wp2b,
                                  bp1, bp2, jlo, jhi, ddp, hxt,
                                  Hseq, outJ, outA);
  k_post<<<320, 256, 0, stream>>>(Hseq, Wo1b, Wo2b, Wvb, bo1, bo2, bv,
                                  Wfk, bfk, pm, ps, outJ, out0, out3);
}